// Round 3
// baseline (1176.085 us; speedup 1.0000x reference)
//
#include <hip/hip_runtime.h>
#include <hip/hip_bf16.h>

#define CHN   512
#define HW    4096
#define C3    1536

typedef __hip_bfloat16 bf16;
typedef __attribute__((ext_vector_type(8))) short short8;
typedef __attribute__((ext_vector_type(4))) float f32x4;

__device__ inline float b2f_bits(short s) {
    union { unsigned u; float f; } uf;
    uf.u = ((unsigned)(unsigned short)s) << 16;
    return uf.f;
}
__device__ inline short f2b_bits(float x) {
    union { __hip_bfloat16 h; short s; } u;
    u.h = __float2bfloat16(x);
    return u.s;
}
// split f32 -> (hi, lo) bf16 pair; x ~= hi + lo with ~2^-18 relative residual
__device__ inline void split_bf16(float x, short& hi, short& lo) {
    hi = f2b_bits(x);
    lo = f2b_bits(x - b2f_bits(hi));
}

// ---------------- [C][N] -> [N][C] transpose, f32 ----------------
__global__ __launch_bounds__(256) void k_transpose_f32(const float* __restrict__ in,
                                                       float* __restrict__ out,
                                                       int Cdim, int Ndim) {
    __shared__ float tile[64][65];
    int c0 = blockIdx.y * 64;
    int n0 = blockIdx.x * 64;
    int t = threadIdx.x;
    int col = t & 63, rr = t >> 6;
#pragma unroll
    for (int p = 0; p < 16; ++p) {
        int r = p * 4 + rr;
        tile[r][col] = in[(long)(c0 + r) * Ndim + n0 + col];
    }
    __syncthreads();
#pragma unroll
    for (int p = 0; p < 16; ++p) {
        int r = p * 4 + rr;
        out[(long)(n0 + r) * Cdim + c0 + col] = tile[col][r];
    }
}

// ---------------- split-precision f32 GEMM: C = A (MxK) * Bt^T (NxK), all f32 ----------------
// 3-pass bf16 MFMA (hh + lh + hl), error ~2^-18 relative
__global__ __launch_bounds__(256) void k_gemm_f32s(const float* __restrict__ A,
                                                   const float* __restrict__ Bt,
                                                   float* __restrict__ C,
                                                   int M, int N, int K) {
    __shared__ short sAh[128 * 72];
    __shared__ short sAl[128 * 72];
    __shared__ short sBh[128 * 72];
    __shared__ short sBl[128 * 72];
    int m0 = blockIdx.y * 128, n0 = blockIdx.x * 128;
    int t = threadIdx.x;
    int wid = t >> 6, lane = t & 63;
    int wr = (wid >> 1) * 64, wc = (wid & 1) * 64;
    int lrow = lane & 15;
    int kgrp = (lane >> 4) * 8;
    f32x4 acc[4][4] = {};
    for (int kt = 0; kt < K; kt += 64) {
#pragma unroll
        for (int p = 0; p < 8; ++p) {
            int id = p * 256 + t;
            int row = id >> 4, c4 = (id & 15) * 4;
            f32x4 va = *(const f32x4*)&A[(long)(m0 + row) * K + kt + c4];
            f32x4 vb = *(const f32x4*)&Bt[(long)(n0 + row) * K + kt + c4];
#pragma unroll
            for (int j = 0; j < 4; ++j) {
                short h, l;
                split_bf16(va[j], h, l);
                sAh[row * 72 + c4 + j] = h;
                sAl[row * 72 + c4 + j] = l;
                split_bf16(vb[j], h, l);
                sBh[row * 72 + c4 + j] = h;
                sBl[row * 72 + c4 + j] = l;
            }
        }
        __syncthreads();
#pragma unroll
        for (int ks = 0; ks < 2; ++ks) {
            short8 ah[4], al[4], bh[4], bl[4];
#pragma unroll
            for (int i = 0; i < 4; ++i) {
                ah[i] = *(const short8*)&sAh[(wr + i * 16 + lrow) * 72 + ks * 32 + kgrp];
                al[i] = *(const short8*)&sAl[(wr + i * 16 + lrow) * 72 + ks * 32 + kgrp];
                bh[i] = *(const short8*)&sBh[(wc + i * 16 + lrow) * 72 + ks * 32 + kgrp];
                bl[i] = *(const short8*)&sBl[(wc + i * 16 + lrow) * 72 + ks * 32 + kgrp];
            }
#pragma unroll
            for (int mi = 0; mi < 4; ++mi)
#pragma unroll
                for (int ni = 0; ni < 4; ++ni) {
                    acc[mi][ni] = __builtin_amdgcn_mfma_f32_16x16x32_bf16(
                        ah[mi], bh[ni], acc[mi][ni], 0, 0, 0);
                    acc[mi][ni] = __builtin_amdgcn_mfma_f32_16x16x32_bf16(
                        al[mi], bh[ni], acc[mi][ni], 0, 0, 0);
                    acc[mi][ni] = __builtin_amdgcn_mfma_f32_16x16x32_bf16(
                        ah[mi], bl[ni], acc[mi][ni], 0, 0, 0);
                }
        }
        __syncthreads();
    }
    int crow = (lane >> 4) * 4, ccol = lane & 15;
#pragma unroll
    for (int mi = 0; mi < 4; ++mi)
#pragma unroll
        for (int ni = 0; ni < 4; ++ni)
#pragma unroll
            for (int r = 0; r < 4; ++r) {
                int row = m0 + wr + mi * 16 + crow + r;
                int col = n0 + wc + ni * 16 + ccol;
                C[(long)row * N + col] = acc[mi][ni][r];
            }
}

// ---------------- fused depthwise 3x3 SAME + (q,k) L2-norm, f32 in-place ----------------
__global__ __launch_bounds__(256) void k_dwl2_f32(float* __restrict__ qkv,
                                                  const float* __restrict__ w) {
    __shared__ float img[64][68];
    __shared__ float red[4];
    int ch = blockIdx.x;
    bool is_qk = ch < 1024;
    float* p = qkv + (long)ch * HW;
    float w9[9];
#pragma unroll
    for (int i = 0; i < 9; ++i) w9[i] = w[ch * 9 + i];
    int t = threadIdx.x;
    int x = t & 63, rr = t >> 6;
#pragma unroll
    for (int ps = 0; ps < 16; ++ps) {
        int y = ps * 4 + rr;
        img[y][x] = p[y * 64 + x];
    }
    __syncthreads();
    float f[16];
#pragma unroll
    for (int ps = 0; ps < 16; ++ps) {
        int y = ps * 4 + rr;
        float s = 0.f;
#pragma unroll
        for (int dy = -1; dy <= 1; ++dy) {
            int yy = y + dy;
            if (yy < 0 || yy > 63) continue;
#pragma unroll
            for (int dx = -1; dx <= 1; ++dx) {
                int xx = x + dx;
                if (xx < 0 || xx > 63) continue;
                s += img[yy][xx] * w9[(dy + 1) * 3 + (dx + 1)];
            }
        }
        f[ps] = s;
    }
    float sc = 1.f;
    if (is_qk) {
        float ss = 0.f;
#pragma unroll
        for (int j = 0; j < 16; ++j) ss += f[j] * f[j];
#pragma unroll
        for (int o = 32; o; o >>= 1) ss += __shfl_xor(ss, o);
        if ((t & 63) == 0) red[t >> 6] = ss;
        __syncthreads();
        float tot = red[0] + red[1] + red[2] + red[3];
        sc = 1.f / fmaxf(sqrtf(tot), 1e-12f);
    }
#pragma unroll
    for (int ps = 0; ps < 16; ++ps) {
        int y = ps * 4 + rr;
        p[y * 64 + x] = f[ps] * sc;
    }
}

// ---------------- attn partials, split q,k: per (h, kslice): q(64xK)*k(64xK)^T ----------------
__global__ __launch_bounds__(256) void k_attn_s(const float* __restrict__ qkvF,
                                                float* __restrict__ attn_part) {
    __shared__ short sQh[64 * 136];
    __shared__ short sQl[64 * 136];
    __shared__ short sKh[64 * 136];
    __shared__ short sKl[64 * 136];
    int h = blockIdx.x, kslice = blockIdx.y;
    const float* qb = qkvF + (long)h * 64 * HW;
    const float* kb = qb + (long)512 * HW;
    int t = threadIdx.x, wid = t >> 6, lane = t & 63;
    int lrow = lane & 15, kgrp = (lane >> 4) * 8;
    f32x4 acc[4] = {};
    for (int kt = kslice * 1024; kt < kslice * 1024 + 1024; kt += 128) {
#pragma unroll
        for (int p = 0; p < 8; ++p) {
            int id = p * 256 + t;
            int row = id >> 5, c4 = (id & 31) * 4;
            f32x4 vq = *(const f32x4*)&qb[(long)row * HW + kt + c4];
            f32x4 vk = *(const f32x4*)&kb[(long)row * HW + kt + c4];
#pragma unroll
            for (int j = 0; j < 4; ++j) {
                short hh, ll;
                split_bf16(vq[j], hh, ll);
                sQh[row * 136 + c4 + j] = hh;
                sQl[row * 136 + c4 + j] = ll;
                split_bf16(vk[j], hh, ll);
                sKh[row * 136 + c4 + j] = hh;
                sKl[row * 136 + c4 + j] = ll;
            }
        }
        __syncthreads();
#pragma unroll
        for (int ks = 0; ks < 4; ++ks) {
            short8 kh = *(const short8*)&sKh[(wid * 16 + lrow) * 136 + ks * 32 + kgrp];
            short8 kl = *(const short8*)&sKl[(wid * 16 + lrow) * 136 + ks * 32 + kgrp];
#pragma unroll
            for (int mi = 0; mi < 4; ++mi) {
                short8 qh = *(const short8*)&sQh[(mi * 16 + lrow) * 136 + ks * 32 + kgrp];
                short8 ql = *(const short8*)&sQl[(mi * 16 + lrow) * 136 + ks * 32 + kgrp];
                acc[mi] = __builtin_amdgcn_mfma_f32_16x16x32_bf16(qh, kh, acc[mi], 0, 0, 0);
                acc[mi] = __builtin_amdgcn_mfma_f32_16x16x32_bf16(ql, kh, acc[mi], 0, 0, 0);
                acc[mi] = __builtin_amdgcn_mfma_f32_16x16x32_bf16(qh, kl, acc[mi], 0, 0, 0);
            }
        }
        __syncthreads();
    }
    float* op = attn_part + ((long)kslice * 8 + h) * 4096;
    int crow = (lane >> 4) * 4, ccol = lane & 15;
#pragma unroll
    for (int mi = 0; mi < 4; ++mi)
#pragma unroll
        for (int r = 0; r < 4; ++r)
            op[(mi * 16 + crow + r) * 64 + wid * 16 + ccol] = acc[mi][r];
}

// ---------------- fused 4x top-k masked softmax combine -> Wc (f32), per batch ----------------
__global__ __launch_bounds__(256) void k_smcomb(const float* __restrict__ attn_part,
                                                const float* __restrict__ temp,
                                                const float* __restrict__ a1,
                                                const float* __restrict__ a2,
                                                const float* __restrict__ a3,
                                                const float* __restrict__ a4,
                                                float* __restrict__ Wc) {
    int t = threadIdx.x, wid = t >> 6, lane = t & 63;
    int r = blockIdx.x * 4 + wid;   // (h, qrow), 0..511
    int h = r >> 6;
    long off = (long)r * 64 + lane;
    float a = attn_part[off] + attn_part[off + 32768] +
              attn_part[off + 65536] + attn_part[off + 98304];
    a *= temp[h];
    int cnt = 0;
#pragma unroll
    for (int j = 0; j < 64; ++j) {
        float aj = __shfl(a, j);
        cnt += (aj > a) ? 1 : 0;
    }
    float m = a;
#pragma unroll
    for (int o = 32; o; o >>= 1) m = fmaxf(m, __shfl_xor(m, o));
    float e = expf(a - m);
    const int kk[4] = {32, 42, 48, 51};
    float coef[4] = {a1[0], a2[0], a3[0], a4[0]};
    float out = 0.f;
#pragma unroll
    for (int i = 0; i < 4; ++i) {
        float ei = (cnt < kk[i]) ? e : 0.f;
        float d = ei;
#pragma unroll
        for (int o = 32; o; o >>= 1) d += __shfl_xor(d, o);
        out += coef[i] * ei / d;
    }
    Wc[off] = out;
}

// ---------------- att[h] (64xN) = Wc[h](split) * vT(split) ; writes attT f32 [N][512] ----------------
__global__ __launch_bounds__(256) void k_wv_s(const float* __restrict__ Wc,
                                              const float* __restrict__ vT,
                                              float* __restrict__ attT) {
    __shared__ short sWh[64 * 72];
    __shared__ short sWl[64 * 72];
    __shared__ short sVh[256 * 72];
    __shared__ short sVl[256 * 72];
    int h = blockIdx.y;
    int n0 = blockIdx.x * 256;
    const float* wp = Wc + (long)h * 4096;
    const float* vp = vT + (long)n0 * 512 + h * 64;
    int t = threadIdx.x, wid = t >> 6, lane = t & 63;
    int lrow = lane & 15, kgrp = (lane >> 4) * 8;
#pragma unroll
    for (int p = 0; p < 4; ++p) {
        int id = p * 256 + t;
        int row = id >> 4, c4 = (id & 15) * 4;
        f32x4 v = *(const f32x4*)&wp[row * 64 + c4];
#pragma unroll
        for (int j = 0; j < 4; ++j) {
            short hh, ll;
            split_bf16(v[j], hh, ll);
            sWh[row * 72 + c4 + j] = hh;
            sWl[row * 72 + c4 + j] = ll;
        }
    }
#pragma unroll
    for (int p = 0; p < 16; ++p) {
        int id = p * 256 + t;
        int row = id >> 4, c4 = (id & 15) * 4;
        f32x4 v = *(const f32x4*)&vp[(long)row * 512 + c4];
#pragma unroll
        for (int j = 0; j < 4; ++j) {
            short hh, ll;
            split_bf16(v[j], hh, ll);
            sVh[row * 72 + c4 + j] = hh;
            sVl[row * 72 + c4 + j] = ll;
        }
    }
    __syncthreads();
    f32x4 acc[4][4] = {};
#pragma unroll
    for (int ks = 0; ks < 2; ++ks) {
        short8 ah[4], al[4], bh[4], bl[4];
#pragma unroll
        for (int i = 0; i < 4; ++i) {
            ah[i] = *(const short8*)&sWh[(i * 16 + lrow) * 72 + ks * 32 + kgrp];
            al[i] = *(const short8*)&sWl[(i * 16 + lrow) * 72 + ks * 32 + kgrp];
            bh[i] = *(const short8*)&sVh[(wid * 64 + i * 16 + lrow) * 72 + ks * 32 + kgrp];
            bl[i] = *(const short8*)&sVl[(wid * 64 + i * 16 + lrow) * 72 + ks * 32 + kgrp];
        }
#pragma unroll
        for (int mi = 0; mi < 4; ++mi)
#pragma unroll
            for (int ni = 0; ni < 4; ++ni) {
                acc[mi][ni] = __builtin_amdgcn_mfma_f32_16x16x32_bf16(
                    ah[mi], bh[ni], acc[mi][ni], 0, 0, 0);
                acc[mi][ni] = __builtin_amdgcn_mfma_f32_16x16x32_bf16(
                    al[mi], bh[ni], acc[mi][ni], 0, 0, 0);
                acc[mi][ni] = __builtin_amdgcn_mfma_f32_16x16x32_bf16(
                    ah[mi], bl[ni], acc[mi][ni], 0, 0, 0);
            }
    }
    int crow = (lane >> 4) * 4, ccol = lane & 15;
#pragma unroll
    for (int mi = 0; mi < 4; ++mi)
#pragma unroll
        for (int ni = 0; ni < 4; ++ni) {
            int c = h * 64 + mi * 16 + crow;
            int n = n0 + wid * 64 + ni * 16 + ccol;
            *(f32x4*)&attT[(long)n * 512 + c] = acc[mi][ni];
        }
}

extern "C" void kernel_launch(void* const* d_in, const int* in_sizes, int n_in,
                              void* d_out, int out_size, void* d_ws, size_t ws_size,
                              hipStream_t stream) {
    const float* x      = (const float*)d_in[0];
    const float* qkv_w  = (const float*)d_in[1];
    const float* dw_w   = (const float*)d_in[2];
    const float* proj_w = (const float*)d_in[3];
    const float* temp   = (const float*)d_in[4];
    const float* a1     = (const float*)d_in[5];
    const float* a2     = (const float*)d_in[6];
    const float* a3     = (const float*)d_in[7];
    const float* a4     = (const float*)d_in[8];
    float* out = (float*)d_out;

    char* ws = (char*)d_ws;
    // per-batch scratch, reused across the 8 sequential batches (~51 MB total):
    float* xT        = (float*)(ws);                 //  8,388,608 B  [4096][512]
    float* qkvF      = (float*)(ws + 8388608);       // 25,165,824 B  [1536][4096]
    float* vT        = (float*)(ws + 33554432);      //  8,388,608 B  [4096][512]
    float* attT      = (float*)(ws + 41943040);      //  8,388,608 B  [4096][512]
    float* attn_part = (float*)(ws + 50331648);      //    524,288 B  [4][8][64][64]
    float* Wc        = (float*)(ws + 50855936);      //    131,072 B  [8][64][64]

    for (int b = 0; b < 8; ++b) {
        const float* xb = x + (long)b * CHN * HW;
        float* outb = out + (long)b * CHN * HW;
        // 1. x [512][4096] -> xT [4096][512] (f32)
        k_transpose_f32<<<dim3(64, 8), 256, 0, stream>>>(xb, xT, CHN, HW);
        // 2. qkv = Wqkv * x   (M=1536, N=4096, K=512), f32 split 3-pass
        k_gemm_f32s<<<dim3(32, 12), 256, 0, stream>>>(qkv_w, xT, qkvF, C3, HW, CHN);
        // 3. fused depthwise 3x3 + q,k L2-norm, f32 in-place
        k_dwl2_f32<<<C3, 256, 0, stream>>>(qkvF, dw_w);
        // 4. v -> vT [4096][512] (f32)
        k_transpose_f32<<<dim3(64, 8), 256, 0, stream>>>(qkvF + (long)1024 * HW, vT, CHN, HW);
        // 5. attn partials (K split x4), split q,k 3-pass
        k_attn_s<<<dim3(8, 4), 256, 0, stream>>>(qkvF, attn_part);
        // 6. fused top-k softmax combine (f32)
        k_smcomb<<<128, 256, 0, stream>>>(attn_part, temp, a1, a2, a3, a4, Wc);
        // 7. att = Wc * v (split 3-pass) -> attT [4096][512] f32
        k_wv_s<<<dim3(16, 8), 256, 0, stream>>>(Wc, vT, attT);
        // 8. out = Wproj * att (M=512, N=4096, K=512), f32 split 3-pass
        k_gemm_f32s<<<dim3(32, 4), 256, 0, stream>>>(proj_w, attT, outb, CHN, HW, CHN);
    }
}

// Round 5
// 428.063 us; speedup vs baseline: 2.7475x; 2.7475x over previous
//
#include <hip/hip_runtime.h>
#include <hip/hip_bf16.h>

#define CHN 512
#define HW  4096
#define C3  1536
#define GB  4   // batches per group

typedef __hip_bfloat16 bf16;
typedef __attribute__((ext_vector_type(8))) short short8;
typedef __attribute__((ext_vector_type(4))) short short4v;
typedef __attribute__((ext_vector_type(4))) float f32x4;
typedef __attribute__((ext_vector_type(4))) int   int4v;

__device__ inline float b2f_bits(short s) {
    union { unsigned u; float f; } uf;
    uf.u = ((unsigned)(unsigned short)s) << 16;
    return uf.f;
}
__device__ inline short f2b_bits(float x) {
    union { __hip_bfloat16 h; short s; } u;
    u.h = __float2bfloat16(x);
    return u.s;
}
// split f32 -> (hi, lo) bf16 pair; x ~= hi + lo with ~2^-17 relative residual
__device__ inline void split_bf16(float x, short& hi, short& lo) {
    hi = f2b_bits(x);
    lo = f2b_bits(x - b2f_bits(hi));
}
__device__ inline int pack_split(float x) {
    short h, l;
    split_bf16(x, h, l);
    return (int)((unsigned short)h | ((unsigned)(unsigned short)l << 16));
}
__device__ inline float unpack_f32(int w) {
    return b2f_bits((short)(w & 0xffff)) + b2f_bits((short)(((unsigned)w) >> 16));
}
__device__ inline void unpack8(int4v a, int4v b, short8& h, short8& l) {
#pragma unroll
    for (int j = 0; j < 4; ++j) {
        h[j]     = (short)(a[j] & 0xffff);
        l[j]     = (short)(((unsigned)a[j]) >> 16);
        h[4 + j] = (short)(b[j] & 0xffff);
        l[4 + j] = (short)(((unsigned)b[j]) >> 16);
    }
}
// XOR-swizzled LDS index (short units): row-major [rows][64], 16B granules
__device__ inline int swz64(int row, int g) {
    return row * 64 + ((g ^ (row & 7)) << 3);
}
__device__ inline int swz128(int row, int g) {
    return row * 128 + ((g ^ (row & 15)) << 3);
}

// ---------------- weights f32 -> hi/lo bf16 planes ----------------
__global__ __launch_bounds__(256) void k_split_w(const float* __restrict__ w,
                                                 short* __restrict__ wh,
                                                 short* __restrict__ wl, int n4) {
    int i = blockIdx.x * 256 + threadIdx.x;
    if (i < n4) {
        f32x4 v = *(const f32x4*)&w[i * 4];
        short4v h, l;
#pragma unroll
        for (int j = 0; j < 4; ++j) {
            short hh, ll;
            split_bf16(v[j], hh, ll);
            h[j] = hh;
            l[j] = ll;
        }
        *(short4v*)&wh[i * 4] = h;
        *(short4v*)&wl[i * 4] = l;
    }
}

// ---------------- [C][N] -> [N][C] transpose into packed int ----------------
template <bool FROM_F32>
__global__ __launch_bounds__(256) void k_transpose_pack(const void* __restrict__ in_,
                                                        int* __restrict__ out,
                                                        long in_bstride, long out_bstride) {
    __shared__ int tile[64][65];
    int b = blockIdx.z;
    int c0 = blockIdx.y * 64, n0 = blockIdx.x * 64;
    int t = threadIdx.x;
#pragma unroll
    for (int p = 0; p < 4; ++p) {
        int id = p * 256 + t;
        int r = id >> 4, c4 = (id & 15) * 4;
        if constexpr (FROM_F32) {
            const float* ip = (const float*)in_ + (long)b * in_bstride;
            f32x4 v = *(const f32x4*)&ip[(long)(c0 + r) * HW + n0 + c4];
#pragma unroll
            for (int j = 0; j < 4; ++j) tile[r][c4 + j] = pack_split(v[j]);
        } else {
            const int* ip = (const int*)in_ + (long)b * in_bstride;
            int4v v = *(const int4v*)&ip[(long)(c0 + r) * HW + n0 + c4];
#pragma unroll
            for (int j = 0; j < 4; ++j) tile[r][c4 + j] = v[j];
        }
    }
    __syncthreads();
    int col = t & 63, rr = t >> 6;
    int* op = out + (long)b * out_bstride;
#pragma unroll
    for (int p = 0; p < 16; ++p) {
        int r = p * 4 + rr;
        op[(long)(n0 + r) * CHN + c0 + col] = tile[col][r];
    }
}

// ---------------- GEMM: C[b] = A (MxK planes) * B[b]^T (NxK packed), 3-pass ----------------
template <bool OUT_SPLIT>
__global__ __launch_bounds__(256) void k_gemm_pp(const short* __restrict__ Ah,
                                                 const short* __restrict__ Al,
                                                 const int* __restrict__ B,
                                                 void* __restrict__ Cv,
                                                 int M, int N, int K,
                                                 long bB, long bC) {
    __shared__ short sAh[128 * 64], sAl[128 * 64], sBh[128 * 64], sBl[128 * 64];
    int b = blockIdx.z;
    int m0 = blockIdx.y * 128, n0 = blockIdx.x * 128;
    const int* Bp = B + (long)b * bB;
    int t = threadIdx.x, wid = t >> 6, lane = t & 63;
    int wr = (wid >> 1) * 64, wc = (wid & 1) * 64;
    int lrow = lane & 15, khalf = lane >> 4;
    f32x4 acc[4][4] = {};
    for (int kt = 0; kt < K; kt += 64) {
#pragma unroll
        for (int p = 0; p < 4; ++p) {
            int id = p * 256 + t, row = id >> 3, g = id & 7;
            int off = swz64(row, g);
            *(short8*)&sAh[off] = *(const short8*)&Ah[(long)(m0 + row) * K + kt + g * 8];
            *(short8*)&sAl[off] = *(const short8*)&Al[(long)(m0 + row) * K + kt + g * 8];
        }
#pragma unroll
        for (int p = 0; p < 4; ++p) {
            int id = p * 256 + t, row = id >> 3, g = id & 7;
            const int* src = &Bp[(long)(n0 + row) * K + kt + g * 8];
            int4v w0 = *(const int4v*)src;
            int4v w1 = *(const int4v*)(src + 4);
            short8 h, l;
            unpack8(w0, w1, h, l);
            int off = swz64(row, g);
            *(short8*)&sBh[off] = h;
            *(short8*)&sBl[off] = l;
        }
        __syncthreads();
#pragma unroll
        for (int ks = 0; ks < 2; ++ks) {
            int gk = ks * 4 + khalf;
            short8 ah[4], al[4], bh[4], bl[4];
#pragma unroll
            for (int i = 0; i < 4; ++i) {
                ah[i] = *(const short8*)&sAh[swz64(wr + i * 16 + lrow, gk)];
                al[i] = *(const short8*)&sAl[swz64(wr + i * 16 + lrow, gk)];
                bh[i] = *(const short8*)&sBh[swz64(wc + i * 16 + lrow, gk)];
                bl[i] = *(const short8*)&sBl[swz64(wc + i * 16 + lrow, gk)];
            }
#pragma unroll
            for (int mi = 0; mi < 4; ++mi)
#pragma unroll
                for (int ni = 0; ni < 4; ++ni) {
                    acc[mi][ni] = __builtin_amdgcn_mfma_f32_16x16x32_bf16(
                        ah[mi], bh[ni], acc[mi][ni], 0, 0, 0);
                    acc[mi][ni] = __builtin_amdgcn_mfma_f32_16x16x32_bf16(
                        al[mi], bh[ni], acc[mi][ni], 0, 0, 0);
                    acc[mi][ni] = __builtin_amdgcn_mfma_f32_16x16x32_bf16(
                        ah[mi], bl[ni], acc[mi][ni], 0, 0, 0);
                }
        }
        __syncthreads();
    }
    int crow = (lane >> 4) * 4, ccol = lane & 15;
#pragma unroll
    for (int mi = 0; mi < 4; ++mi)
#pragma unroll
        for (int ni = 0; ni < 4; ++ni)
#pragma unroll
            for (int r = 0; r < 4; ++r) {
                long row = m0 + wr + mi * 16 + crow + r;
                long col = n0 + wc + ni * 16 + ccol;
                if constexpr (OUT_SPLIT)
                    ((int*)Cv)[(long)b * bC + row * N + col] = pack_split(acc[mi][ni][r]);
                else
                    ((float*)Cv)[(long)b * bC + row * N + col] = acc[mi][ni][r];
            }
}

// ---------------- fused depthwise 3x3 SAME + (q,k) L2-norm, packed in-place ----------------
__global__ __launch_bounds__(256) void k_dwl2_pp(int* __restrict__ qkv,
                                                 const float* __restrict__ w) {
    __shared__ float img[64][68];
    __shared__ float red[4];
    int ch = blockIdx.x, b = blockIdx.y;
    bool is_qk = ch < 1024;
    int* p = qkv + ((long)b * C3 + ch) * HW;
    float w9[9];
#pragma unroll
    for (int i = 0; i < 9; ++i) w9[i] = w[ch * 9 + i];
    int t = threadIdx.x;
#pragma unroll
    for (int pp = 0; pp < 2; ++pp) {
        int u = pp * 256 + t, y = u >> 3, x8 = (u & 7) * 8;
        const int* src = &p[y * 64 + x8];
        int4v w0 = *(const int4v*)src;
        int4v w1 = *(const int4v*)(src + 4);
#pragma unroll
        for (int j = 0; j < 4; ++j) {
            img[y][x8 + j]     = unpack_f32(w0[j]);
            img[y][x8 + 4 + j] = unpack_f32(w1[j]);
        }
    }
    __syncthreads();
    float fv[2][8];
#pragma unroll
    for (int pp = 0; pp < 2; ++pp) {
        int u = pp * 256 + t, y = u >> 3, x8 = (u & 7) * 8;
#pragma unroll
        for (int j = 0; j < 8; ++j) {
            int xx = x8 + j;
            float s = 0.f;
#pragma unroll
            for (int dy = -1; dy <= 1; ++dy) {
                int yy = y + dy;
                if (yy < 0 || yy > 63) continue;
#pragma unroll
                for (int dx = -1; dx <= 1; ++dx) {
                    int xxx = xx + dx;
                    if (xxx < 0 || xxx > 63) continue;
                    s += img[yy][xxx] * w9[(dy + 1) * 3 + (dx + 1)];
                }
            }
            fv[pp][j] = s;
        }
    }
    float ss = 0.f;
#pragma unroll
    for (int pp = 0; pp < 2; ++pp)
#pragma unroll
        for (int j = 0; j < 8; ++j) ss += fv[pp][j] * fv[pp][j];
#pragma unroll
    for (int o = 32; o; o >>= 1) ss += __shfl_xor(ss, o);
    if ((t & 63) == 0) red[t >> 6] = ss;
    __syncthreads();
    float tot = red[0] + red[1] + red[2] + red[3];
    float sc = is_qk ? (1.f / fmaxf(sqrtf(tot), 1e-12f)) : 1.f;
#pragma unroll
    for (int pp = 0; pp < 2; ++pp) {
        int u = pp * 256 + t, y = u >> 3, x8 = (u & 7) * 8;
        int4v o0, o1;
#pragma unroll
        for (int j = 0; j < 4; ++j) {
            o0[j] = pack_split(fv[pp][j] * sc);
            o1[j] = pack_split(fv[pp][4 + j] * sc);
        }
        *(int4v*)&p[y * 64 + x8]     = o0;
        *(int4v*)&p[y * 64 + x8 + 4] = o1;
    }
}

// ---------------- attn partials: per (h, kslice, b): q(64xK) * k(64xK)^T, 3-pass ----------------
__global__ __launch_bounds__(256) void k_attn_pp(const int* __restrict__ qkv,
                                                 float* __restrict__ attn_part) {
    __shared__ short sQh[64 * 128], sQl[64 * 128], sKh[64 * 128], sKl[64 * 128];
    int h = blockIdx.x, ksl = blockIdx.y, b = blockIdx.z;
    const int* qb = qkv + ((long)b * C3 + h * 64) * HW;
    const int* kb = qb + (long)512 * HW;
    int t = threadIdx.x, wid = t >> 6, lane = t & 63;
    int lrow = lane & 15, khalf = lane >> 4;
    f32x4 acc[4] = {};
    for (int kt = ksl * 512; kt < ksl * 512 + 512; kt += 128) {
#pragma unroll
        for (int p = 0; p < 4; ++p) {
            int id = p * 256 + t, row = id >> 4, g = id & 15;
            int off = swz128(row, g);
            {
                const int* s = &qb[(long)row * HW + kt + g * 8];
                int4v w0 = *(const int4v*)s, w1 = *(const int4v*)(s + 4);
                short8 hh, ll;
                unpack8(w0, w1, hh, ll);
                *(short8*)&sQh[off] = hh;
                *(short8*)&sQl[off] = ll;
            }
            {
                const int* s = &kb[(long)row * HW + kt + g * 8];
                int4v w0 = *(const int4v*)s, w1 = *(const int4v*)(s + 4);
                short8 hh, ll;
                unpack8(w0, w1, hh, ll);
                *(short8*)&sKh[off] = hh;
                *(short8*)&sKl[off] = ll;
            }
        }
        __syncthreads();
#pragma unroll
        for (int ks = 0; ks < 4; ++ks) {
            int gk = ks * 4 + khalf;
            short8 kh = *(const short8*)&sKh[swz128(wid * 16 + lrow, gk)];
            short8 kl = *(const short8*)&sKl[swz128(wid * 16 + lrow, gk)];
#pragma unroll
            for (int mi = 0; mi < 4; ++mi) {
                short8 qh = *(const short8*)&sQh[swz128(mi * 16 + lrow, gk)];
                short8 ql = *(const short8*)&sQl[swz128(mi * 16 + lrow, gk)];
                acc[mi] = __builtin_amdgcn_mfma_f32_16x16x32_bf16(qh, kh, acc[mi], 0, 0, 0);
                acc[mi] = __builtin_amdgcn_mfma_f32_16x16x32_bf16(ql, kh, acc[mi], 0, 0, 0);
                acc[mi] = __builtin_amdgcn_mfma_f32_16x16x32_bf16(qh, kl, acc[mi], 0, 0, 0);
            }
        }
        __syncthreads();
    }
    float* op = attn_part + (((long)b * 8 + ksl) * 8 + h) * 4096;
    int crow = (lane >> 4) * 4, ccol = lane & 15;
#pragma unroll
    for (int mi = 0; mi < 4; ++mi)
#pragma unroll
        for (int r = 0; r < 4; ++r)
            op[(mi * 16 + crow + r) * 64 + wid * 16 + ccol] = acc[mi][r];
}

// ---------------- fused 4x top-k masked softmax combine -> Wc (f32) ----------------
__global__ __launch_bounds__(256) void k_smcomb(const float* __restrict__ attn_part,
                                                const float* __restrict__ temp,
                                                const float* __restrict__ a1,
                                                const float* __restrict__ a2,
                                                const float* __restrict__ a3,
                                                const float* __restrict__ a4,
                                                float* __restrict__ Wc) {
    int t = threadIdx.x, wid = t >> 6, lane = t & 63;
    int b = blockIdx.z;
    int r = blockIdx.x * 4 + wid;   // (h, qrow) 0..511
    int h = r >> 6, qr = r & 63;
    float a = 0.f;
#pragma unroll
    for (int s = 0; s < 8; ++s)
        a += attn_part[(((long)b * 8 + s) * 8 + h) * 4096 + qr * 64 + lane];
    a *= temp[h];
    int cnt = 0;
#pragma unroll
    for (int j = 0; j < 64; ++j) {
        float aj = __shfl(a, j);
        cnt += (aj > a) ? 1 : 0;
    }
    float m = a;
#pragma unroll
    for (int o = 32; o; o >>= 1) m = fmaxf(m, __shfl_xor(m, o));
    float e = expf(a - m);
    const int kk[4] = {32, 42, 48, 51};
    float coef[4] = {a1[0], a2[0], a3[0], a4[0]};
    float out = 0.f;
#pragma unroll
    for (int i = 0; i < 4; ++i) {
        float ei = (cnt < kk[i]) ? e : 0.f;
        float d = ei;
#pragma unroll
        for (int o = 32; o; o >>= 1) d += __shfl_xor(d, o);
        out += coef[i] * ei / d;
    }
    Wc[((long)b * 8 + h) * 4096 + qr * 64 + lane] = out;
}

// ---------------- attT[n][c] = sum_d vT[n][d] * Wc[c][d], 3-pass, packed out ----------------
__global__ __launch_bounds__(256) void k_wv_pp(const float* __restrict__ Wc,
                                               const int* __restrict__ vT,
                                               int* __restrict__ attT) {
    __shared__ short sVh[128 * 64], sVl[128 * 64];
    __shared__ short sWh[64 * 64], sWl[64 * 64];
    int nb = blockIdx.x, h = blockIdx.y, b = blockIdx.z;
    int n0 = nb * 128;
    const float* wp = Wc + ((long)b * 8 + h) * 4096;
    const int* vp = vT + (long)b * ((long)HW * CHN) + (long)n0 * CHN + h * 64;
    int t = threadIdx.x, wid = t >> 6, lane = t & 63;
    int lrow = lane & 15, khalf = lane >> 4;
#pragma unroll
    for (int p = 0; p < 4; ++p) {
        int id = p * 256 + t, row = id >> 3, g = id & 7;
        const int* src = &vp[(long)row * CHN + g * 8];
        int4v w0 = *(const int4v*)src, w1 = *(const int4v*)(src + 4);
        short8 hh, ll;
        unpack8(w0, w1, hh, ll);
        int off = swz64(row, g);
        *(short8*)&sVh[off] = hh;
        *(short8*)&sVl[off] = ll;
    }
#pragma unroll
    for (int p = 0; p < 2; ++p) {
        int id = p * 256 + t, row = id >> 3, g = id & 7;
        f32x4 va = *(const f32x4*)&wp[row * 64 + g * 8];
        f32x4 vb = *(const f32x4*)&wp[row * 64 + g * 8 + 4];
        short8 hh, ll;
#pragma unroll
        for (int j = 0; j < 4; ++j) {
            short h0, l0, h1, l1;
            split_bf16(va[j], h0, l0);
            split_bf16(vb[j], h1, l1);
            hh[j] = h0;     ll[j] = l0;
            hh[4 + j] = h1; ll[4 + j] = l1;
        }
        int off = swz64(row, g);
        *(short8*)&sWh[off] = hh;
        *(short8*)&sWl[off] = ll;
    }
    __syncthreads();
    f32x4 acc[2][4] = {};
#pragma unroll
    for (int ks = 0; ks < 2; ++ks) {
        int gk = ks * 4 + khalf;
        short8 vh[2], vl[2], wh[4], wl[4];
#pragma unroll
        for (int i = 0; i < 2; ++i) {
            int rr = wid * 32 + i * 16 + lrow;
            vh[i] = *(const short8*)&sVh[swz64(rr, gk)];
            vl[i] = *(const short8*)&sVl[swz64(rr, gk)];
        }
#pragma unroll
        for (int i = 0; i < 4; ++i) {
            int rr = i * 16 + lrow;
            wh[i] = *(const short8*)&sWh[swz64(rr, gk)];
            wl[i] = *(const short8*)&sWl[swz64(rr, gk)];
        }
#pragma unroll
        for (int mi = 0; mi < 2; ++mi)
#pragma unroll
            for (int ni = 0; ni < 4; ++ni) {
                acc[mi][ni] = __builtin_amdgcn_mfma_f32_16x16x32_bf16(
                    vh[mi], wh[ni], acc[mi][ni], 0, 0, 0);
                acc[mi][ni] = __builtin_amdgcn_mfma_f32_16x16x32_bf16(
                    vl[mi], wh[ni], acc[mi][ni], 0, 0, 0);
                acc[mi][ni] = __builtin_amdgcn_mfma_f32_16x16x32_bf16(
                    vh[mi], wl[ni], acc[mi][ni], 0, 0, 0);
            }
    }
    int* op = attT + (long)b * ((long)C3 * HW);
    int crow = (lane >> 4) * 4, ccol = lane & 15;
#pragma unroll
    for (int mi = 0; mi < 2; ++mi)
#pragma unroll
        for (int ni = 0; ni < 4; ++ni)
#pragma unroll
            for (int r = 0; r < 4; ++r) {
                long n = n0 + wid * 32 + mi * 16 + crow + r;
                int c = h * 64 + ni * 16 + ccol;
                op[n * CHN + c] = pack_split(acc[mi][ni][r]);
            }
}

extern "C" void kernel_launch(void* const* d_in, const int* in_sizes, int n_in,
                              void* d_out, int out_size, void* d_ws, size_t ws_size,
                              hipStream_t stream) {
    const float* x      = (const float*)d_in[0];
    const float* qkv_w  = (const float*)d_in[1];
    const float* dw_w   = (const float*)d_in[2];
    const float* proj_w = (const float*)d_in[3];
    const float* temp   = (const float*)d_in[4];
    const float* a1     = (const float*)d_in[5];
    const float* a2     = (const float*)d_in[6];
    const float* a3     = (const float*)d_in[7];
    const float* a4     = (const float*)d_in[8];
    float* out = (float*)d_out;

    char* ws = (char*)d_ws;
    // layout (139,984,896 B total <= 141,033,472 proven in R1):
    //   0           qkvi: packed [GB][1536][4096] int (100,663,296 B);
    //               per-batch q-region reused as attT [4096][512] after attn
    //   100663296   xTi: packed [GB][4096][512] int (33,554,432 B); reused as vT
    //   134217728   REGION_A (4,194,304 B): wq planes (3 MB, per group) then attn_part
    //   138412032   Wc f32 [GB][8][64][64] (524,288 B)
    //   138936320   wph (524,288 B)
    //   139460608   wpl (524,288 B)
    int*   qkvi      = (int*)(ws);
    int*   xTi       = (int*)(ws + 100663296);
    short* wqh       = (short*)(ws + 134217728);
    short* wql       = (short*)(ws + 134217728 + 1572864);
    float* attn_part = (float*)(ws + 134217728);
    float* Wc        = (float*)(ws + 138412032);
    short* wph       = (short*)(ws + 138936320);
    short* wpl       = (short*)(ws + 139460608);

    k_split_w<<<256, 256, 0, stream>>>(proj_w, wph, wpl, 65536);

    for (int g = 0; g < 2; ++g) {
        const float* xg = x + (long)g * GB * CHN * HW;
        float* outg = out + (long)g * GB * CHN * HW;
        // 0. split qkv weights (region shared with attn_part; wq dead before attn)
        k_split_w<<<768, 256, 0, stream>>>(qkv_w, wqh, wql, 196608);
        // 1. x -> xTi packed [n][c]
        k_transpose_pack<true><<<dim3(64, 8, GB), 256, 0, stream>>>(
            xg, xTi, (long)CHN * HW, (long)HW * CHN);
        // 2. qkv = Wqkv * x  (M=1536, N=4096, K=512)
        k_gemm_pp<true><<<dim3(32, 12, GB), 256, 0, stream>>>(
            wqh, wql, xTi, qkvi, C3, HW, CHN, (long)HW * CHN, (long)C3 * HW);
        // 3. depthwise 3x3 + q,k L2-norm, in-place packed
        k_dwl2_pp<<<dim3(C3, GB), 256, 0, stream>>>(qkvi, dw_w);
        // 4. v -> vT packed [n][c] (into xTi; xT dead)
        k_transpose_pack<false><<<dim3(64, 8, GB), 256, 0, stream>>>(
            qkvi + (long)1024 * HW, xTi, (long)C3 * HW, (long)HW * CHN);
        // 5. attn partials (8 K-slices)
        k_attn_pp<<<dim3(8, 8, GB), 256, 0, stream>>>(qkvi, attn_part);
        // 6. fused top-k softmax combine
        k_smcomb<<<dim3(128, 1, GB), 256, 0, stream>>>(attn_part, temp, a1, a2, a3, a4, Wc);
        // 7. attT = (Wc * v)^T packed, into dead q-region of qkvi
        k_wv_pp<<<dim3(32, 8, GB), 256, 0, stream>>>(Wc, xTi, qkvi);
        // 8. out = Wproj * att  (M=512, N=4096, K=512), f32 out
        k_gemm_pp<false><<<dim3(32, 4, GB), 256, 0, stream>>>(
            wph, wpl, qkvi, outg, CHN, HW, CHN, (long)C3 * HW, (long)CHN * HW);
    }
}

// Round 6
// 364.770 us; speedup vs baseline: 3.2242x; 1.1735x over previous
//
#include <hip/hip_runtime.h>
#include <hip/hip_bf16.h>

#define CHN 512
#define HW  4096
#define C3  1536
#define GB  4   // batches per group

typedef __hip_bfloat16 bf16;
typedef __attribute__((ext_vector_type(8))) short short8;
typedef __attribute__((ext_vector_type(4))) short short4v;
typedef __attribute__((ext_vector_type(4))) float f32x4;
typedef __attribute__((ext_vector_type(4))) int   int4v;
typedef _Float16 h8_t __attribute__((ext_vector_type(8)));

__device__ inline float b2f_bits(short s) {
    union { unsigned u; float f; } uf;
    uf.u = ((unsigned)(unsigned short)s) << 16;
    return uf.f;
}
__device__ inline short f2b_bits(float x) {
    union { __hip_bfloat16 h; short s; } u;
    u.h = __float2bfloat16(x);
    return u.s;
}
// bf16 split (x ~= hi+lo, ~2^-17): used on the precision-critical q/k/v path
__device__ inline void split_bf16(float x, short& hi, short& lo) {
    hi = f2b_bits(x);
    lo = f2b_bits(x - b2f_bits(hi));
}
__device__ inline int pack_split(float x) {
    short h, l;
    split_bf16(x, h, l);
    return (int)((unsigned short)h | ((unsigned)(unsigned short)l << 16));
}
__device__ inline float unpack_f32(int w) {
    return b2f_bits((short)(w & 0xffff)) + b2f_bits((short)(((unsigned)w) >> 16));
}
__device__ inline void unpack8(int4v a, int4v b, short8& h, short8& l) {
#pragma unroll
    for (int j = 0; j < 4; ++j) {
        h[j]     = (short)(a[j] & 0xffff);
        l[j]     = (short)(((unsigned)a[j]) >> 16);
        h[4 + j] = (short)(b[j] & 0xffff);
        l[4 + j] = (short)(((unsigned)b[j]) >> 16);
    }
}
// f16 helpers (weight GEMMs, 2-pass): hi ~2^-12, hi+lo ~2^-24
__device__ inline short f2h_bits(float x) {
    _Float16 h = (_Float16)x;
    return __builtin_bit_cast(short, h);
}
__device__ inline void split_f16(float x, short& hi, short& lo) {
    _Float16 h = (_Float16)x;
    _Float16 l = (_Float16)(x - (float)h);
    hi = __builtin_bit_cast(short, h);
    lo = __builtin_bit_cast(short, l);
}
// XOR-swizzled LDS index (short units): row-major [rows][64], 16B granules
__device__ inline int swz64(int row, int g) {
    return row * 64 + ((g ^ (row & 7)) << 3);
}
__device__ inline int swz128(int row, int g) {
    return row * 128 + ((g ^ (row & 15)) << 3);
}

// ---------------- weights f32 -> hi/lo f16 planes ----------------
__global__ __launch_bounds__(256) void k_split_w(const float* __restrict__ w,
                                                 short* __restrict__ wh,
                                                 short* __restrict__ wl, int n4) {
    int i = blockIdx.x * 256 + threadIdx.x;
    if (i < n4) {
        f32x4 v = *(const f32x4*)&w[i * 4];
        short4v h, l;
#pragma unroll
        for (int j = 0; j < 4; ++j) {
            short hh, ll;
            split_f16(v[j], hh, ll);
            h[j] = hh;
            l[j] = ll;
        }
        *(short4v*)&wh[i * 4] = h;
        *(short4v*)&wl[i * 4] = l;
    }
}

// ---------------- x [C][N] f32 -> xT [N][C] f16 ----------------
__global__ __launch_bounds__(256) void k_transpose_xf16(const float* __restrict__ in,
                                                        short* __restrict__ out) {
    __shared__ float tile[64][65];
    int b = blockIdx.z;
    int c0 = blockIdx.y * 64, n0 = blockIdx.x * 64;
    const float* ip = in + (long)b * ((long)CHN * HW);
    short* op = out + (long)b * ((long)HW * CHN);
    int t = threadIdx.x;
#pragma unroll
    for (int p = 0; p < 4; ++p) {
        int id = p * 256 + t;
        int r = id >> 4, c4 = (id & 15) * 4;
        f32x4 v = *(const f32x4*)&ip[(long)(c0 + r) * HW + n0 + c4];
#pragma unroll
        for (int j = 0; j < 4; ++j) tile[r][c4 + j] = v[j];
    }
    __syncthreads();
    int col = t & 63, rr = t >> 6;
#pragma unroll
    for (int p = 0; p < 16; ++p) {
        int r = p * 4 + rr;
        op[(long)(n0 + r) * CHN + c0 + col] = f2h_bits(tile[col][r]);
    }
}

// ---------------- v [C][N] packed int -> vT [N][C] packed int ----------------
__global__ __launch_bounds__(256) void k_transpose_int(const int* __restrict__ in,
                                                       int* __restrict__ out,
                                                       long in_bstride, long out_bstride) {
    __shared__ int tile[64][65];
    int b = blockIdx.z;
    int c0 = blockIdx.y * 64, n0 = blockIdx.x * 64;
    const int* ip = in + (long)b * in_bstride;
    int* op = out + (long)b * out_bstride;
    int t = threadIdx.x;
#pragma unroll
    for (int p = 0; p < 4; ++p) {
        int id = p * 256 + t;
        int r = id >> 4, c4 = (id & 15) * 4;
        int4v v = *(const int4v*)&ip[(long)(c0 + r) * HW + n0 + c4];
#pragma unroll
        for (int j = 0; j < 4; ++j) tile[r][c4 + j] = v[j];
    }
    __syncthreads();
    int col = t & 63, rr = t >> 6;
#pragma unroll
    for (int p = 0; p < 16; ++p) {
        int r = p * 4 + rr;
        op[(long)(n0 + r) * CHN + c0 + col] = tile[col][r];
    }
}

// ---------------- GEMM: C[b] = A (MxK f16 planes, exact) * B[b]^T (NxK f16), 2-pass ----------------
template <bool OUT_SPLIT>
__global__ __launch_bounds__(256) void k_gemm_f16(const short* __restrict__ Ah,
                                                  const short* __restrict__ Al,
                                                  const short* __restrict__ B,
                                                  void* __restrict__ Cv,
                                                  int M, int N, int K,
                                                  long bB, long bC) {
    __shared__ short sAh[128 * 64], sAl[128 * 64], sB[128 * 64];
    int b = blockIdx.z;
    int m0 = blockIdx.y * 128, n0 = blockIdx.x * 128;
    const short* Bp = B + (long)b * bB;
    int t = threadIdx.x, wid = t >> 6, lane = t & 63;
    int wr = (wid >> 1) * 64, wc = (wid & 1) * 64;
    int lrow = lane & 15, khalf = lane >> 4;
    f32x4 acc[4][4] = {};
    for (int kt = 0; kt < K; kt += 64) {
#pragma unroll
        for (int p = 0; p < 4; ++p) {
            int id = p * 256 + t, row = id >> 3, g = id & 7;
            int off = swz64(row, g);
            *(short8*)&sAh[off] = *(const short8*)&Ah[(long)(m0 + row) * K + kt + g * 8];
            *(short8*)&sAl[off] = *(const short8*)&Al[(long)(m0 + row) * K + kt + g * 8];
        }
#pragma unroll
        for (int p = 0; p < 4; ++p) {
            int id = p * 256 + t, row = id >> 3, g = id & 7;
            *(short8*)&sB[swz64(row, g)] =
                *(const short8*)&Bp[(long)(n0 + row) * K + kt + g * 8];
        }
        __syncthreads();
#pragma unroll
        for (int ks = 0; ks < 2; ++ks) {
            int gk = ks * 4 + khalf;
            h8_t ah[4], al[4], bh[4];
#pragma unroll
            for (int i = 0; i < 4; ++i) {
                ah[i] = *(const h8_t*)&sAh[swz64(wr + i * 16 + lrow, gk)];
                al[i] = *(const h8_t*)&sAl[swz64(wr + i * 16 + lrow, gk)];
                bh[i] = *(const h8_t*)&sB[swz64(wc + i * 16 + lrow, gk)];
            }
#pragma unroll
            for (int mi = 0; mi < 4; ++mi)
#pragma unroll
                for (int ni = 0; ni < 4; ++ni) {
                    acc[mi][ni] = __builtin_amdgcn_mfma_f32_16x16x32_f16(
                        ah[mi], bh[ni], acc[mi][ni], 0, 0, 0);
                    acc[mi][ni] = __builtin_amdgcn_mfma_f32_16x16x32_f16(
                        al[mi], bh[ni], acc[mi][ni], 0, 0, 0);
                }
        }
        __syncthreads();
    }
    int crow = (lane >> 4) * 4, ccol = lane & 15;
#pragma unroll
    for (int mi = 0; mi < 4; ++mi)
#pragma unroll
        for (int ni = 0; ni < 4; ++ni)
#pragma unroll
            for (int r = 0; r < 4; ++r) {
                long row = m0 + wr + mi * 16 + crow + r;
                long col = n0 + wc + ni * 16 + ccol;
                if constexpr (OUT_SPLIT)
                    ((int*)Cv)[(long)b * bC + row * N + col] = pack_split(acc[mi][ni][r]);
                else
                    ((float*)Cv)[(long)b * bC + row * N + col] = acc[mi][ni][r];
            }
}

// ---------------- fused depthwise 3x3 SAME + (q,k) L2-norm, packed bf16-pair in-place ----------------
__global__ __launch_bounds__(256) void k_dwl2_pp(int* __restrict__ qkv,
                                                 const float* __restrict__ w) {
    __shared__ float img[64][68];
    __shared__ float red[4];
    int ch = blockIdx.x, b = blockIdx.y;
    bool is_qk = ch < 1024;
    int* p = qkv + ((long)b * C3 + ch) * HW;
    float w9[9];
#pragma unroll
    for (int i = 0; i < 9; ++i) w9[i] = w[ch * 9 + i];
    int t = threadIdx.x;
#pragma unroll
    for (int pp = 0; pp < 2; ++pp) {
        int u = pp * 256 + t, y = u >> 3, x8 = (u & 7) * 8;
        const int* src = &p[y * 64 + x8];
        int4v w0 = *(const int4v*)src;
        int4v w1 = *(const int4v*)(src + 4);
#pragma unroll
        for (int j = 0; j < 4; ++j) {
            img[y][x8 + j]     = unpack_f32(w0[j]);
            img[y][x8 + 4 + j] = unpack_f32(w1[j]);
        }
    }
    __syncthreads();
    float fv[2][8];
#pragma unroll
    for (int pp = 0; pp < 2; ++pp) {
        int u = pp * 256 + t, y = u >> 3, x8 = (u & 7) * 8;
#pragma unroll
        for (int j = 0; j < 8; ++j) {
            int xx = x8 + j;
            float s = 0.f;
#pragma unroll
            for (int dy = -1; dy <= 1; ++dy) {
                int yy = y + dy;
                if (yy < 0 || yy > 63) continue;
#pragma unroll
                for (int dx = -1; dx <= 1; ++dx) {
                    int xxx = xx + dx;
                    if (xxx < 0 || xxx > 63) continue;
                    s += img[yy][xxx] * w9[(dy + 1) * 3 + (dx + 1)];
                }
            }
            fv[pp][j] = s;
        }
    }
    float ss = 0.f;
#pragma unroll
    for (int pp = 0; pp < 2; ++pp)
#pragma unroll
        for (int j = 0; j < 8; ++j) ss += fv[pp][j] * fv[pp][j];
#pragma unroll
    for (int o = 32; o; o >>= 1) ss += __shfl_xor(ss, o);
    if ((t & 63) == 0) red[t >> 6] = ss;
    __syncthreads();
    float tot = red[0] + red[1] + red[2] + red[3];
    float sc = is_qk ? (1.f / fmaxf(sqrtf(tot), 1e-12f)) : 1.f;
#pragma unroll
    for (int pp = 0; pp < 2; ++pp) {
        int u = pp * 256 + t, y = u >> 3, x8 = (u & 7) * 8;
        int4v o0, o1;
#pragma unroll
        for (int j = 0; j < 4; ++j) {
            o0[j] = pack_split(fv[pp][j] * sc);
            o1[j] = pack_split(fv[pp][4 + j] * sc);
        }
        *(int4v*)&p[y * 64 + x8]     = o0;
        *(int4v*)&p[y * 64 + x8 + 4] = o1;
    }
}

// ---------------- attn partials: per (h, kslice, b): q(64xK)*k(64xK)^T, bf16 3-pass ----------------
__global__ __launch_bounds__(256) void k_attn_pp(const int* __restrict__ qkv,
                                                 float* __restrict__ attn_part) {
    __shared__ short sQh[64 * 128], sQl[64 * 128], sKh[64 * 128], sKl[64 * 128];
    int h = blockIdx.x, ksl = blockIdx.y, b = blockIdx.z;
    const int* qb = qkv + ((long)b * C3 + h * 64) * HW;
    const int* kb = qb + (long)512 * HW;
    int t = threadIdx.x, wid = t >> 6, lane = t & 63;
    int lrow = lane & 15, khalf = lane >> 4;
    f32x4 acc[4] = {};
    for (int kt = ksl * 512; kt < ksl * 512 + 512; kt += 128) {
#pragma unroll
        for (int p = 0; p < 4; ++p) {
            int id = p * 256 + t, row = id >> 4, g = id & 15;
            int off = swz128(row, g);
            {
                const int* s = &qb[(long)row * HW + kt + g * 8];
                int4v w0 = *(const int4v*)s, w1 = *(const int4v*)(s + 4);
                short8 hh, ll;
                unpack8(w0, w1, hh, ll);
                *(short8*)&sQh[off] = hh;
                *(short8*)&sQl[off] = ll;
            }
            {
                const int* s = &kb[(long)row * HW + kt + g * 8];
                int4v w0 = *(const int4v*)s, w1 = *(const int4v*)(s + 4);
                short8 hh, ll;
                unpack8(w0, w1, hh, ll);
                *(short8*)&sKh[off] = hh;
                *(short8*)&sKl[off] = ll;
            }
        }
        __syncthreads();
#pragma unroll
        for (int ks = 0; ks < 4; ++ks) {
            int gk = ks * 4 + khalf;
            short8 kh = *(const short8*)&sKh[swz128(wid * 16 + lrow, gk)];
            short8 kl = *(const short8*)&sKl[swz128(wid * 16 + lrow, gk)];
#pragma unroll
            for (int mi = 0; mi < 4; ++mi) {
                short8 qh = *(const short8*)&sQh[swz128(mi * 16 + lrow, gk)];
                short8 ql = *(const short8*)&sQl[swz128(mi * 16 + lrow, gk)];
                acc[mi] = __builtin_amdgcn_mfma_f32_16x16x32_bf16(qh, kh, acc[mi], 0, 0, 0);
                acc[mi] = __builtin_amdgcn_mfma_f32_16x16x32_bf16(ql, kh, acc[mi], 0, 0, 0);
                acc[mi] = __builtin_amdgcn_mfma_f32_16x16x32_bf16(qh, kl, acc[mi], 0, 0, 0);
            }
        }
        __syncthreads();
    }
    float* op = attn_part + (((long)b * 8 + ksl) * 8 + h) * 4096;
    int crow = (lane >> 4) * 4, ccol = lane & 15;
#pragma unroll
    for (int mi = 0; mi < 4; ++mi)
#pragma unroll
        for (int r = 0; r < 4; ++r)
            op[(mi * 16 + crow + r) * 64 + wid * 16 + ccol] = acc[mi][r];
}

// ---------------- fused 4x top-k masked softmax combine -> Wc (f32) ----------------
__global__ __launch_bounds__(256) void k_smcomb(const float* __restrict__ attn_part,
                                                const float* __restrict__ temp,
                                                const float* __restrict__ a1,
                                                const float* __restrict__ a2,
                                                const float* __restrict__ a3,
                                                const float* __restrict__ a4,
                                                float* __restrict__ Wc) {
    int t = threadIdx.x, wid = t >> 6, lane = t & 63;
    int b = blockIdx.z;
    int r = blockIdx.x * 4 + wid;   // (h, qrow) 0..511
    int h = r >> 6, qr = r & 63;
    float a = 0.f;
#pragma unroll
    for (int s = 0; s < 8; ++s)
        a += attn_part[(((long)b * 8 + s) * 8 + h) * 4096 + qr * 64 + lane];
    a *= temp[h];
    int cnt = 0;
#pragma unroll
    for (int j = 0; j < 64; ++j) {
        float aj = __shfl(a, j);
        cnt += (aj > a) ? 1 : 0;
    }
    float m = a;
#pragma unroll
    for (int o = 32; o; o >>= 1) m = fmaxf(m, __shfl_xor(m, o));
    float e = expf(a - m);
    const int kk[4] = {32, 42, 48, 51};
    float coef[4] = {a1[0], a2[0], a3[0], a4[0]};
    float out = 0.f;
#pragma unroll
    for (int i = 0; i < 4; ++i) {
        float ei = (cnt < kk[i]) ? e : 0.f;
        float d = ei;
#pragma unroll
        for (int o = 32; o; o >>= 1) d += __shfl_xor(d, o);
        out += coef[i] * ei / d;
    }
    Wc[((long)b * 8 + h) * 4096 + qr * 64 + lane] = out;
}

// ---------------- attT[n][c] = sum_d vT[n][d]*Wc[c][d], bf16 3-pass, f16 out ----------------
__global__ __launch_bounds__(256) void k_wv_pp(const float* __restrict__ Wc,
                                               const int* __restrict__ vT,
                                               short* __restrict__ attTs) {
    __shared__ short sVh[128 * 64], sVl[128 * 64];
    __shared__ short sWh[64 * 64], sWl[64 * 64];
    int nb = blockIdx.x, h = blockIdx.y, b = blockIdx.z;
    int n0 = nb * 128;
    const float* wp = Wc + ((long)b * 8 + h) * 4096;
    const int* vp = vT + (long)b * ((long)HW * CHN) + (long)n0 * CHN + h * 64;
    int t = threadIdx.x, wid = t >> 6, lane = t & 63;
    int lrow = lane & 15, khalf = lane >> 4;
#pragma unroll
    for (int p = 0; p < 4; ++p) {
        int id = p * 256 + t, row = id >> 3, g = id & 7;
        const int* src = &vp[(long)row * CHN + g * 8];
        int4v w0 = *(const int4v*)src, w1 = *(const int4v*)(src + 4);
        short8 hh, ll;
        unpack8(w0, w1, hh, ll);
        int off = swz64(row, g);
        *(short8*)&sVh[off] = hh;
        *(short8*)&sVl[off] = ll;
    }
#pragma unroll
    for (int p = 0; p < 2; ++p) {
        int id = p * 256 + t, row = id >> 3, g = id & 7;
        f32x4 va = *(const f32x4*)&wp[row * 64 + g * 8];
        f32x4 vb = *(const f32x4*)&wp[row * 64 + g * 8 + 4];
        short8 hh, ll;
#pragma unroll
        for (int j = 0; j < 4; ++j) {
            short h0, l0, h1, l1;
            split_bf16(va[j], h0, l0);
            split_bf16(vb[j], h1, l1);
            hh[j] = h0;     ll[j] = l0;
            hh[4 + j] = h1; ll[4 + j] = l1;
        }
        int off = swz64(row, g);
        *(short8*)&sWh[off] = hh;
        *(short8*)&sWl[off] = ll;
    }
    __syncthreads();
    f32x4 acc[2][4] = {};
#pragma unroll
    for (int ks = 0; ks < 2; ++ks) {
        int gk = ks * 4 + khalf;
        short8 vh[2], vl[2], wh[4], wl[4];
#pragma unroll
        for (int i = 0; i < 2; ++i) {
            int rr = wid * 32 + i * 16 + lrow;
            vh[i] = *(const short8*)&sVh[swz64(rr, gk)];
            vl[i] = *(const short8*)&sVl[swz64(rr, gk)];
        }
#pragma unroll
        for (int i = 0; i < 4; ++i) {
            int rr = i * 16 + lrow;
            wh[i] = *(const short8*)&sWh[swz64(rr, gk)];
            wl[i] = *(const short8*)&sWl[swz64(rr, gk)];
        }
#pragma unroll
        for (int mi = 0; mi < 2; ++mi)
#pragma unroll
            for (int ni = 0; ni < 4; ++ni) {
                acc[mi][ni] = __builtin_amdgcn_mfma_f32_16x16x32_bf16(
                    vh[mi], wh[ni], acc[mi][ni], 0, 0, 0);
                acc[mi][ni] = __builtin_amdgcn_mfma_f32_16x16x32_bf16(
                    vl[mi], wh[ni], acc[mi][ni], 0, 0, 0);
                acc[mi][ni] = __builtin_amdgcn_mfma_f32_16x16x32_bf16(
                    vh[mi], wl[ni], acc[mi][ni], 0, 0, 0);
            }
    }
    short* op = attTs + (long)b * ((long)C3 * HW * 2);
    int crow = (lane >> 4) * 4, ccol = lane & 15;
#pragma unroll
    for (int mi = 0; mi < 2; ++mi)
#pragma unroll
        for (int ni = 0; ni < 4; ++ni)
#pragma unroll
            for (int r = 0; r < 4; ++r) {
                long n = n0 + wid * 32 + mi * 16 + crow + r;
                int c = h * 64 + ni * 16 + ccol;
                op[n * CHN + c] = f2h_bits(acc[mi][ni][r]);
            }
}

extern "C" void kernel_launch(void* const* d_in, const int* in_sizes, int n_in,
                              void* d_out, int out_size, void* d_ws, size_t ws_size,
                              hipStream_t stream) {
    const float* x      = (const float*)d_in[0];
    const float* qkv_w  = (const float*)d_in[1];
    const float* dw_w   = (const float*)d_in[2];
    const float* proj_w = (const float*)d_in[3];
    const float* temp   = (const float*)d_in[4];
    const float* a1     = (const float*)d_in[5];
    const float* a2     = (const float*)d_in[6];
    const float* a3     = (const float*)d_in[7];
    const float* a4     = (const float*)d_in[8];
    float* out = (float*)d_out;

    char* ws = (char*)d_ws;
    // layout (139,984,896 B total, proven safe):
    //   0           qkvi: packed bf16-pair [GB][1536][4096] int (100,663,296 B);
    //               per-batch q-region reused as attT f16 [4096][512] after attn
    //   100663296   vT region (33,554,432 B): xTs f16 [GB][4096][512] (16 MB, steps 1-2),
    //               then vT packed int [GB][4096][512] (32 MB, steps 4-7)
    //   134217728   REGION_A (4,194,304 B): wq f16 planes (3 MB) then attn_part f32
    //   138412032   Wc f32 [GB][8][64][64] (524,288 B)
    //   138936320   wph (524,288 B)
    //   139460608   wpl (524,288 B)
    int*   qkvi      = (int*)(ws);
    short* xTs       = (short*)(ws + 100663296);
    int*   vT        = (int*)(ws + 100663296);
    short* wqh       = (short*)(ws + 134217728);
    short* wql       = (short*)(ws + 134217728 + 1572864);
    float* attn_part = (float*)(ws + 134217728);
    float* Wc        = (float*)(ws + 138412032);
    short* wph       = (short*)(ws + 138936320);
    short* wpl       = (short*)(ws + 139460608);

    k_split_w<<<256, 256, 0, stream>>>(proj_w, wph, wpl, 65536);

    for (int g = 0; g < 2; ++g) {
        const float* xg = x + (long)g * GB * CHN * HW;
        float* outg = out + (long)g * GB * CHN * HW;
        // 0. split qkv weights to f16 planes (region shared with attn_part)
        k_split_w<<<768, 256, 0, stream>>>(qkv_w, wqh, wql, 196608);
        // 1. x -> xTs f16 [n][c]
        k_transpose_xf16<<<dim3(64, 8, GB), 256, 0, stream>>>(xg, xTs);
        // 2. qkv = Wqkv * x  (M=1536, N=4096, K=512), 2-pass f16 -> bf16-pair out
        k_gemm_f16<true><<<dim3(32, 12, GB), 256, 0, stream>>>(
            wqh, wql, xTs, qkvi, C3, HW, CHN, (long)HW * CHN, (long)C3 * HW);
        // 3. depthwise 3x3 + q,k L2-norm, in-place packed bf16-pair
        k_dwl2_pp<<<dim3(C3, GB), 256, 0, stream>>>(qkvi, dw_w);
        // 4. v -> vT packed int [n][c] (overwrites dead xTs)
        k_transpose_int<<<dim3(64, 8, GB), 256, 0, stream>>>(
            qkvi + (long)1024 * HW, vT, (long)C3 * HW, (long)HW * CHN);
        // 5. attn partials (8 K-slices), exact bf16 3-pass
        k_attn_pp<<<dim3(8, 8, GB), 256, 0, stream>>>(qkvi, attn_part);
        // 6. fused top-k softmax combine
        k_smcomb<<<dim3(128, 1, GB), 256, 0, stream>>>(attn_part, temp, a1, a2, a3, a4, Wc);
        // 7. attT f16 = (Wc * v)^T, into dead q-region of qkvi
        k_wv_pp<<<dim3(32, 8, GB), 256, 0, stream>>>(Wc, vT, (short*)qkvi);
        // 8. out = Wproj * att  (M=512, N=4096, K=512), 2-pass f16, f32 out
        k_gemm_f16<false><<<dim3(32, 4, GB), 256, 0, stream>>>(
            wph, wpl, (const short*)qkvi, outg, CHN, HW, CHN,
            (long)C3 * HW * 2, (long)CHN * HW);
    }
}

// Round 7
// 364.719 us; speedup vs baseline: 3.2246x; 1.0001x over previous
//
#include <hip/hip_runtime.h>
#include <hip/hip_bf16.h>

#define CHN 512
#define HW  4096
#define C3  1536
#define GB  4   // batches per group

typedef __hip_bfloat16 bf16;
typedef __attribute__((ext_vector_type(8))) short short8;
typedef __attribute__((ext_vector_type(4))) short short4v;
typedef __attribute__((ext_vector_type(4))) float f32x4;
typedef __attribute__((ext_vector_type(4))) int   int4v;
typedef _Float16 h8_t __attribute__((ext_vector_type(8)));

__device__ inline float b2f_bits(short s) {
    union { unsigned u; float f; } uf;
    uf.u = ((unsigned)(unsigned short)s) << 16;
    return uf.f;
}
__device__ inline short f2b_bits(float x) {
    union { __hip_bfloat16 h; short s; } u;
    u.h = __float2bfloat16(x);
    return u.s;
}
// bf16 split (x ~= hi+lo, ~2^-17): used on the precision-critical q/k/v path
__device__ inline void split_bf16(float x, short& hi, short& lo) {
    hi = f2b_bits(x);
    lo = f2b_bits(x - b2f_bits(hi));
}
__device__ inline int pack_split(float x) {
    short h, l;
    split_bf16(x, h, l);
    return (int)((unsigned short)h | ((unsigned)(unsigned short)l << 16));
}
__device__ inline float unpack_f32(int w) {
    return b2f_bits((short)(w & 0xffff)) + b2f_bits((short)(((unsigned)w) >> 16));
}
__device__ inline void unpack8(int4v a, int4v b, short8& h, short8& l) {
#pragma unroll
    for (int j = 0; j < 4; ++j) {
        h[j]     = (short)(a[j] & 0xffff);
        l[j]     = (short)(((unsigned)a[j]) >> 16);
        h[4 + j] = (short)(b[j] & 0xffff);
        l[4 + j] = (short)(((unsigned)b[j]) >> 16);
    }
}
// f16 helpers (weight GEMMs, 2-pass): hi ~2^-12, hi+lo ~2^-24
__device__ inline short f2h_bits(float x) {
    _Float16 h = (_Float16)x;
    return __builtin_bit_cast(short, h);
}
__device__ inline void split_f16(float x, short& hi, short& lo) {
    _Float16 h = (_Float16)x;
    _Float16 l = (_Float16)(x - (float)h);
    hi = __builtin_bit_cast(short, h);
    lo = __builtin_bit_cast(short, l);
}
// XOR-swizzled LDS index (short units): row-major [rows][64], 16B granules
__device__ inline int swz64(int row, int g) {
    return row * 64 + ((g ^ (row & 7)) << 3);
}
__device__ inline int swz128(int row, int g) {
    return row * 128 + ((g ^ (row & 15)) << 3);
}
// async global->LDS 16B: lane's data lands at lds_base + lane*16B
__device__ inline void gload16(const void* g, void* l) {
    __builtin_amdgcn_global_load_lds(
        (const __attribute__((address_space(1))) void*)g,
        (__attribute__((address_space(3))) void*)l, 16, 0, 0);
}

// ---------------- weights f32 -> hi/lo f16 planes ----------------
__global__ __launch_bounds__(256) void k_split_w(const float* __restrict__ w,
                                                 short* __restrict__ wh,
                                                 short* __restrict__ wl, int n4) {
    int i = blockIdx.x * 256 + threadIdx.x;
    if (i < n4) {
        f32x4 v = *(const f32x4*)&w[i * 4];
        short4v h, l;
#pragma unroll
        for (int j = 0; j < 4; ++j) {
            short hh, ll;
            split_f16(v[j], hh, ll);
            h[j] = hh;
            l[j] = ll;
        }
        *(short4v*)&wh[i * 4] = h;
        *(short4v*)&wl[i * 4] = l;
    }
}

// ---------------- x [C][N] f32 -> xT [N][C] f16 ----------------
__global__ __launch_bounds__(256) void k_transpose_xf16(const float* __restrict__ in,
                                                        short* __restrict__ out) {
    __shared__ float tile[64][65];
    int b = blockIdx.z;
    int c0 = blockIdx.y * 64, n0 = blockIdx.x * 64;
    const float* ip = in + (long)b * ((long)CHN * HW);
    short* op = out + (long)b * ((long)HW * CHN);
    int t = threadIdx.x;
#pragma unroll
    for (int p = 0; p < 4; ++p) {
        int id = p * 256 + t;
        int r = id >> 4, c4 = (id & 15) * 4;
        f32x4 v = *(const f32x4*)&ip[(long)(c0 + r) * HW + n0 + c4];
#pragma unroll
        for (int j = 0; j < 4; ++j) tile[r][c4 + j] = v[j];
    }
    __syncthreads();
    int col = t & 63, rr = t >> 6;
#pragma unroll
    for (int p = 0; p < 16; ++p) {
        int r = p * 4 + rr;
        op[(long)(n0 + r) * CHN + c0 + col] = f2h_bits(tile[col][r]);
    }
}

// ---------------- v [C][N] packed int -> vT [N][C] packed int ----------------
__global__ __launch_bounds__(256) void k_transpose_int(const int* __restrict__ in,
                                                       int* __restrict__ out,
                                                       long in_bstride, long out_bstride) {
    __shared__ int tile[64][65];
    int b = blockIdx.z;
    int c0 = blockIdx.y * 64, n0 = blockIdx.x * 64;
    const int* ip = in + (long)b * in_bstride;
    int* op = out + (long)b * out_bstride;
    int t = threadIdx.x;
#pragma unroll
    for (int p = 0; p < 4; ++p) {
        int id = p * 256 + t;
        int r = id >> 4, c4 = (id & 15) * 4;
        int4v v = *(const int4v*)&ip[(long)(c0 + r) * HW + n0 + c4];
#pragma unroll
        for (int j = 0; j < 4; ++j) tile[r][c4 + j] = v[j];
    }
    __syncthreads();
    int col = t & 63, rr = t >> 6;
#pragma unroll
    for (int p = 0; p < 16; ++p) {
        int r = p * 4 + rr;
        op[(long)(n0 + r) * CHN + c0 + col] = tile[col][r];
    }
}

// ---------------- GEMM: C[b] = A (MxK f16 planes, exact) * B[b]^T (NxK f16), 2-pass ----------------
// Staging via global_load_lds(16B) with pre-swizzled source granule; LDS stays
// linear-per-row with the same XOR involution the ds_read_b128 fragments use.
template <int MT, bool OUT_SPLIT>
__global__ __launch_bounds__(256) void k_gemm_f16(const short* __restrict__ Ah,
                                                  const short* __restrict__ Al,
                                                  const short* __restrict__ B,
                                                  void* __restrict__ Cv,
                                                  int M, int N, int K,
                                                  long bB, long bC) {
    __shared__ short sAh[MT * 64], sAl[MT * 64], sB[128 * 64];
    int b = blockIdx.z;
    int m0 = blockIdx.y * MT, n0 = blockIdx.x * 128;
    const short* Bp = B + (long)b * bB;
    int t = threadIdx.x, wid = t >> 6, lane = t & 63;
    int wr = (wid >> 1) * (MT / 2), wc = (wid & 1) * 64;
    int lrow = lane & 15, khalf = lane >> 4;
    int lrow8 = lane >> 3;                         // 0..7 within wave's 8 rows
    int gl = ((lane & 7) ^ lrow8) << 3;            // pre-swizzled source granule (shorts)
    constexpr int MR = MT / 32;                    // acc M-fragments per wave
    f32x4 acc[MR][4] = {};
    for (int kt = 0; kt < K; kt += 64) {
#pragma unroll
        for (int i = 0; i < MT / 32; ++i) {
            int rb = i * 32 + wid * 8;
            int row = rb + lrow8;
            gload16(&Ah[(long)(m0 + row) * K + kt + gl], &sAh[rb * 64]);
            gload16(&Al[(long)(m0 + row) * K + kt + gl], &sAl[rb * 64]);
        }
#pragma unroll
        for (int i = 0; i < 4; ++i) {
            int rb = i * 32 + wid * 8;
            int row = rb + lrow8;
            gload16(&Bp[(long)(n0 + row) * K + kt + gl], &sB[rb * 64]);
        }
        __syncthreads();
#pragma unroll
        for (int ks = 0; ks < 2; ++ks) {
            int gk = ks * 4 + khalf;
            h8_t ah[MR], al[MR], bh[4];
#pragma unroll
            for (int i = 0; i < MR; ++i) {
                ah[i] = *(const h8_t*)&sAh[swz64(wr + i * 16 + lrow, gk)];
                al[i] = *(const h8_t*)&sAl[swz64(wr + i * 16 + lrow, gk)];
            }
#pragma unroll
            for (int i = 0; i < 4; ++i)
                bh[i] = *(const h8_t*)&sB[swz64(wc + i * 16 + lrow, gk)];
#pragma unroll
            for (int mi = 0; mi < MR; ++mi)
#pragma unroll
                for (int ni = 0; ni < 4; ++ni) {
                    acc[mi][ni] = __builtin_amdgcn_mfma_f32_16x16x32_f16(
                        ah[mi], bh[ni], acc[mi][ni], 0, 0, 0);
                    acc[mi][ni] = __builtin_amdgcn_mfma_f32_16x16x32_f16(
                        al[mi], bh[ni], acc[mi][ni], 0, 0, 0);
                }
        }
        __syncthreads();
    }
    int crow = (lane >> 4) * 4, ccol = lane & 15;
#pragma unroll
    for (int mi = 0; mi < MR; ++mi)
#pragma unroll
        for (int ni = 0; ni < 4; ++ni)
#pragma unroll
            for (int r = 0; r < 4; ++r) {
                long row = m0 + wr + mi * 16 + crow + r;
                long col = n0 + wc + ni * 16 + ccol;
                if constexpr (OUT_SPLIT)
                    ((int*)Cv)[(long)b * bC + row * N + col] = pack_split(acc[mi][ni][r]);
                else
                    ((float*)Cv)[(long)b * bC + row * N + col] = acc[mi][ni][r];
            }
}

// ---------------- fused depthwise 3x3 SAME + (q,k) L2-norm, packed bf16-pair in-place ----------------
__global__ __launch_bounds__(256) void k_dwl2_pp(int* __restrict__ qkv,
                                                 const float* __restrict__ w) {
    __shared__ float img[64][68];
    __shared__ float red[4];
    int ch = blockIdx.x, b = blockIdx.y;
    bool is_qk = ch < 1024;
    int* p = qkv + ((long)b * C3 + ch) * HW;
    float w9[9];
#pragma unroll
    for (int i = 0; i < 9; ++i) w9[i] = w[ch * 9 + i];
    int t = threadIdx.x;
#pragma unroll
    for (int pp = 0; pp < 2; ++pp) {
        int u = pp * 256 + t, y = u >> 3, x8 = (u & 7) * 8;
        const int* src = &p[y * 64 + x8];
        int4v w0 = *(const int4v*)src;
        int4v w1 = *(const int4v*)(src + 4);
#pragma unroll
        for (int j = 0; j < 4; ++j) {
            img[y][x8 + j]     = unpack_f32(w0[j]);
            img[y][x8 + 4 + j] = unpack_f32(w1[j]);
        }
    }
    __syncthreads();
    float fv[2][8];
#pragma unroll
    for (int pp = 0; pp < 2; ++pp) {
        int u = pp * 256 + t, y = u >> 3, x8 = (u & 7) * 8;
#pragma unroll
        for (int j = 0; j < 8; ++j) {
            int xx = x8 + j;
            float s = 0.f;
#pragma unroll
            for (int dy = -1; dy <= 1; ++dy) {
                int yy = y + dy;
                if (yy < 0 || yy > 63) continue;
#pragma unroll
                for (int dx = -1; dx <= 1; ++dx) {
                    int xxx = xx + dx;
                    if (xxx < 0 || xxx > 63) continue;
                    s += img[yy][xxx] * w9[(dy + 1) * 3 + (dx + 1)];
                }
            }
            fv[pp][j] = s;
        }
    }
    float ss = 0.f;
#pragma unroll
    for (int pp = 0; pp < 2; ++pp)
#pragma unroll
        for (int j = 0; j < 8; ++j) ss += fv[pp][j] * fv[pp][j];
#pragma unroll
    for (int o = 32; o; o >>= 1) ss += __shfl_xor(ss, o);
    if ((t & 63) == 0) red[t >> 6] = ss;
    __syncthreads();
    float tot = red[0] + red[1] + red[2] + red[3];
    float sc = is_qk ? (1.f / fmaxf(sqrtf(tot), 1e-12f)) : 1.f;
#pragma unroll
    for (int pp = 0; pp < 2; ++pp) {
        int u = pp * 256 + t, y = u >> 3, x8 = (u & 7) * 8;
        int4v o0, o1;
#pragma unroll
        for (int j = 0; j < 4; ++j) {
            o0[j] = pack_split(fv[pp][j] * sc);
            o1[j] = pack_split(fv[pp][4 + j] * sc);
        }
        *(int4v*)&p[y * 64 + x8]     = o0;
        *(int4v*)&p[y * 64 + x8 + 4] = o1;
    }
}

// ---------------- attn partials: per (h, kslice, b): q(64xK)*k(64xK)^T, bf16 3-pass ----------------
__global__ __launch_bounds__(256) void k_attn_pp(const int* __restrict__ qkv,
                                                 float* __restrict__ attn_part) {
    __shared__ short sQh[64 * 128], sQl[64 * 128], sKh[64 * 128], sKl[64 * 128];
    int h = blockIdx.x, ksl = blockIdx.y, b = blockIdx.z;
    const int* qb = qkv + ((long)b * C3 + h * 64) * HW;
    const int* kb = qb + (long)512 * HW;
    int t = threadIdx.x, wid = t >> 6, lane = t & 63;
    int lrow = lane & 15, khalf = lane >> 4;
    f32x4 acc[4] = {};
    for (int kt = ksl * 512; kt < ksl * 512 + 512; kt += 128) {
#pragma unroll
        for (int p = 0; p < 4; ++p) {
            int id = p * 256 + t, row = id >> 4, g = id & 15;
            int off = swz128(row, g);
            {
                const int* s = &qb[(long)row * HW + kt + g * 8];
                int4v w0 = *(const int4v*)s, w1 = *(const int4v*)(s + 4);
                short8 hh, ll;
                unpack8(w0, w1, hh, ll);
                *(short8*)&sQh[off] = hh;
                *(short8*)&sQl[off] = ll;
            }
            {
                const int* s = &kb[(long)row * HW + kt + g * 8];
                int4v w0 = *(const int4v*)s, w1 = *(const int4v*)(s + 4);
                short8 hh, ll;
                unpack8(w0, w1, hh, ll);
                *(short8*)&sKh[off] = hh;
                *(short8*)&sKl[off] = ll;
            }
        }
        __syncthreads();
#pragma unroll
        for (int ks = 0; ks < 4; ++ks) {
            int gk = ks * 4 + khalf;
            short8 kh = *(const short8*)&sKh[swz128(wid * 16 + lrow, gk)];
            short8 kl = *(const short8*)&sKl[swz128(wid * 16 + lrow, gk)];
#pragma unroll
            for (int mi = 0; mi < 4; ++mi) {
                short8 qh = *(const short8*)&sQh[swz128(mi * 16 + lrow, gk)];
                short8 ql = *(const short8*)&sQl[swz128(mi * 16 + lrow, gk)];
                acc[mi] = __builtin_amdgcn_mfma_f32_16x16x32_bf16(qh, kh, acc[mi], 0, 0, 0);
                acc[mi] = __builtin_amdgcn_mfma_f32_16x16x32_bf16(ql, kh, acc[mi], 0, 0, 0);
                acc[mi] = __builtin_amdgcn_mfma_f32_16x16x32_bf16(qh, kl, acc[mi], 0, 0, 0);
            }
        }
        __syncthreads();
    }
    float* op = attn_part + (((long)b * 8 + ksl) * 8 + h) * 4096;
    int crow = (lane >> 4) * 4, ccol = lane & 15;
#pragma unroll
    for (int mi = 0; mi < 4; ++mi)
#pragma unroll
        for (int r = 0; r < 4; ++r)
            op[(mi * 16 + crow + r) * 64 + wid * 16 + ccol] = acc[mi][r];
}

// ---------------- fused 4x top-k masked softmax combine -> Wc (f32) ----------------
__global__ __launch_bounds__(256) void k_smcomb(const float* __restrict__ attn_part,
                                                const float* __restrict__ temp,
                                                const float* __restrict__ a1,
                                                const float* __restrict__ a2,
                                                const float* __restrict__ a3,
                                                const float* __restrict__ a4,
                                                float* __restrict__ Wc) {
    int t = threadIdx.x, wid = t >> 6, lane = t & 63;
    int b = blockIdx.z;
    int r = blockIdx.x * 4 + wid;   // (h, qrow) 0..511
    int h = r >> 6, qr = r & 63;
    float a = 0.f;
#pragma unroll
    for (int s = 0; s < 8; ++s)
        a += attn_part[(((long)b * 8 + s) * 8 + h) * 4096 + qr * 64 + lane];
    a *= temp[h];
    int cnt = 0;
#pragma unroll
    for (int j = 0; j < 64; ++j) {
        float aj = __shfl(a, j);
        cnt += (aj > a) ? 1 : 0;
    }
    float m = a;
#pragma unroll
    for (int o = 32; o; o >>= 1) m = fmaxf(m, __shfl_xor(m, o));
    float e = expf(a - m);
    const int kk[4] = {32, 42, 48, 51};
    float coef[4] = {a1[0], a2[0], a3[0], a4[0]};
    float out = 0.f;
#pragma unroll
    for (int i = 0; i < 4; ++i) {
        float ei = (cnt < kk[i]) ? e : 0.f;
        float d = ei;
#pragma unroll
        for (int o = 32; o; o >>= 1) d += __shfl_xor(d, o);
        out += coef[i] * ei / d;
    }
    Wc[((long)b * 8 + h) * 4096 + qr * 64 + lane] = out;
}

// ---------------- attT[n][c] = sum_d vT[n][d]*Wc[c][d], bf16 3-pass, f16 out ----------------
__global__ __launch_bounds__(256) void k_wv_pp(const float* __restrict__ Wc,
                                               const int* __restrict__ vT,
                                               short* __restrict__ attTs) {
    __shared__ short sVh[128 * 64], sVl[128 * 64];
    __shared__ short sWh[64 * 64], sWl[64 * 64];
    int nb = blockIdx.x, h = blockIdx.y, b = blockIdx.z;
    int n0 = nb * 128;
    const float* wp = Wc + ((long)b * 8 + h) * 4096;
    const int* vp = vT + (long)b * ((long)HW * CHN) + (long)n0 * CHN + h * 64;
    int t = threadIdx.x, wid = t >> 6, lane = t & 63;
    int lrow = lane & 15, khalf = lane >> 4;
#pragma unroll
    for (int p = 0; p < 4; ++p) {
        int id = p * 256 + t, row = id >> 3, g = id & 7;
        const int* src = &vp[(long)row * CHN + g * 8];
        int4v w0 = *(const int4v*)src, w1 = *(const int4v*)(src + 4);
        short8 hh, ll;
        unpack8(w0, w1, hh, ll);
        int off = swz64(row, g);
        *(short8*)&sVh[off] = hh;
        *(short8*)&sVl[off] = ll;
    }
#pragma unroll
    for (int p = 0; p < 2; ++p) {
        int id = p * 256 + t, row = id >> 3, g = id & 7;
        f32x4 va = *(const f32x4*)&wp[row * 64 + g * 8];
        f32x4 vb = *(const f32x4*)&wp[row * 64 + g * 8 + 4];
        short8 hh, ll;
#pragma unroll
        for (int j = 0; j < 4; ++j) {
            short h0, l0, h1, l1;
            split_bf16(va[j], h0, l0);
            split_bf16(vb[j], h1, l1);
            hh[j] = h0;     ll[j] = l0;
            hh[4 + j] = h1; ll[4 + j] = l1;
        }
        int off = swz64(row, g);
        *(short8*)&sWh[off] = hh;
        *(short8*)&sWl[off] = ll;
    }
    __syncthreads();
    f32x4 acc[2][4] = {};
#pragma unroll
    for (int ks = 0; ks < 2; ++ks) {
        int gk = ks * 4 + khalf;
        short8 vh[2], vl[2], wh[4], wl[4];
#pragma unroll
        for (int i = 0; i < 2; ++i) {
            int rr = wid * 32 + i * 16 + lrow;
            vh[i] = *(const short8*)&sVh[swz64(rr, gk)];
            vl[i] = *(const short8*)&sVl[swz64(rr, gk)];
        }
#pragma unroll
        for (int i = 0; i < 4; ++i) {
            int rr = i * 16 + lrow;
            wh[i] = *(const short8*)&sWh[swz64(rr, gk)];
            wl[i] = *(const short8*)&sWl[swz64(rr, gk)];
        }
#pragma unroll
        for (int mi = 0; mi < 2; ++mi)
#pragma unroll
            for (int ni = 0; ni < 4; ++ni) {
                acc[mi][ni] = __builtin_amdgcn_mfma_f32_16x16x32_bf16(
                    vh[mi], wh[ni], acc[mi][ni], 0, 0, 0);
                acc[mi][ni] = __builtin_amdgcn_mfma_f32_16x16x32_bf16(
                    vl[mi], wh[ni], acc[mi][ni], 0, 0, 0);
                acc[mi][ni] = __builtin_amdgcn_mfma_f32_16x16x32_bf16(
                    vh[mi], wl[ni], acc[mi][ni], 0, 0, 0);
            }
    }
    short* op = attTs + (long)b * ((long)C3 * HW * 2);
    int crow = (lane >> 4) * 4, ccol = lane & 15;
#pragma unroll
    for (int mi = 0; mi < 2; ++mi)
#pragma unroll
        for (int ni = 0; ni < 4; ++ni)
#pragma unroll
            for (int r = 0; r < 4; ++r) {
                long n = n0 + wid * 32 + mi * 16 + crow + r;
                int c = h * 64 + ni * 16 + ccol;
                op[n * CHN + c] = f2h_bits(acc[mi][ni][r]);
            }
}

extern "C" void kernel_launch(void* const* d_in, const int* in_sizes, int n_in,
                              void* d_out, int out_size, void* d_ws, size_t ws_size,
                              hipStream_t stream) {
    const float* x      = (const float*)d_in[0];
    const float* qkv_w  = (const float*)d_in[1];
    const float* dw_w   = (const float*)d_in[2];
    const float* proj_w = (const float*)d_in[3];
    const float* temp   = (const float*)d_in[4];
    const float* a1     = (const float*)d_in[5];
    const float* a2     = (const float*)d_in[6];
    const float* a3     = (const float*)d_in[7];
    const float* a4     = (const float*)d_in[8];
    float* out = (float*)d_out;

    char* ws = (char*)d_ws;
    // layout (139,984,896 B total, proven safe):
    //   0           qkvi: packed bf16-pair [GB][1536][4096] int (100,663,296 B);
    //               per-batch q-region reused as attT f16 [4096][512] after attn
    //   100663296   vT region (33,554,432 B): xTs f16 [GB][4096][512] (16 MB, steps 1-2),
    //               then vT packed int [GB][4096][512] (32 MB, steps 4-7)
    //   134217728   REGION_A (4,194,304 B): wq f16 planes (3 MB) then attn_part f32
    //   138412032   Wc f32 [GB][8][64][64] (524,288 B)
    //   138936320   wph (524,288 B)
    //   139460608   wpl (524,288 B)
    int*   qkvi      = (int*)(ws);
    short* xTs       = (short*)(ws + 100663296);
    int*   vT        = (int*)(ws + 100663296);
    short* wqh       = (short*)(ws + 134217728);
    short* wql       = (short*)(ws + 134217728 + 1572864);
    float* attn_part = (float*)(ws + 134217728);
    float* Wc        = (float*)(ws + 138412032);
    short* wph       = (short*)(ws + 138936320);
    short* wpl       = (short*)(ws + 139460608);

    k_split_w<<<256, 256, 0, stream>>>(proj_w, wph, wpl, 65536);

    for (int g = 0; g < 2; ++g) {
        const float* xg = x + (long)g * GB * CHN * HW;
        float* outg = out + (long)g * GB * CHN * HW;
        // 0. split qkv weights to f16 planes (region shared with attn_part)
        k_split_w<<<768, 256, 0, stream>>>(qkv_w, wqh, wql, 196608);
        // 1. x -> xTs f16 [n][c]
        k_transpose_xf16<<<dim3(64, 8, GB), 256, 0, stream>>>(xg, xTs);
        // 2. qkv = Wqkv * x  (M=1536, N=4096, K=512), 2-pass f16 -> bf16-pair out
        k_gemm_f16<128, true><<<dim3(32, 12, GB), 256, 0, stream>>>(
            wqh, wql, xTs, qkvi, C3, HW, CHN, (long)HW * CHN, (long)C3 * HW);
        // 3. depthwise 3x3 + q,k L2-norm, in-place packed bf16-pair
        k_dwl2_pp<<<dim3(C3, GB), 256, 0, stream>>>(qkvi, dw_w);
        // 4. v -> vT packed int [n][c] (overwrites dead xTs)
        k_transpose_int<<<dim3(64, 8, GB), 256, 0, stream>>>(
            qkvi + (long)1024 * HW, vT, (long)C3 * HW, (long)HW * CHN);
        // 5. attn partials (8 K-slices), exact bf16 3-pass
        k_attn_pp<<<dim3(8, 8, GB), 256, 0, stream>>>(qkvi, attn_part);
        // 6. fused top-k softmax combine
        k_smcomb<<<dim3(128, 1, GB), 256, 0, stream>>>(attn_part, temp, a1, a2, a3, a4, Wc);
        // 7. attT f16 = (Wc * v)^T, into dead q-region of qkvi
        k_wv_pp<<<dim3(32, 8, GB), 256, 0, stream>>>(Wc, vT, (short*)qkvi);
        // 8. out = Wproj * att  (M=512, N=4096, K=512), 2-pass f16, f32 out, 64-row tiles
        k_gemm_f16<64, false><<<dim3(32, 8, GB), 256, 0, stream>>>(
            wph, wpl, (const short*)qkvi, outg, CHN, HW, CHN,
            (long)C3 * HW * 2, (long)CHN * HW);
    }
}

// Round 8
// 323.492 us; speedup vs baseline: 3.6356x; 1.1274x over previous
//
#include <hip/hip_runtime.h>
#include <hip/hip_bf16.h>

#define CHN 512
#define HW  4096
#define C3  1536
#define GB  4   // batches per group

typedef __hip_bfloat16 bf16;
typedef __attribute__((ext_vector_type(8))) short short8;
typedef __attribute__((ext_vector_type(4))) short short4v;
typedef __attribute__((ext_vector_type(4))) float f32x4;
typedef __attribute__((ext_vector_type(4))) int   int4v;
typedef _Float16 h8_t __attribute__((ext_vector_type(8)));

__device__ inline float b2f_bits(short s) {
    union { unsigned u; float f; } uf;
    uf.u = ((unsigned)(unsigned short)s) << 16;
    return uf.f;
}
__device__ inline short f2b_bits(float x) {
    union { __hip_bfloat16 h; short s; } u;
    u.h = __float2bfloat16(x);
    return u.s;
}
// bf16 split (x ~= hi+lo, ~2^-17): used on the precision-critical q/k/v path
__device__ inline void split_bf16(float x, short& hi, short& lo) {
    hi = f2b_bits(x);
    lo = f2b_bits(x - b2f_bits(hi));
}
__device__ inline int pack_split(float x) {
    short h, l;
    split_bf16(x, h, l);
    return (int)((unsigned short)h | ((unsigned)(unsigned short)l << 16));
}
__device__ inline float unpack_f32(int w) {
    return b2f_bits((short)(w & 0xffff)) + b2f_bits((short)(((unsigned)w) >> 16));
}
__device__ inline void unpack8(int4v a, int4v b, short8& h, short8& l) {
#pragma unroll
    for (int j = 0; j < 4; ++j) {
        h[j]     = (short)(a[j] & 0xffff);
        l[j]     = (short)(((unsigned)a[j]) >> 16);
        h[4 + j] = (short)(b[j] & 0xffff);
        l[4 + j] = (short)(((unsigned)b[j]) >> 16);
    }
}
// f16 helpers: hi ~2^-11, hi+lo ~2^-22
__device__ inline short f2h_bits(float x) {
    _Float16 h = (_Float16)x;
    return __builtin_bit_cast(short, h);
}
__device__ inline void split_f16(float x, short& hi, short& lo) {
    _Float16 h = (_Float16)x;
    _Float16 l = (_Float16)(x - (float)h);
    hi = __builtin_bit_cast(short, h);
    lo = __builtin_bit_cast(short, l);
}
// XOR-swizzled LDS index (short units): row-major [rows][64], 16B granules
__device__ inline int swz64(int row, int g) {
    return row * 64 + ((g ^ (row & 7)) << 3);
}
__device__ inline int swz128(int row, int g) {
    return row * 128 + ((g ^ (row & 15)) << 3);
}
// async global->LDS 16B: lane's data lands at lds_base + lane*16B
__device__ inline void gload16(const void* g, void* l) {
    __builtin_amdgcn_global_load_lds(
        (const __attribute__((address_space(1))) void*)g,
        (__attribute__((address_space(3))) void*)l, 16, 0, 0);
}

// ---------------- weights f32 -> hi/lo f16 planes ----------------
__global__ __launch_bounds__(256) void k_split_w(const float* __restrict__ w,
                                                 short* __restrict__ wh,
                                                 short* __restrict__ wl, int n4) {
    int i = blockIdx.x * 256 + threadIdx.x;
    if (i < n4) {
        f32x4 v = *(const f32x4*)&w[i * 4];
        short4v h, l;
#pragma unroll
        for (int j = 0; j < 4; ++j) {
            short hh, ll;
            split_f16(v[j], hh, ll);
            h[j] = hh;
            l[j] = ll;
        }
        *(short4v*)&wh[i * 4] = h;
        *(short4v*)&wl[i * 4] = l;
    }
}

// ---------------- weights f32 -> f16 (hi only) ----------------
__global__ __launch_bounds__(256) void k_w_hi(const float* __restrict__ w,
                                              short* __restrict__ wh, int n4) {
    int i = blockIdx.x * 256 + threadIdx.x;
    if (i < n4) {
        f32x4 v = *(const f32x4*)&w[i * 4];
        short4v h;
#pragma unroll
        for (int j = 0; j < 4; ++j) h[j] = f2h_bits(v[j]);
        *(short4v*)&wh[i * 4] = h;
    }
}

// ---------------- x [C][N] f32 -> xT [N][C] f16 ----------------
__global__ __launch_bounds__(256) void k_transpose_xf16(const float* __restrict__ in,
                                                        short* __restrict__ out) {
    __shared__ float tile[64][65];
    int b = blockIdx.z;
    int c0 = blockIdx.y * 64, n0 = blockIdx.x * 64;
    const float* ip = in + (long)b * ((long)CHN * HW);
    short* op = out + (long)b * ((long)HW * CHN);
    int t = threadIdx.x;
#pragma unroll
    for (int p = 0; p < 4; ++p) {
        int id = p * 256 + t;
        int r = id >> 4, c4 = (id & 15) * 4;
        f32x4 v = *(const f32x4*)&ip[(long)(c0 + r) * HW + n0 + c4];
#pragma unroll
        for (int j = 0; j < 4; ++j) tile[r][c4 + j] = v[j];
    }
    __syncthreads();
    int col = t & 63, rr = t >> 6;
#pragma unroll
    for (int p = 0; p < 16; ++p) {
        int r = p * 4 + rr;
        op[(long)(n0 + r) * CHN + c0 + col] = f2h_bits(tile[col][r]);
    }
}

// ---------------- v [C][N] packed int -> vT [N][C] packed int ----------------
__global__ __launch_bounds__(256) void k_transpose_int(const int* __restrict__ in,
                                                       int* __restrict__ out,
                                                       long in_bstride, long out_bstride) {
    __shared__ int tile[64][65];
    int b = blockIdx.z;
    int c0 = blockIdx.y * 64, n0 = blockIdx.x * 64;
    const int* ip = in + (long)b * in_bstride;
    int* op = out + (long)b * out_bstride;
    int t = threadIdx.x;
#pragma unroll
    for (int p = 0; p < 4; ++p) {
        int id = p * 256 + t;
        int r = id >> 4, c4 = (id & 15) * 4;
        int4v v = *(const int4v*)&ip[(long)(c0 + r) * HW + n0 + c4];
#pragma unroll
        for (int j = 0; j < 4; ++j) tile[r][c4 + j] = v[j];
    }
    __syncthreads();
    int col = t & 63, rr = t >> 6;
#pragma unroll
    for (int p = 0; p < 16; ++p) {
        int r = p * 4 + rr;
        op[(long)(n0 + r) * CHN + c0 + col] = tile[col][r];
    }
}

// ---------------- GEMM: C[b] = A (MxK f16 planes) * B[b]^T (NxK f16) ----------------
// PASSES=1: A-hi only. PASSES=2: (Ah+Al)·B, A exact to ~2^-22.
// Staging via global_load_lds(16B) with pre-swizzled source granule.
template <int MT, int PASSES, bool OUT_SPLIT>
__global__ __launch_bounds__(256) void k_gemm_f16(const short* __restrict__ Ah,
                                                  const short* __restrict__ Al,
                                                  const short* __restrict__ B,
                                                  void* __restrict__ Cv,
                                                  int M, int N, int K,
                                                  long bB, long bC) {
    __shared__ short sAh[MT * 64], sB[128 * 64];
    __shared__ short sAl[PASSES == 2 ? MT * 64 : 8];
    int b = blockIdx.z;
    int m0 = blockIdx.y * MT, n0 = blockIdx.x * 128;
    const short* Bp = B + (long)b * bB;
    int t = threadIdx.x, wid = t >> 6, lane = t & 63;
    int wr = (wid >> 1) * (MT / 2), wc = (wid & 1) * 64;
    int lrow = lane & 15, khalf = lane >> 4;
    int lrow8 = lane >> 3;                         // 0..7 within wave's 8 rows
    int gl = ((lane & 7) ^ lrow8) << 3;            // pre-swizzled source granule (shorts)
    constexpr int MR = MT / 32;                    // acc M-fragments per wave
    f32x4 acc[MR][4] = {};
    for (int kt = 0; kt < K; kt += 64) {
#pragma unroll
        for (int i = 0; i < MT / 32; ++i) {
            int rb = i * 32 + wid * 8;
            int row = rb + lrow8;
            gload16(&Ah[(long)(m0 + row) * K + kt + gl], &sAh[rb * 64]);
            if constexpr (PASSES == 2)
                gload16(&Al[(long)(m0 + row) * K + kt + gl], &sAl[rb * 64]);
        }
#pragma unroll
        for (int i = 0; i < 4; ++i) {
            int rb = i * 32 + wid * 8;
            int row = rb + lrow8;
            gload16(&Bp[(long)(n0 + row) * K + kt + gl], &sB[rb * 64]);
        }
        __syncthreads();
#pragma unroll
        for (int ks = 0; ks < 2; ++ks) {
            int gk = ks * 4 + khalf;
            h8_t ah[MR], al[MR], bh[4];
#pragma unroll
            for (int i = 0; i < MR; ++i) {
                ah[i] = *(const h8_t*)&sAh[swz64(wr + i * 16 + lrow, gk)];
                if constexpr (PASSES == 2)
                    al[i] = *(const h8_t*)&sAl[swz64(wr + i * 16 + lrow, gk)];
            }
#pragma unroll
            for (int i = 0; i < 4; ++i)
                bh[i] = *(const h8_t*)&sB[swz64(wc + i * 16 + lrow, gk)];
#pragma unroll
            for (int mi = 0; mi < MR; ++mi)
#pragma unroll
                for (int ni = 0; ni < 4; ++ni) {
                    acc[mi][ni] = __builtin_amdgcn_mfma_f32_16x16x32_f16(
                        ah[mi], bh[ni], acc[mi][ni], 0, 0, 0);
                    if constexpr (PASSES == 2)
                        acc[mi][ni] = __builtin_amdgcn_mfma_f32_16x16x32_f16(
                            al[mi], bh[ni], acc[mi][ni], 0, 0, 0);
                }
        }
        __syncthreads();
    }
    int crow = (lane >> 4) * 4, ccol = lane & 15;
#pragma unroll
    for (int mi = 0; mi < MR; ++mi)
#pragma unroll
        for (int ni = 0; ni < 4; ++ni)
#pragma unroll
            for (int r = 0; r < 4; ++r) {
                long row = m0 + wr + mi * 16 + crow + r;
                long col = n0 + wc + ni * 16 + ccol;
                if constexpr (OUT_SPLIT)
                    ((int*)Cv)[(long)b * bC + row * N + col] = pack_split(acc[mi][ni][r]);
                else
                    ((float*)Cv)[(long)b * bC + row * N + col] = acc[mi][ni][r];
            }
}

// ---------------- fused depthwise 3x3 SAME + (q,k) L2-norm, packed bf16-pair in-place ----------------
__global__ __launch_bounds__(256) void k_dwl2_pp(int* __restrict__ qkv,
                                                 const float* __restrict__ w) {
    __shared__ float img[64][68];
    __shared__ float red[4];
    int ch = blockIdx.x, b = blockIdx.y;
    bool is_qk = ch < 1024;
    int* p = qkv + ((long)b * C3 + ch) * HW;
    float w9[9];
#pragma unroll
    for (int i = 0; i < 9; ++i) w9[i] = w[ch * 9 + i];
    int t = threadIdx.x;
#pragma unroll
    for (int pp = 0; pp < 2; ++pp) {
        int u = pp * 256 + t, y = u >> 3, x8 = (u & 7) * 8;
        const int* src = &p[y * 64 + x8];
        int4v w0 = *(const int4v*)src;
        int4v w1 = *(const int4v*)(src + 4);
#pragma unroll
        for (int j = 0; j < 4; ++j) {
            img[y][x8 + j]     = unpack_f32(w0[j]);
            img[y][x8 + 4 + j] = unpack_f32(w1[j]);
        }
    }
    __syncthreads();
    float fv[2][8];
#pragma unroll
    for (int pp = 0; pp < 2; ++pp) {
        int u = pp * 256 + t, y = u >> 3, x8 = (u & 7) * 8;
#pragma unroll
        for (int j = 0; j < 8; ++j) {
            int xx = x8 + j;
            float s = 0.f;
#pragma unroll
            for (int dy = -1; dy <= 1; ++dy) {
                int yy = y + dy;
                if (yy < 0 || yy > 63) continue;
#pragma unroll
                for (int dx = -1; dx <= 1; ++dx) {
                    int xxx = xx + dx;
                    if (xxx < 0 || xxx > 63) continue;
                    s += img[yy][xxx] * w9[(dy + 1) * 3 + (dx + 1)];
                }
            }
            fv[pp][j] = s;
        }
    }
    float ss = 0.f;
#pragma unroll
    for (int pp = 0; pp < 2; ++pp)
#pragma unroll
        for (int j = 0; j < 8; ++j) ss += fv[pp][j] * fv[pp][j];
#pragma unroll
    for (int o = 32; o; o >>= 1) ss += __shfl_xor(ss, o);
    if ((t & 63) == 0) red[t >> 6] = ss;
    __syncthreads();
    float tot = red[0] + red[1] + red[2] + red[3];
    float sc = is_qk ? (1.f / fmaxf(sqrtf(tot), 1e-12f)) : 1.f;
#pragma unroll
    for (int pp = 0; pp < 2; ++pp) {
        int u = pp * 256 + t, y = u >> 3, x8 = (u & 7) * 8;
        int4v o0, o1;
#pragma unroll
        for (int j = 0; j < 4; ++j) {
            o0[j] = pack_split(fv[pp][j] * sc);
            o1[j] = pack_split(fv[pp][4 + j] * sc);
        }
        *(int4v*)&p[y * 64 + x8]     = o0;
        *(int4v*)&p[y * 64 + x8 + 4] = o1;
    }
}

// ---------------- attn partials: per (h, kslice, b): q(64xK)*k(64xK)^T, bf16 3-pass ----------------
__global__ __launch_bounds__(256) void k_attn_pp(const int* __restrict__ qkv,
                                                 float* __restrict__ attn_part) {
    __shared__ short sQh[64 * 128], sQl[64 * 128], sKh[64 * 128], sKl[64 * 128];
    int h = blockIdx.x, ksl = blockIdx.y, b = blockIdx.z;
    const int* qb = qkv + ((long)b * C3 + h * 64) * HW;
    const int* kb = qb + (long)512 * HW;
    int t = threadIdx.x, wid = t >> 6, lane = t & 63;
    int lrow = lane & 15, khalf = lane >> 4;
    f32x4 acc[4] = {};
    for (int kt = ksl * 512; kt < ksl * 512 + 512; kt += 128) {
#pragma unroll
        for (int p = 0; p < 4; ++p) {
            int id = p * 256 + t, row = id >> 4, g = id & 15;
            int off = swz128(row, g);
            {
                const int* s = &qb[(long)row * HW + kt + g * 8];
                int4v w0 = *(const int4v*)s, w1 = *(const int4v*)(s + 4);
                short8 hh, ll;
                unpack8(w0, w1, hh, ll);
                *(short8*)&sQh[off] = hh;
                *(short8*)&sQl[off] = ll;
            }
            {
                const int* s = &kb[(long)row * HW + kt + g * 8];
                int4v w0 = *(const int4v*)s, w1 = *(const int4v*)(s + 4);
                short8 hh, ll;
                unpack8(w0, w1, hh, ll);
                *(short8*)&sKh[off] = hh;
                *(short8*)&sKl[off] = ll;
            }
        }
        __syncthreads();
#pragma unroll
        for (int ks = 0; ks < 4; ++ks) {
            int gk = ks * 4 + khalf;
            short8 kh = *(const short8*)&sKh[swz128(wid * 16 + lrow, gk)];
            short8 kl = *(const short8*)&sKl[swz128(wid * 16 + lrow, gk)];
#pragma unroll
            for (int mi = 0; mi < 4; ++mi) {
                short8 qh = *(const short8*)&sQh[swz128(mi * 16 + lrow, gk)];
                short8 ql = *(const short8*)&sQl[swz128(mi * 16 + lrow, gk)];
                acc[mi] = __builtin_amdgcn_mfma_f32_16x16x32_bf16(qh, kh, acc[mi], 0, 0, 0);
                acc[mi] = __builtin_amdgcn_mfma_f32_16x16x32_bf16(ql, kh, acc[mi], 0, 0, 0);
                acc[mi] = __builtin_amdgcn_mfma_f32_16x16x32_bf16(qh, kl, acc[mi], 0, 0, 0);
            }
        }
        __syncthreads();
    }
    float* op = attn_part + (((long)b * 8 + ksl) * 8 + h) * 4096;
    int crow = (lane >> 4) * 4, ccol = lane & 15;
#pragma unroll
    for (int mi = 0; mi < 4; ++mi)
#pragma unroll
        for (int r = 0; r < 4; ++r)
            op[(mi * 16 + crow + r) * 64 + wid * 16 + ccol] = acc[mi][r];
}

// ---------------- fused 4x top-k masked softmax combine -> Wc (f32) ----------------
__global__ __launch_bounds__(256) void k_smcomb(const float* __restrict__ attn_part,
                                                const float* __restrict__ temp,
                                                const float* __restrict__ a1,
                                                const float* __restrict__ a2,
                                                const float* __restrict__ a3,
                                                const float* __restrict__ a4,
                                                float* __restrict__ Wc) {
    int t = threadIdx.x, wid = t >> 6, lane = t & 63;
    int b = blockIdx.z;
    int r = blockIdx.x * 4 + wid;   // (h, qrow) 0..511
    int h = r >> 6, qr = r & 63;
    float a = 0.f;
#pragma unroll
    for (int s = 0; s < 8; ++s)
        a += attn_part[(((long)b * 8 + s) * 8 + h) * 4096 + qr * 64 + lane];
    a *= temp[h];
    int cnt = 0;
#pragma unroll
    for (int j = 0; j < 64; ++j) {
        float aj = __shfl(a, j);
        cnt += (aj > a) ? 1 : 0;
    }
    float m = a;
#pragma unroll
    for (int o = 32; o; o >>= 1) m = fmaxf(m, __shfl_xor(m, o));
    float e = expf(a - m);
    const int kk[4] = {32, 42, 48, 51};
    float coef[4] = {a1[0], a2[0], a3[0], a4[0]};
    float out = 0.f;
#pragma unroll
    for (int i = 0; i < 4; ++i) {
        float ei = (cnt < kk[i]) ? e : 0.f;
        float d = ei;
#pragma unroll
        for (int o = 32; o; o >>= 1) d += __shfl_xor(d, o);
        out += coef[i] * ei / d;
    }
    Wc[((long)b * 8 + h) * 4096 + qr * 64 + lane] = out;
}

// ---------------- attT[n][c] = sum_d vT[n][d]*Wc[c][d], bf16 3-pass, f16 out ----------------
__global__ __launch_bounds__(256) void k_wv_pp(const float* __restrict__ Wc,
                                               const int* __restrict__ vT,
                                               short* __restrict__ attTs) {
    __shared__ short sVh[128 * 64], sVl[128 * 64];
    __shared__ short sWh[64 * 64], sWl[64 * 64];
    int nb = blockIdx.x, h = blockIdx.y, b = blockIdx.z;
    int n0 = nb * 128;
    const float* wp = Wc + ((long)b * 8 + h) * 4096;
    const int* vp = vT + (long)b * ((long)HW * CHN) + (long)n0 * CHN + h * 64;
    int t = threadIdx.x, wid = t >> 6, lane = t & 63;
    int lrow = lane & 15, khalf = lane >> 4;
#pragma unroll
    for (int p = 0; p < 4; ++p) {
        int id = p * 256 + t, row = id >> 3, g = id & 7;
        const int* src = &vp[(long)row * CHN + g * 8];
        int4v w0 = *(const int4v*)src, w1 = *(const int4v*)(src + 4);
        short8 hh, ll;
        unpack8(w0, w1, hh, ll);
        int off = swz64(row, g);
        *(short8*)&sVh[off] = hh;
        *(short8*)&sVl[off] = ll;
    }
#pragma unroll
    for (int p = 0; p < 2; ++p) {
        int id = p * 256 + t, row = id >> 3, g = id & 7;
        f32x4 va = *(const f32x4*)&wp[row * 64 + g * 8];
        f32x4 vb = *(const f32x4*)&wp[row * 64 + g * 8 + 4];
        short8 hh, ll;
#pragma unroll
        for (int j = 0; j < 4; ++j) {
            short h0, l0, h1, l1;
            split_bf16(va[j], h0, l0);
            split_bf16(vb[j], h1, l1);
            hh[j] = h0;     ll[j] = l0;
            hh[4 + j] = h1; ll[4 + j] = l1;
        }
        int off = swz64(row, g);
        *(short8*)&sWh[off] = hh;
        *(short8*)&sWl[off] = ll;
    }
    __syncthreads();
    f32x4 acc[2][4] = {};
#pragma unroll
    for (int ks = 0; ks < 2; ++ks) {
        int gk = ks * 4 + khalf;
        short8 vh[2], vl[2], wh[4], wl[4];
#pragma unroll
        for (int i = 0; i < 2; ++i) {
            int rr = wid * 32 + i * 16 + lrow;
            vh[i] = *(const short8*)&sVh[swz64(rr, gk)];
            vl[i] = *(const short8*)&sVl[swz64(rr, gk)];
        }
#pragma unroll
        for (int i = 0; i < 4; ++i) {
            int rr = i * 16 + lrow;
            wh[i] = *(const short8*)&sWh[swz64(rr, gk)];
            wl[i] = *(const short8*)&sWl[swz64(rr, gk)];
        }
#pragma unroll
        for (int mi = 0; mi < 2; ++mi)
#pragma unroll
            for (int ni = 0; ni < 4; ++ni) {
                acc[mi][ni] = __builtin_amdgcn_mfma_f32_16x16x32_bf16(
                    vh[mi], wh[ni], acc[mi][ni], 0, 0, 0);
                acc[mi][ni] = __builtin_amdgcn_mfma_f32_16x16x32_bf16(
                    vl[mi], wh[ni], acc[mi][ni], 0, 0, 0);
                acc[mi][ni] = __builtin_amdgcn_mfma_f32_16x16x32_bf16(
                    vh[mi], wl[ni], acc[mi][ni], 0, 0, 0);
            }
    }
    short* op = attTs + (long)b * ((long)C3 * HW * 2);
    int crow = (lane >> 4) * 4, ccol = lane & 15;
#pragma unroll
    for (int mi = 0; mi < 2; ++mi)
#pragma unroll
        for (int ni = 0; ni < 4; ++ni)
#pragma unroll
            for (int r = 0; r < 4; ++r) {
                long n = n0 + wid * 32 + mi * 16 + crow + r;
                int c = h * 64 + ni * 16 + ccol;
                op[n * CHN + c] = f2h_bits(acc[mi][ni][r]);
            }
}

extern "C" void kernel_launch(void* const* d_in, const int* in_sizes, int n_in,
                              void* d_out, int out_size, void* d_ws, size_t ws_size,
                              hipStream_t stream) {
    const float* x      = (const float*)d_in[0];
    const float* qkv_w  = (const float*)d_in[1];
    const float* dw_w   = (const float*)d_in[2];
    const float* proj_w = (const float*)d_in[3];
    const float* temp   = (const float*)d_in[4];
    const float* a1     = (const float*)d_in[5];
    const float* a2     = (const float*)d_in[6];
    const float* a3     = (const float*)d_in[7];
    const float* a4     = (const float*)d_in[8];
    float* out = (float*)d_out;

    char* ws = (char*)d_ws;
    // layout (139,984,896 B total, proven safe):
    //   0           qkvi: packed bf16-pair [GB][1536][4096] int (100,663,296 B);
    //               per-batch q-region reused as attT f16 [4096][512] after attn
    //   100663296   vT region (33,554,432 B): xTs f16 [GB][4096][512] (16 MB, steps 1-2),
    //               then vT packed int [GB][4096][512] (32 MB, steps 4-7)
    //   134217728   REGION_A (4,194,304 B): wqh f16 hi plane (1.5 MB) then attn_part f32
    //   138412032   Wc f32 [GB][8][64][64] (524,288 B)
    //   138936320   wph (524,288 B)
    //   139460608   wpl (524,288 B)
    int*   qkvi      = (int*)(ws);
    short* xTs       = (short*)(ws + 100663296);
    int*   vT        = (int*)(ws + 100663296);
    short* wqh       = (short*)(ws + 134217728);
    float* attn_part = (float*)(ws + 134217728);
    float* Wc        = (float*)(ws + 138412032);
    short* wph       = (short*)(ws + 138936320);
    short* wpl       = (short*)(ws + 139460608);

    k_split_w<<<256, 256, 0, stream>>>(proj_w, wph, wpl, 65536);

    for (int g = 0; g < 2; ++g) {
        const float* xg = x + (long)g * GB * CHN * HW;
        float* outg = out + (long)g * GB * CHN * HW;
        // 0. qkv weights -> f16 hi plane (region shared with attn_part)
        k_w_hi<<<768, 256, 0, stream>>>(qkv_w, wqh, 196608);
        // 1. x -> xTs f16 [n][c]
        k_transpose_xf16<<<dim3(64, 8, GB), 256, 0, stream>>>(xg, xTs);
        // 2. qkv = Wqkv(f16 hi) * x  (M=1536, N=4096, K=512), 1-pass -> bf16-pair out
        k_gemm_f16<128, 1, true><<<dim3(32, 12, GB), 256, 0, stream>>>(
            wqh, nullptr, xTs, qkvi, C3, HW, CHN, (long)HW * CHN, (long)C3 * HW);
        // 3. depthwise 3x3 + q,k L2-norm, in-place packed bf16-pair
        k_dwl2_pp<<<dim3(C3, GB), 256, 0, stream>>>(qkvi, dw_w);
        // 4. v -> vT packed int [n][c] (overwrites dead xTs)
        k_transpose_int<<<dim3(64, 8, GB), 256, 0, stream>>>(
            qkvi + (long)1024 * HW, vT, (long)C3 * HW, (long)HW * CHN);
        // 5. attn partials (8 K-slices), exact bf16 3-pass
        k_attn_pp<<<dim3(8, 8, GB), 256, 0, stream>>>(qkvi, attn_part);
        // 6. fused top-k softmax combine
        k_smcomb<<<dim3(128, 1, GB), 256, 0, stream>>>(attn_part, temp, a1, a2, a3, a4, Wc);
        // 7. attT f16 = (Wc * v)^T, into dead q-region of qkvi
        k_wv_pp<<<dim3(32, 8, GB), 256, 0, stream>>>(Wc, vT, (short*)qkvi);
        // 8. out = Wproj * att  (M=512, N=4096, K=512), 2-pass f16, f32 out, 64-row tiles
        k_gemm_f16<64, 2, false><<<dim3(32, 8, GB), 256, 0, stream>>>(
            wph, wpl, (const short*)qkvi, outg, CHN, HW, CHN,
            (long)C3 * HW * 2, (long)CHN * HW);
    }
}

// Round 9
// 307.698 us; speedup vs baseline: 3.8222x; 1.0513x over previous
//
#include <hip/hip_runtime.h>
#include <hip/hip_bf16.h>

#define CHN 512
#define HW  4096
#define C3  1536
#define GB  4   // batches per group

typedef __hip_bfloat16 bf16;
typedef __attribute__((ext_vector_type(8))) short short8;
typedef __attribute__((ext_vector_type(4))) short short4v;
typedef __attribute__((ext_vector_type(4))) float f32x4;
typedef __attribute__((ext_vector_type(4))) int   int4v;
typedef _Float16 h8_t __attribute__((ext_vector_type(8)));

__device__ inline float b2f_bits(short s) {
    union { unsigned u; float f; } uf;
    uf.u = ((unsigned)(unsigned short)s) << 16;
    return uf.f;
}
__device__ inline short f2b_bits(float x) {
    union { __hip_bfloat16 h; short s; } u;
    u.h = __float2bfloat16(x);
    return u.s;
}
// bf16 split (x ~= hi+lo, ~2^-17): precision-critical q/k/v path
__device__ inline void split_bf16(float x, short& hi, short& lo) {
    hi = f2b_bits(x);
    lo = f2b_bits(x - b2f_bits(hi));
}
__device__ inline int pack_split(float x) {
    short h, l;
    split_bf16(x, h, l);
    return (int)((unsigned short)h | ((unsigned)(unsigned short)l << 16));
}
__device__ inline void unpack8(int4v a, int4v b, short8& h, short8& l) {
#pragma unroll
    for (int j = 0; j < 4; ++j) {
        h[j]     = (short)(a[j] & 0xffff);
        l[j]     = (short)(((unsigned)a[j]) >> 16);
        h[4 + j] = (short)(b[j] & 0xffff);
        l[4 + j] = (short)(((unsigned)b[j]) >> 16);
    }
}
// f16 helpers: hi ~2^-11, hi+lo ~2^-22
__device__ inline short f2h_bits(float x) {
    _Float16 h = (_Float16)x;
    return __builtin_bit_cast(short, h);
}
__device__ inline void split_f16(float x, short& hi, short& lo) {
    _Float16 h = (_Float16)x;
    _Float16 l = (_Float16)(x - (float)h);
    hi = __builtin_bit_cast(short, h);
    lo = __builtin_bit_cast(short, l);
}
// XOR-swizzled LDS index (short units): row-major [rows][64], 16B granules
__device__ inline int swz64(int row, int g) {
    return row * 64 + ((g ^ (row & 7)) << 3);
}
__device__ inline int swz128(int row, int g) {
    return row * 128 + ((g ^ (row & 15)) << 3);
}
// async global->LDS 16B: lane's data lands at lds_base + lane*16B
__device__ inline void gload16(const void* g, void* l) {
    __builtin_amdgcn_global_load_lds(
        (const __attribute__((address_space(1))) void*)g,
        (__attribute__((address_space(3))) void*)l, 16, 0, 0);
}

// ---------------- weights f32 -> hi/lo f16 planes ----------------
__global__ __launch_bounds__(256) void k_split_w(const float* __restrict__ w,
                                                 short* __restrict__ wh,
                                                 short* __restrict__ wl, int n4) {
    int i = blockIdx.x * 256 + threadIdx.x;
    if (i < n4) {
        f32x4 v = *(const f32x4*)&w[i * 4];
        short4v h, l;
#pragma unroll
        for (int j = 0; j < 4; ++j) {
            short hh, ll;
            split_f16(v[j], hh, ll);
            h[j] = hh;
            l[j] = ll;
        }
        *(short4v*)&wh[i * 4] = h;
        *(short4v*)&wl[i * 4] = l;
    }
}

// ---------------- weights f32 -> f16 (hi only) ----------------
__global__ __launch_bounds__(256) void k_w_hi(const float* __restrict__ w,
                                              short* __restrict__ wh, int n4) {
    int i = blockIdx.x * 256 + threadIdx.x;
    if (i < n4) {
        f32x4 v = *(const f32x4*)&w[i * 4];
        short4v h;
#pragma unroll
        for (int j = 0; j < 4; ++j) h[j] = f2h_bits(v[j]);
        *(short4v*)&wh[i * 4] = h;
    }
}

// ---------------- x [C][N] f32 -> xT [N][C] f16 ----------------
__global__ __launch_bounds__(256) void k_transpose_xf16(const float* __restrict__ in,
                                                        short* __restrict__ out) {
    __shared__ float tile[64][65];
    int b = blockIdx.z;
    int c0 = blockIdx.y * 64, n0 = blockIdx.x * 64;
    const float* ip = in + (long)b * ((long)CHN * HW);
    short* op = out + (long)b * ((long)HW * CHN);
    int t = threadIdx.x;
#pragma unroll
    for (int p = 0; p < 4; ++p) {
        int id = p * 256 + t;
        int r = id >> 4, c4 = (id & 15) * 4;
        f32x4 v = *(const f32x4*)&ip[(long)(c0 + r) * HW + n0 + c4];
#pragma unroll
        for (int j = 0; j < 4; ++j) tile[r][c4 + j] = v[j];
    }
    __syncthreads();
    int col = t & 63, rr = t >> 6;
#pragma unroll
    for (int p = 0; p < 16; ++p) {
        int r = p * 4 + rr;
        op[(long)(n0 + r) * CHN + c0 + col] = f2h_bits(tile[col][r]);
    }
}

// ---------------- GEMM: C[b] = A (MxK f16 planes) * B[b]^T (NxK f16), f32 out ----------------
// PASSES=1: A-hi only. PASSES=2: (Ah+Al)·B, A exact to ~2^-22.
template <int MT, int PASSES>
__global__ __launch_bounds__(256) void k_gemm_f16(const short* __restrict__ Ah,
                                                  const short* __restrict__ Al,
                                                  const short* __restrict__ B,
                                                  float* __restrict__ C,
                                                  int M, int N, int K,
                                                  long bB, long bC) {
    __shared__ short sAh[MT * 64], sB[128 * 64];
    __shared__ short sAl[PASSES == 2 ? MT * 64 : 8];
    int b = blockIdx.z;
    int m0 = blockIdx.y * MT, n0 = blockIdx.x * 128;
    const short* Bp = B + (long)b * bB;
    int t = threadIdx.x, wid = t >> 6, lane = t & 63;
    int wr = (wid >> 1) * (MT / 2), wc = (wid & 1) * 64;
    int lrow = lane & 15, khalf = lane >> 4;
    int lrow8 = lane >> 3;                         // 0..7 within wave's 8 rows
    int gl = ((lane & 7) ^ lrow8) << 3;            // pre-swizzled source granule (shorts)
    constexpr int MR = MT / 32;                    // acc M-fragments per wave
    f32x4 acc[MR][4] = {};
    for (int kt = 0; kt < K; kt += 64) {
#pragma unroll
        for (int i = 0; i < MT / 32; ++i) {
            int rb = i * 32 + wid * 8;
            int row = rb + lrow8;
            gload16(&Ah[(long)(m0 + row) * K + kt + gl], &sAh[rb * 64]);
            if constexpr (PASSES == 2)
                gload16(&Al[(long)(m0 + row) * K + kt + gl], &sAl[rb * 64]);
        }
#pragma unroll
        for (int i = 0; i < 4; ++i) {
            int rb = i * 32 + wid * 8;
            int row = rb + lrow8;
            gload16(&Bp[(long)(n0 + row) * K + kt + gl], &sB[rb * 64]);
        }
        __syncthreads();
#pragma unroll
        for (int ks = 0; ks < 2; ++ks) {
            int gk = ks * 4 + khalf;
            h8_t ah[MR], al[MR], bh[4];
#pragma unroll
            for (int i = 0; i < MR; ++i) {
                ah[i] = *(const h8_t*)&sAh[swz64(wr + i * 16 + lrow, gk)];
                if constexpr (PASSES == 2)
                    al[i] = *(const h8_t*)&sAl[swz64(wr + i * 16 + lrow, gk)];
            }
#pragma unroll
            for (int i = 0; i < 4; ++i)
                bh[i] = *(const h8_t*)&sB[swz64(wc + i * 16 + lrow, gk)];
#pragma unroll
            for (int mi = 0; mi < MR; ++mi)
#pragma unroll
                for (int ni = 0; ni < 4; ++ni) {
                    acc[mi][ni] = __builtin_amdgcn_mfma_f32_16x16x32_f16(
                        ah[mi], bh[ni], acc[mi][ni], 0, 0, 0);
                    if constexpr (PASSES == 2)
                        acc[mi][ni] = __builtin_amdgcn_mfma_f32_16x16x32_f16(
                            al[mi], bh[ni], acc[mi][ni], 0, 0, 0);
                }
        }
        __syncthreads();
    }
    int crow = (lane >> 4) * 4, ccol = lane & 15;
#pragma unroll
    for (int mi = 0; mi < MR; ++mi)
#pragma unroll
        for (int ni = 0; ni < 4; ++ni)
#pragma unroll
            for (int r = 0; r < 4; ++r) {
                long row = m0 + wr + mi * 16 + crow + r;
                long col = n0 + wc + ni * 16 + ccol;
                C[(long)b * bC + row * N + col] = acc[mi][ni][r];
            }
}

// ---------------- fused depthwise 3x3 + (q,k) L2-norm: f32 in -> packed pair out, in-place ----------------
// Register column-stencil: lane = column, wave = 16 output rows. No LDS image.
__global__ __launch_bounds__(256) void k_dwl2_rs(int* __restrict__ qkv,
                                                 const float* __restrict__ w) {
    __shared__ float red[4];
    int ch = blockIdx.x, b = blockIdx.y;
    bool is_qk = ch < 1024;
    float* pf = (float*)(qkv + ((long)b * C3 + ch) * HW);
    int* pi = qkv + ((long)b * C3 + ch) * HW;
    float w9[9];
#pragma unroll
    for (int i = 0; i < 9; ++i) w9[i] = w[ch * 9 + i];
    int t = threadIdx.x, wid = t >> 6, lane = t & 63;
    int y0 = wid * 16;
    float out[16];
#pragma unroll
    for (int j = 0; j < 16; ++j) out[j] = 0.f;
#pragma unroll
    for (int i = 0; i < 18; ++i) {
        int r = y0 - 1 + i;
        float v = (r >= 0 && r < 64) ? pf[r * 64 + lane] : 0.f;
        float vl = __shfl_up(v, 1);
        float vr = __shfl_down(v, 1);
        if (lane == 0) vl = 0.f;
        if (lane == 63) vr = 0.f;
        int j = i - 1;  // r - y0
        if (j + 1 >= 0 && j + 1 < 16) out[j + 1] += w9[0] * vl + w9[1] * v + w9[2] * vr;
        if (j >= 0 && j < 16)         out[j]     += w9[3] * vl + w9[4] * v + w9[5] * vr;
        if (j - 1 >= 0 && j - 1 < 16) out[j - 1] += w9[6] * vl + w9[7] * v + w9[8] * vr;
    }
    float sc = 1.f;
    if (is_qk) {
        float ss = 0.f;
#pragma unroll
        for (int j = 0; j < 16; ++j) ss += out[j] * out[j];
#pragma unroll
        for (int o = 32; o; o >>= 1) ss += __shfl_xor(ss, o);
        if (lane == 0) red[wid] = ss;
        __syncthreads();   // also orders all loads before in-place stores
        float tot = red[0] + red[1] + red[2] + red[3];
        sc = 1.f / fmaxf(sqrtf(tot), 1e-12f);
    } else {
        __syncthreads();   // in-place safety: all loads before any store
    }
#pragma unroll
    for (int j = 0; j < 16; ++j)
        pi[(y0 + j) * 64 + lane] = pack_split(out[j] * sc);
}

// ---------------- attn partials: per (h, kslice, b): q(64xK)*k(64xK)^T, bf16 3-pass ----------------
__global__ __launch_bounds__(256) void k_attn_pp(const int* __restrict__ qkv,
                                                 float* __restrict__ attn_part) {
    __shared__ short sQh[64 * 128], sQl[64 * 128], sKh[64 * 128], sKl[64 * 128];
    int h = blockIdx.x, ksl = blockIdx.y, b = blockIdx.z;
    const int* qb = qkv + ((long)b * C3 + h * 64) * HW;
    const int* kb = qb + (long)512 * HW;
    int t = threadIdx.x, wid = t >> 6, lane = t & 63;
    int lrow = lane & 15, khalf = lane >> 4;
    f32x4 acc[4] = {};
    for (int kt = ksl * 512; kt < ksl * 512 + 512; kt += 128) {
#pragma unroll
        for (int p = 0; p < 4; ++p) {
            int id = p * 256 + t, row = id >> 4, g = id & 15;
            int off = swz128(row, g);
            {
                const int* s = &qb[(long)row * HW + kt + g * 8];
                int4v w0 = *(const int4v*)s, w1 = *(const int4v*)(s + 4);
                short8 hh, ll;
                unpack8(w0, w1, hh, ll);
                *(short8*)&sQh[off] = hh;
                *(short8*)&sQl[off] = ll;
            }
            {
                const int* s = &kb[(long)row * HW + kt + g * 8];
                int4v w0 = *(const int4v*)s, w1 = *(const int4v*)(s + 4);
                short8 hh, ll;
                unpack8(w0, w1, hh, ll);
                *(short8*)&sKh[off] = hh;
                *(short8*)&sKl[off] = ll;
            }
        }
        __syncthreads();
#pragma unroll
        for (int ks = 0; ks < 4; ++ks) {
            int gk = ks * 4 + khalf;
            short8 kh = *(const short8*)&sKh[swz128(wid * 16 + lrow, gk)];
            short8 kl = *(const short8*)&sKl[swz128(wid * 16 + lrow, gk)];
#pragma unroll
            for (int mi = 0; mi < 4; ++mi) {
                short8 qh = *(const short8*)&sQh[swz128(mi * 16 + lrow, gk)];
                short8 ql = *(const short8*)&sQl[swz128(mi * 16 + lrow, gk)];
                acc[mi] = __builtin_amdgcn_mfma_f32_16x16x32_bf16(qh, kh, acc[mi], 0, 0, 0);
                acc[mi] = __builtin_amdgcn_mfma_f32_16x16x32_bf16(ql, kh, acc[mi], 0, 0, 0);
                acc[mi] = __builtin_amdgcn_mfma_f32_16x16x32_bf16(qh, kl, acc[mi], 0, 0, 0);
            }
        }
        __syncthreads();
    }
    float* op = attn_part + (((long)b * 8 + ksl) * 8 + h) * 4096;
    int crow = (lane >> 4) * 4, ccol = lane & 15;
#pragma unroll
    for (int mi = 0; mi < 4; ++mi)
#pragma unroll
        for (int r = 0; r < 4; ++r)
            op[(mi * 16 + crow + r) * 64 + wid * 16 + ccol] = acc[mi][r];
}

// ---------------- fused 4x top-k masked softmax combine -> Wc (f32) ----------------
__global__ __launch_bounds__(256) void k_smcomb(const float* __restrict__ attn_part,
                                                const float* __restrict__ temp,
                                                const float* __restrict__ a1,
                                                const float* __restrict__ a2,
                                                const float* __restrict__ a3,
                                                const float* __restrict__ a4,
                                                float* __restrict__ Wc) {
    int t = threadIdx.x, wid = t >> 6, lane = t & 63;
    int b = blockIdx.z;
    int r = blockIdx.x * 4 + wid;   // (h, qrow) 0..511
    int h = r >> 6, qr = r & 63;
    float a = 0.f;
#pragma unroll
    for (int s = 0; s < 8; ++s)
        a += attn_part[(((long)b * 8 + s) * 8 + h) * 4096 + qr * 64 + lane];
    a *= temp[h];
    int cnt = 0;
#pragma unroll
    for (int j = 0; j < 64; ++j) {
        float aj = __shfl(a, j);
        cnt += (aj > a) ? 1 : 0;
    }
    float m = a;
#pragma unroll
    for (int o = 32; o; o >>= 1) m = fmaxf(m, __shfl_xor(m, o));
    float e = expf(a - m);
    const int kk[4] = {32, 42, 48, 51};
    float coef[4] = {a1[0], a2[0], a3[0], a4[0]};
    float out = 0.f;
#pragma unroll
    for (int i = 0; i < 4; ++i) {
        float ei = (cnt < kk[i]) ? e : 0.f;
        float d = ei;
#pragma unroll
        for (int o = 32; o; o >>= 1) d += __shfl_xor(d, o);
        out += coef[i] * ei / d;
    }
    Wc[((long)b * 8 + h) * 4096 + qr * 64 + lane] = out;
}

// ---------------- attT[n][c] = sum_d v[d][n]*Wc[c][d], bf16 3-pass, f16 out ----------------
// v read directly from qkv packed-pair [d][n]; transpose fused into LDS staging.
__global__ __launch_bounds__(256) void k_wv_pp(const float* __restrict__ Wc,
                                               const int* __restrict__ qkv_pp,
                                               short* __restrict__ attTs) {
    __shared__ int sVi[64 * 128];            // [d][n ^ swz(d)] packed ints (32 KB)
    __shared__ short sWh[64 * 64], sWl[64 * 64];
    int nb = blockIdx.x, h = blockIdx.y, b = blockIdx.z;
    int n0 = nb * 128;
    const float* wp = Wc + ((long)b * 8 + h) * 4096;
    const int* vp = qkv_pp + ((long)b * C3 + 1024 + h * 64) * HW;
    int t = threadIdx.x, wid = t >> 6, lane = t & 63;
    int lrow = lane & 15, khalf = lane >> 4;
    // stage V tile: rows d=0..63, cols n0..n0+127 (coalesced), XOR-swizzled cols
#pragma unroll
    for (int p = 0; p < 8; ++p) {
        int id = p * 256 + t;
        int d = id >> 5, c4 = (id & 31) * 4;
        int4v v = *(const int4v*)&vp[(long)d * HW + n0 + c4];
        int cs = c4 ^ (((d >> 3) & 3) << 3);
        *(int4v*)&sVi[d * 128 + cs] = v;
    }
    // stage Wc hi/lo planes
#pragma unroll
    for (int p = 0; p < 2; ++p) {
        int id = p * 256 + t, row = id >> 3, g = id & 7;
        f32x4 va = *(const f32x4*)&wp[row * 64 + g * 8];
        f32x4 vb = *(const f32x4*)&wp[row * 64 + g * 8 + 4];
        short8 hh, ll;
#pragma unroll
        for (int j = 0; j < 4; ++j) {
            short h0, l0, h1, l1;
            split_bf16(va[j], h0, l0);
            split_bf16(vb[j], h1, l1);
            hh[j] = h0;     ll[j] = l0;
            hh[4 + j] = h1; ll[4 + j] = l1;
        }
        int off = swz64(row, g);
        *(short8*)&sWh[off] = hh;
        *(short8*)&sWl[off] = ll;
    }
    __syncthreads();
    f32x4 acc[2][4] = {};
#pragma unroll
    for (int ks = 0; ks < 2; ++ks) {
        int gk = ks * 4 + khalf;
        short8 vh[2], vl[2], wh[4], wl[4];
#pragma unroll
        for (int i = 0; i < 2; ++i) {
            int nrow = wid * 32 + i * 16 + lrow;
            int col = nrow ^ ((gk & 3) << 3);
            int vi[8];
#pragma unroll
            for (int j = 0; j < 8; ++j)
                vi[j] = sVi[(gk * 8 + j) * 128 + col];
            int hi_[4], lo_[4];
#pragma unroll
            for (int m = 0; m < 4; ++m) {
                unsigned a = (unsigned)vi[2 * m], c = (unsigned)vi[2 * m + 1];
                hi_[m] = (int)((a & 0xffffu) | (c << 16));          // hi shorts (low16)
                lo_[m] = (int)((a >> 16) | (c & 0xffff0000u));      // lo shorts (high16)
            }
            int4v hv = {hi_[0], hi_[1], hi_[2], hi_[3]};
            int4v lv = {lo_[0], lo_[1], lo_[2], lo_[3]};
            vh[i] = __builtin_bit_cast(short8, hv);
            vl[i] = __builtin_bit_cast(short8, lv);
        }
#pragma unroll
        for (int i = 0; i < 4; ++i) {
            int rr = i * 16 + lrow;
            wh[i] = *(const short8*)&sWh[swz64(rr, gk)];
            wl[i] = *(const short8*)&sWl[swz64(rr, gk)];
        }
#pragma unroll
        for (int mi = 0; mi < 2; ++mi)
#pragma unroll
            for (int ni = 0; ni < 4; ++ni) {
                acc[mi][ni] = __builtin_amdgcn_mfma_f32_16x16x32_bf16(
                    vh[mi], wh[ni], acc[mi][ni], 0, 0, 0);
                acc[mi][ni] = __builtin_amdgcn_mfma_f32_16x16x32_bf16(
                    vl[mi], wh[ni], acc[mi][ni], 0, 0, 0);
                acc[mi][ni] = __builtin_amdgcn_mfma_f32_16x16x32_bf16(
                    vh[mi], wl[ni], acc[mi][ni], 0, 0, 0);
            }
    }
    short* op = attTs + (long)b * ((long)C3 * HW * 2);
    int crow = (lane >> 4) * 4, ccol = lane & 15;
#pragma unroll
    for (int mi = 0; mi < 2; ++mi)
#pragma unroll
        for (int ni = 0; ni < 4; ++ni)
#pragma unroll
            for (int r = 0; r < 4; ++r) {
                long n = n0 + wid * 32 + mi * 16 + crow + r;
                int c = h * 64 + ni * 16 + ccol;
                op[n * CHN + c] = f2h_bits(acc[mi][ni][r]);
            }
}

extern "C" void kernel_launch(void* const* d_in, const int* in_sizes, int n_in,
                              void* d_out, int out_size, void* d_ws, size_t ws_size,
                              hipStream_t stream) {
    const float* x      = (const float*)d_in[0];
    const float* qkv_w  = (const float*)d_in[1];
    const float* dw_w   = (const float*)d_in[2];
    const float* proj_w = (const float*)d_in[3];
    const float* temp   = (const float*)d_in[4];
    const float* a1     = (const float*)d_in[5];
    const float* a2     = (const float*)d_in[6];
    const float* a3     = (const float*)d_in[7];
    const float* a4     = (const float*)d_in[8];
    float* out = (float*)d_out;

    char* ws = (char*)d_ws;
    // layout (139,984,896 B total, proven safe):
    //   0           qkvi: f32 qkv (GEMM out) -> packed bf16-pair in-place (dwl2);
    //               per-batch q-region reused as attT f16 after attn      (100,663,296 B)
    //   100663296   xTs f16 [GB][4096][512] (16 MB)
    //   134217728   REGION_A: wqh f16 hi plane (1.5 MB) then attn_part f32 (4 MB)
    //   138412032   Wc f32 [GB][8][64][64] (524,288 B)
    //   138936320   wph (524,288 B)
    //   139460608   wpl (524,288 B)
    int*   qkvi      = (int*)(ws);
    short* xTs       = (short*)(ws + 100663296);
    short* wqh       = (short*)(ws + 134217728);
    float* attn_part = (float*)(ws + 134217728);
    float* Wc        = (float*)(ws + 138412032);
    short* wph       = (short*)(ws + 138936320);
    short* wpl       = (short*)(ws + 139460608);

    k_split_w<<<256, 256, 0, stream>>>(proj_w, wph, wpl, 65536);

    for (int g = 0; g < 2; ++g) {
        const float* xg = x + (long)g * GB * CHN * HW;
        float* outg = out + (long)g * GB * CHN * HW;
        // 0. qkv weights -> f16 hi plane (region shared with attn_part)
        k_w_hi<<<768, 256, 0, stream>>>(qkv_w, wqh, 196608);
        // 1. x -> xTs f16 [n][c]
        k_transpose_xf16<<<dim3(64, 8, GB), 256, 0, stream>>>(xg, xTs);
        // 2. qkv = Wqkv(f16 hi) * x  (M=1536, N=4096, K=512), 1-pass, f32 out
        k_gemm_f16<128, 1><<<dim3(32, 12, GB), 256, 0, stream>>>(
            wqh, nullptr, xTs, (float*)qkvi, C3, HW, CHN, (long)HW * CHN, (long)C3 * HW);
        // 3. depthwise 3x3 + q,k L2-norm: f32 -> packed pair, in-place, register stencil
        k_dwl2_rs<<<dim3(C3, GB), 256, 0, stream>>>(qkvi, dw_w);
        // 4. attn partials (8 K-slices), exact bf16 3-pass
        k_attn_pp<<<dim3(8, 8, GB), 256, 0, stream>>>(qkvi, attn_part);
        // 5. fused top-k softmax combine
        k_smcomb<<<dim3(128, 1, GB), 256, 0, stream>>>(attn_part, temp, a1, a2, a3, a4, Wc);
        // 6. attT f16 = (Wc * v)^T, v read directly (fused transpose), into dead q-region
        k_wv_pp<<<dim3(32, 8, GB), 256, 0, stream>>>(Wc, qkvi, (short*)qkvi);
        // 7. out = Wproj * att  (M=512, N=4096, K=512), 2-pass f16, f32 out, 64-row tiles
        k_gemm_f16<64, 2><<<dim3(32, 8, GB), 256, 0, stream>>>(
            wph, wpl, (const short*)qkvi, outg, CHN, HW, CHN,
            (long)C3 * HW * 2, (long)CHN * HW);
    }
}

// Round 10
// 295.349 us; speedup vs baseline: 3.9820x; 1.0418x over previous
//
#include <hip/hip_runtime.h>
#include <hip/hip_bf16.h>

#define CHN 512
#define HW  4096
#define C3  1536
#define GB  4   // batches per group

typedef __hip_bfloat16 bf16;
typedef __attribute__((ext_vector_type(8))) short short8;
typedef __attribute__((ext_vector_type(4))) short short4v;
typedef __attribute__((ext_vector_type(4))) float f32x4;
typedef __attribute__((ext_vector_type(4))) int   int4v;
typedef _Float16 h8_t __attribute__((ext_vector_type(8)));

__device__ inline float b2f_bits(short s) {
    union { unsigned u; float f; } uf;
    uf.u = ((unsigned)(unsigned short)s) << 16;
    return uf.f;
}
__device__ inline short f2b_bits(float x) {
    union { __hip_bfloat16 h; short s; } u;
    u.h = __float2bfloat16(x);
    return u.s;
}
// bf16 split (x ~= hi+lo, ~2^-17): precision-critical q/k/v path
__device__ inline void split_bf16(float x, short& hi, short& lo) {
    hi = f2b_bits(x);
    lo = f2b_bits(x - b2f_bits(hi));
}
__device__ inline int pack_split(float x) {
    short h, l;
    split_bf16(x, h, l);
    return (int)((unsigned short)h | ((unsigned)(unsigned short)l << 16));
}
__device__ inline void unpack8(int4v a, int4v b, short8& h, short8& l) {
#pragma unroll
    for (int j = 0; j < 4; ++j) {
        h[j]     = (short)(a[j] & 0xffff);
        l[j]     = (short)(((unsigned)a[j]) >> 16);
        h[4 + j] = (short)(b[j] & 0xffff);
        l[4 + j] = (short)(((unsigned)b[j]) >> 16);
    }
}
// f16 helpers: hi ~2^-11
__device__ inline short f2h_bits(float x) {
    _Float16 h = (_Float16)x;
    return __builtin_bit_cast(short, h);
}
// XOR-swizzled LDS index (short units): row-major [rows][64], 16B granules
__device__ inline int swz64(int row, int g) {
    return row * 64 + ((g ^ (row & 7)) << 3);
}
__device__ inline int swz128(int row, int g) {
    return row * 128 + ((g ^ (row & 15)) << 3);
}
// async global->LDS 16B: lane's data lands at lds_base + lane*16B
__device__ inline void gload16(const void* g, void* l) {
    __builtin_amdgcn_global_load_lds(
        (const __attribute__((address_space(1))) void*)g,
        (__attribute__((address_space(3))) void*)l, 16, 0, 0);
}

// ---------------- weights f32 -> f16 (hi only) ----------------
__global__ __launch_bounds__(256) void k_w_hi(const float* __restrict__ w,
                                              short* __restrict__ wh, int n4) {
    int i = blockIdx.x * 256 + threadIdx.x;
    if (i < n4) {
        f32x4 v = *(const f32x4*)&w[i * 4];
        short4v h;
#pragma unroll
        for (int j = 0; j < 4; ++j) h[j] = f2h_bits(v[j]);
        *(short4v*)&wh[i * 4] = h;
    }
}

// ---------------- x [C][N] f32 -> xT [N][C] f16 ----------------
__global__ __launch_bounds__(256) void k_transpose_xf16(const float* __restrict__ in,
                                                        short* __restrict__ out) {
    __shared__ float tile[64][65];
    int b = blockIdx.z;
    int c0 = blockIdx.y * 64, n0 = blockIdx.x * 64;
    const float* ip = in + (long)b * ((long)CHN * HW);
    short* op = out + (long)b * ((long)HW * CHN);
    int t = threadIdx.x;
#pragma unroll
    for (int p = 0; p < 4; ++p) {
        int id = p * 256 + t;
        int r = id >> 4, c4 = (id & 15) * 4;
        f32x4 v = *(const f32x4*)&ip[(long)(c0 + r) * HW + n0 + c4];
#pragma unroll
        for (int j = 0; j < 4; ++j) tile[r][c4 + j] = v[j];
    }
    __syncthreads();
    int col = t & 63, rr = t >> 6;
#pragma unroll
    for (int p = 0; p < 16; ++p) {
        int r = p * 4 + rr;
        op[(long)(n0 + r) * CHN + c0 + col] = f2h_bits(tile[col][r]);
    }
}

// ---------------- GEMM: C[b] = A (MxK f16 hi) * B[b]^T (NxK f16), 1-pass, f32 out ----------------
template <int MT>
__global__ __launch_bounds__(256) void k_gemm_f16(const short* __restrict__ Ah,
                                                  const short* __restrict__ B,
                                                  float* __restrict__ C,
                                                  int M, int N, int K,
                                                  long bB, long bC) {
    __shared__ short sAh[MT * 64], sB[128 * 64];
    int b = blockIdx.z;
    int m0 = blockIdx.y * MT, n0 = blockIdx.x * 128;
    const short* Bp = B + (long)b * bB;
    int t = threadIdx.x, wid = t >> 6, lane = t & 63;
    int wr = (wid >> 1) * (MT / 2), wc = (wid & 1) * 64;
    int lrow = lane & 15, khalf = lane >> 4;
    int lrow8 = lane >> 3;                         // 0..7 within wave's 8 rows
    int gl = ((lane & 7) ^ lrow8) << 3;            // pre-swizzled source granule (shorts)
    constexpr int MR = MT / 32;                    // acc M-fragments per wave
    f32x4 acc[MR][4] = {};
    for (int kt = 0; kt < K; kt += 64) {
#pragma unroll
        for (int i = 0; i < MT / 32; ++i) {
            int rb = i * 32 + wid * 8;
            int row = rb + lrow8;
            gload16(&Ah[(long)(m0 + row) * K + kt + gl], &sAh[rb * 64]);
        }
#pragma unroll
        for (int i = 0; i < 4; ++i) {
            int rb = i * 32 + wid * 8;
            int row = rb + lrow8;
            gload16(&Bp[(long)(n0 + row) * K + kt + gl], &sB[rb * 64]);
        }
        __syncthreads();
#pragma unroll
        for (int ks = 0; ks < 2; ++ks) {
            int gk = ks * 4 + khalf;
            h8_t ah[MR], bh[4];
#pragma unroll
            for (int i = 0; i < MR; ++i)
                ah[i] = *(const h8_t*)&sAh[swz64(wr + i * 16 + lrow, gk)];
#pragma unroll
            for (int i = 0; i < 4; ++i)
                bh[i] = *(const h8_t*)&sB[swz64(wc + i * 16 + lrow, gk)];
#pragma unroll
            for (int mi = 0; mi < MR; ++mi)
#pragma unroll
                for (int ni = 0; ni < 4; ++ni)
                    acc[mi][ni] = __builtin_amdgcn_mfma_f32_16x16x32_f16(
                        ah[mi], bh[ni], acc[mi][ni], 0, 0, 0);
        }
        __syncthreads();
    }
    int crow = (lane >> 4) * 4, ccol = lane & 15;
#pragma unroll
    for (int mi = 0; mi < MR; ++mi)
#pragma unroll
        for (int ni = 0; ni < 4; ++ni)
#pragma unroll
            for (int r = 0; r < 4; ++r) {
                long row = m0 + wr + mi * 16 + crow + r;
                long col = n0 + wc + ni * 16 + ccol;
                C[(long)b * bC + row * N + col] = acc[mi][ni][r];
            }
}

// ---------------- fused depthwise 3x3 + (q,k) L2-norm, register column-stencil ----------------
// In-place per channel slot (16 KB). q/k channels (ch<1024): write [hi 4096 shorts][lo 4096 shorts].
// v channels: write packed-pair ints (as before).
__global__ __launch_bounds__(256) void k_dwl2_rs(int* __restrict__ qkv,
                                                 const float* __restrict__ w) {
    __shared__ float red[4];
    int ch = blockIdx.x, b = blockIdx.y;
    bool is_qk = ch < 1024;
    float* pf = (float*)(qkv + ((long)b * C3 + ch) * HW);
    int* pi = qkv + ((long)b * C3 + ch) * HW;
    short* ps = (short*)pi;
    float w9[9];
#pragma unroll
    for (int i = 0; i < 9; ++i) w9[i] = w[ch * 9 + i];
    int t = threadIdx.x, wid = t >> 6, lane = t & 63;
    int y0 = wid * 16;
    float out[16];
#pragma unroll
    for (int j = 0; j < 16; ++j) out[j] = 0.f;
#pragma unroll
    for (int i = 0; i < 18; ++i) {
        int r = y0 - 1 + i;
        float v = (r >= 0 && r < 64) ? pf[r * 64 + lane] : 0.f;
        float vl = __shfl_up(v, 1);
        float vr = __shfl_down(v, 1);
        if (lane == 0) vl = 0.f;
        if (lane == 63) vr = 0.f;
        int j = i - 1;  // r - y0
        if (j + 1 >= 0 && j + 1 < 16) out[j + 1] += w9[0] * vl + w9[1] * v + w9[2] * vr;
        if (j >= 0 && j < 16)         out[j]     += w9[3] * vl + w9[4] * v + w9[5] * vr;
        if (j - 1 >= 0 && j - 1 < 16) out[j - 1] += w9[6] * vl + w9[7] * v + w9[8] * vr;
    }
    if (is_qk) {
        float ss = 0.f;
#pragma unroll
        for (int j = 0; j < 16; ++j) ss += out[j] * out[j];
#pragma unroll
        for (int o = 32; o; o >>= 1) ss += __shfl_xor(ss, o);
        if (lane == 0) red[wid] = ss;
        __syncthreads();   // also orders all loads before in-place stores
        float tot = red[0] + red[1] + red[2] + red[3];
        float sc = 1.f / fmaxf(sqrtf(tot), 1e-12f);
#pragma unroll
        for (int j = 0; j < 16; ++j) {
            short hi, lo;
            split_bf16(out[j] * sc, hi, lo);
            int n = (y0 + j) * 64 + lane;
            ps[n] = hi;
            ps[4096 + n] = lo;
        }
    } else {
        __syncthreads();   // in-place safety: all loads before any store
#pragma unroll
        for (int j = 0; j < 16; ++j)
            pi[(y0 + j) * 64 + lane] = pack_split(out[j]);
    }
}

// ---------------- attn partials: per (h, kslice, b): q(64xK)*k(64xK)^T, bf16 3-pass ----------------
// q/k read from channel-local hi/lo half-planes via global_load_lds (pre-swizzled source).
__global__ __launch_bounds__(256) void k_attn_gl(const short* __restrict__ qkv_sh,
                                                 float* __restrict__ attn_part) {
    __shared__ short sQh[64 * 128], sQl[64 * 128], sKh[64 * 128], sKl[64 * 128];
    int h = blockIdx.x, ksl = blockIdx.y, b = blockIdx.z;
    // channel slot = HW*2 shorts (hi 4096 | lo 4096)
    const short* qb = qkv_sh + ((long)b * C3 + h * 64) * (HW * 2L);
    const short* kb = qb + (long)512 * HW * 2;
    int t = threadIdx.x, wid = t >> 6, lane = t & 63;
    int lrow = lane & 15, khalf = lane >> 4;
    f32x4 acc[4] = {};
    for (int kt = ksl * 512; kt < ksl * 512 + 512; kt += 128) {
#pragma unroll
        for (int i = 0; i < 4; ++i) {
            int rb = wid * 16 + i * 4;
            int row = rb + (lane >> 4);
            int gsrc = ((lane & 15) ^ (row & 15)) << 3;
            const short* qrow = qb + (long)row * (HW * 2L) + kt + gsrc;
            const short* krow = kb + (long)row * (HW * 2L) + kt + gsrc;
            gload16(qrow,        &sQh[rb * 128]);
            gload16(qrow + 4096, &sQl[rb * 128]);
            gload16(krow,        &sKh[rb * 128]);
            gload16(krow + 4096, &sKl[rb * 128]);
        }
        __syncthreads();
#pragma unroll
        for (int ks = 0; ks < 4; ++ks) {
            int gk = ks * 4 + khalf;
            short8 kh = *(const short8*)&sKh[swz128(wid * 16 + lrow, gk)];
            short8 kl = *(const short8*)&sKl[swz128(wid * 16 + lrow, gk)];
#pragma unroll
            for (int mi = 0; mi < 4; ++mi) {
                short8 qh = *(const short8*)&sQh[swz128(mi * 16 + lrow, gk)];
                short8 ql = *(const short8*)&sQl[swz128(mi * 16 + lrow, gk)];
                acc[mi] = __builtin_amdgcn_mfma_f32_16x16x32_bf16(qh, kh, acc[mi], 0, 0, 0);
                acc[mi] = __builtin_amdgcn_mfma_f32_16x16x32_bf16(ql, kh, acc[mi], 0, 0, 0);
                acc[mi] = __builtin_amdgcn_mfma_f32_16x16x32_bf16(qh, kl, acc[mi], 0, 0, 0);
            }
        }
        __syncthreads();
    }
    float* op = attn_part + (((long)b * 8 + ksl) * 8 + h) * 4096;
    int crow = (lane >> 4) * 4, ccol = lane & 15;
#pragma unroll
    for (int mi = 0; mi < 4; ++mi)
#pragma unroll
        for (int r = 0; r < 4; ++r)
            op[(mi * 16 + crow + r) * 64 + wid * 16 + ccol] = acc[mi][r];
}

// ---------------- fused 4x top-k masked softmax combine -> Wc (f32) ----------------
__global__ __launch_bounds__(256) void k_smcomb(const float* __restrict__ attn_part,
                                                const float* __restrict__ temp,
                                                const float* __restrict__ a1,
                                                const float* __restrict__ a2,
                                                const float* __restrict__ a3,
                                                const float* __restrict__ a4,
                                                float* __restrict__ Wc) {
    int t = threadIdx.x, wid = t >> 6, lane = t & 63;
    int b = blockIdx.z;
    int r = blockIdx.x * 4 + wid;   // (h, qrow) 0..511
    int h = r >> 6, qr = r & 63;
    float a = 0.f;
#pragma unroll
    for (int s = 0; s < 8; ++s)
        a += attn_part[(((long)b * 8 + s) * 8 + h) * 4096 + qr * 64 + lane];
    a *= temp[h];
    int cnt = 0;
#pragma unroll
    for (int j = 0; j < 64; ++j) {
        float aj = __shfl(a, j);
        cnt += (aj > a) ? 1 : 0;
    }
    float m = a;
#pragma unroll
    for (int o = 32; o; o >>= 1) m = fmaxf(m, __shfl_xor(m, o));
    float e = expf(a - m);
    const int kk[4] = {32, 42, 48, 51};
    float coef[4] = {a1[0], a2[0], a3[0], a4[0]};
    float out = 0.f;
#pragma unroll
    for (int i = 0; i < 4; ++i) {
        float ei = (cnt < kk[i]) ? e : 0.f;
        float d = ei;
#pragma unroll
        for (int o = 32; o; o >>= 1) d += __shfl_xor(d, o);
        out += coef[i] * ei / d;
    }
    Wc[((long)b * 8 + h) * 4096 + qr * 64 + lane] = out;
}

// ---------------- attT[n][c] = sum_d v[d][n]*Wc[c][d], bf16 3-pass, f16 out ----------------
// v read directly from qkv packed-pair [d][n]; transpose fused into LDS staging.
__global__ __launch_bounds__(256) void k_wv_pp(const float* __restrict__ Wc,
                                               const int* __restrict__ qkv_pp,
                                               short* __restrict__ attTs) {
    __shared__ int sVi[64 * 128];            // [d][n ^ swz(d)] packed ints (32 KB)
    __shared__ short sWh[64 * 64], sWl[64 * 64];
    int nb = blockIdx.x, h = blockIdx.y, b = blockIdx.z;
    int n0 = nb * 128;
    const float* wp = Wc + ((long)b * 8 + h) * 4096;
    const int* vp = qkv_pp + ((long)b * C3 + 1024 + h * 64) * HW;
    int t = threadIdx.x, wid = t >> 6, lane = t & 63;
    int lrow = lane & 15, khalf = lane >> 4;
    // stage V tile: rows d=0..63, cols n0..n0+127 (coalesced), XOR-swizzled cols
#pragma unroll
    for (int p = 0; p < 8; ++p) {
        int id = p * 256 + t;
        int d = id >> 5, c4 = (id & 31) * 4;
        int4v v = *(const int4v*)&vp[(long)d * HW + n0 + c4];
        int cs = c4 ^ (((d >> 3) & 3) << 3);
        *(int4v*)&sVi[d * 128 + cs] = v;
    }
    // stage Wc hi/lo planes
#pragma unroll
    for (int p = 0; p < 2; ++p) {
        int id = p * 256 + t, row = id >> 3, g = id & 7;
        f32x4 va = *(const f32x4*)&wp[row * 64 + g * 8];
        f32x4 vb = *(const f32x4*)&wp[row * 64 + g * 8 + 4];
        short8 hh, ll;
#pragma unroll
        for (int j = 0; j < 4; ++j) {
            short h0, l0, h1, l1;
            split_bf16(va[j], h0, l0);
            split_bf16(vb[j], h1, l1);
            hh[j] = h0;     ll[j] = l0;
            hh[4 + j] = h1; ll[4 + j] = l1;
        }
        int off = swz64(row, g);
        *(short8*)&sWh[off] = hh;
        *(short8*)&sWl[off] = ll;
    }
    __syncthreads();
    f32x4 acc[2][4] = {};
#pragma unroll
    for (int ks = 0; ks < 2; ++ks) {
        int gk = ks * 4 + khalf;
        short8 vh[2], vl[2], wh[4], wl[4];
#pragma unroll
        for (int i = 0; i < 2; ++i) {
            int nrow = wid * 32 + i * 16 + lrow;
            int col = nrow ^ ((gk & 3) << 3);
            int vi[8];
#pragma unroll
            for (int j = 0; j < 8; ++j)
                vi[j] = sVi[(gk * 8 + j) * 128 + col];
            int hi_[4], lo_[4];
#pragma unroll
            for (int m = 0; m < 4; ++m) {
                unsigned a = (unsigned)vi[2 * m], c = (unsigned)vi[2 * m + 1];
                hi_[m] = (int)((a & 0xffffu) | (c << 16));          // hi shorts (low16)
                lo_[m] = (int)((a >> 16) | (c & 0xffff0000u));      // lo shorts (high16)
            }
            int4v hv = {hi_[0], hi_[1], hi_[2], hi_[3]};
            int4v lv = {lo_[0], lo_[1], lo_[2], lo_[3]};
            vh[i] = __builtin_bit_cast(short8, hv);
            vl[i] = __builtin_bit_cast(short8, lv);
        }
#pragma unroll
        for (int i = 0; i < 4; ++i) {
            int rr = i * 16 + lrow;
            wh[i] = *(const short8*)&sWh[swz64(rr, gk)];
            wl[i] = *(const short8*)&sWl[swz64(rr, gk)];
        }
#pragma unroll
        for (int mi = 0; mi < 2; ++mi)
#pragma unroll
            for (int ni = 0; ni < 4; ++ni) {
                acc[mi][ni] = __builtin_amdgcn_mfma_f32_16x16x32_bf16(
                    vh[mi], wh[ni], acc[mi][ni], 0, 0, 0);
                acc[mi][ni] = __builtin_amdgcn_mfma_f32_16x16x32_bf16(
                    vl[mi], wh[ni], acc[mi][ni], 0, 0, 0);
                acc[mi][ni] = __builtin_amdgcn_mfma_f32_16x16x32_bf16(
                    vh[mi], wl[ni], acc[mi][ni], 0, 0, 0);
            }
    }
    short* op = attTs + (long)b * ((long)C3 * HW * 2);
    int crow = (lane >> 4) * 4, ccol = lane & 15;
#pragma unroll
    for (int mi = 0; mi < 2; ++mi)
#pragma unroll
        for (int ni = 0; ni < 4; ++ni)
#pragma unroll
            for (int r = 0; r < 4; ++r) {
                long n = n0 + wid * 32 + mi * 16 + crow + r;
                int c = h * 64 + ni * 16 + ccol;
                op[n * CHN + c] = f2h_bits(acc[mi][ni][r]);
            }
}

extern "C" void kernel_launch(void* const* d_in, const int* in_sizes, int n_in,
                              void* d_out, int out_size, void* d_ws, size_t ws_size,
                              hipStream_t stream) {
    const float* x      = (const float*)d_in[0];
    const float* qkv_w  = (const float*)d_in[1];
    const float* dw_w   = (const float*)d_in[2];
    const float* proj_w = (const float*)d_in[3];
    const float* temp   = (const float*)d_in[4];
    const float* a1     = (const float*)d_in[5];
    const float* a2     = (const float*)d_in[6];
    const float* a3     = (const float*)d_in[7];
    const float* a4     = (const float*)d_in[8];
    float* out = (float*)d_out;

    char* ws = (char*)d_ws;
    // layout (139,984,896 B total, proven safe):
    //   0           qkvi: f32 qkv (GEMM out); dwl2 rewrites in-place:
    //               q/k channels -> [hi 4096 sh | lo 4096 sh] per 16KB slot,
    //               v channels  -> packed bf16-pair ints.
    //               Per-batch q-region reused as attT f16 after attn.  (100,663,296 B)
    //   100663296   xTs f16 [GB][4096][512] (16 MB)
    //   134217728   REGION_A: wqh f16 hi plane (1.5 MB) then attn_part f32 (4 MB)
    //   138412032   Wc f32 [GB][8][64][64] (524,288 B)
    //   138936320   wph (524,288 B)
    int*   qkvi      = (int*)(ws);
    short* xTs       = (short*)(ws + 100663296);
    short* wqh       = (short*)(ws + 134217728);
    float* attn_part = (float*)(ws + 134217728);
    float* Wc        = (float*)(ws + 138412032);
    short* wph       = (short*)(ws + 138936320);

    k_w_hi<<<256, 256, 0, stream>>>(proj_w, wph, 65536);

    for (int g = 0; g < 2; ++g) {
        const float* xg = x + (long)g * GB * CHN * HW;
        float* outg = out + (long)g * GB * CHN * HW;
        // 0. qkv weights -> f16 hi plane (region shared with attn_part)
        k_w_hi<<<768, 256, 0, stream>>>(qkv_w, wqh, 196608);
        // 1. x -> xTs f16 [n][c]
        k_transpose_xf16<<<dim3(64, 8, GB), 256, 0, stream>>>(xg, xTs);
        // 2. qkv = Wqkv(f16 hi) * x  (M=1536, N=4096, K=512), 1-pass, f32 out
        k_gemm_f16<128><<<dim3(32, 12, GB), 256, 0, stream>>>(
            wqh, xTs, (float*)qkvi, C3, HW, CHN, (long)HW * CHN, (long)C3 * HW);
        // 3. depthwise 3x3 + q,k L2-norm: f32 -> hi/lo half-planes (q,k) / packed pair (v)
        k_dwl2_rs<<<dim3(C3, GB), 256, 0, stream>>>(qkvi, dw_w);
        // 4. attn partials (8 K-slices), exact bf16 3-pass, gload_lds staging
        k_attn_gl<<<dim3(8, 8, GB), 256, 0, stream>>>((const short*)qkvi, attn_part);
        // 5. fused top-k softmax combine
        k_smcomb<<<dim3(128, 1, GB), 256, 0, stream>>>(attn_part, temp, a1, a2, a3, a4, Wc);
        // 6. attT f16 = (Wc * v)^T, v read directly (fused transpose), into dead q-region
        k_wv_pp<<<dim3(32, 8, GB), 256, 0, stream>>>(Wc, qkvi, (short*)qkvi);
        // 7. out = Wproj(f16 hi) * att  (M=512, N=4096, K=512), 1-pass, f32 out
        k_gemm_f16<64><<<dim3(32, 8, GB), 256, 0, stream>>>(
            wph, (const short*)qkvi, outg, CHN, HW, CHN,
            (long)C3 * HW * 2, (long)CHN * HW);
    }
}

// Round 11
// 273.312 us; speedup vs baseline: 4.3031x; 1.0806x over previous
//
#include <hip/hip_runtime.h>
#include <hip/hip_bf16.h>

#define CHN 512
#define HW  4096
#define C3  1536
#define GB  4   // batches per group

typedef __hip_bfloat16 bf16;
typedef __attribute__((ext_vector_type(8))) short short8;
typedef __attribute__((ext_vector_type(4))) short short4v;
typedef __attribute__((ext_vector_type(4))) float f32x4;
typedef __attribute__((ext_vector_type(4))) int   int4v;
typedef _Float16 h8_t __attribute__((ext_vector_type(8)));

__device__ inline float b2f_bits(short s) {
    union { unsigned u; float f; } uf;
    uf.u = ((unsigned)(unsigned short)s) << 16;
    return uf.f;
}
__device__ inline short f2b_bits(float x) {
    union { __hip_bfloat16 h; short s; } u;
    u.h = __float2bfloat16(x);
    return u.s;
}
// bf16 split (x ~= hi+lo, ~2^-17): precision-critical q/k/v path
__device__ inline void split_bf16(float x, short& hi, short& lo) {
    hi = f2b_bits(x);
    lo = f2b_bits(x - b2f_bits(hi));
}
__device__ inline int pack_split(float x) {
    short h, l;
    split_bf16(x, h, l);
    return (int)((unsigned short)h | ((unsigned)(unsigned short)l << 16));
}
// f16 helpers: ~2^-12 relative
__device__ inline short f2h_bits(float x) {
    _Float16 h = (_Float16)x;
    return __builtin_bit_cast(short, h);
}
__device__ inline float h2f_bits(short s) {
    return (float)__builtin_bit_cast(_Float16, s);
}
// XOR-swizzled LDS index (short units): row-major [rows][64], 16B granules
__device__ inline int swz64(int row, int g) {
    return row * 64 + ((g ^ (row & 7)) << 3);
}
__device__ inline int swz128(int row, int g) {
    return row * 128 + ((g ^ (row & 15)) << 3);
}
// async global->LDS 16B: lane's data lands at lds_base + lane*16B
__device__ inline void gload16(const void* g, void* l) {
    __builtin_amdgcn_global_load_lds(
        (const __attribute__((address_space(1))) void*)g,
        (__attribute__((address_space(3))) void*)l, 16, 0, 0);
}

// ---------------- weights f32 -> f16 (hi only) ----------------
__global__ __launch_bounds__(256) void k_w_hi(const float* __restrict__ w,
                                              short* __restrict__ wh, int n4) {
    int i = blockIdx.x * 256 + threadIdx.x;
    if (i < n4) {
        f32x4 v = *(const f32x4*)&w[i * 4];
        short4v h;
#pragma unroll
    for (int j = 0; j < 4; ++j) h[j] = f2h_bits(v[j]);
        *(short4v*)&wh[i * 4] = h;
    }
}

// ---------------- x [C][N] f32 -> xT [N][C] f16 ----------------
__global__ __launch_bounds__(256) void k_transpose_xf16(const float* __restrict__ in,
                                                        short* __restrict__ out) {
    __shared__ float tile[64][65];
    int b = blockIdx.z;
    int c0 = blockIdx.y * 64, n0 = blockIdx.x * 64;
    const float* ip = in + (long)b * ((long)CHN * HW);
    short* op = out + (long)b * ((long)HW * CHN);
    int t = threadIdx.x;
#pragma unroll
    for (int p = 0; p < 4; ++p) {
        int id = p * 256 + t;
        int r = id >> 4, c4 = (id & 15) * 4;
        f32x4 v = *(const f32x4*)&ip[(long)(c0 + r) * HW + n0 + c4];
#pragma unroll
        for (int j = 0; j < 4; ++j) tile[r][c4 + j] = v[j];
    }
    __syncthreads();
    int col = t & 63, rr = t >> 6;
#pragma unroll
    for (int p = 0; p < 16; ++p) {
        int r = p * 4 + rr;
        op[(long)(n0 + r) * CHN + c0 + col] = f2h_bits(tile[col][r]);
    }
}

// ---------------- GEMM: C[b] = A (MxK f16 hi) * B[b]^T (NxK f16), 1-pass ----------------
// OUT_F16: write f16 at row stride rstride (shorts); else f32 at rstride (floats).
template <int MT, bool OUT_F16>
__global__ __launch_bounds__(256) void k_gemm_f16(const short* __restrict__ Ah,
                                                  const short* __restrict__ B,
                                                  void* __restrict__ Cv,
                                                  int M, int N, int K,
                                                  long bB, long bC, long rstride) {
    __shared__ short sAh[MT * 64], sB[128 * 64];
    int b = blockIdx.z;
    int m0 = blockIdx.y * MT, n0 = blockIdx.x * 128;
    const short* Bp = B + (long)b * bB;
    int t = threadIdx.x, wid = t >> 6, lane = t & 63;
    int wr = (wid >> 1) * (MT / 2), wc = (wid & 1) * 64;
    int lrow = lane & 15, khalf = lane >> 4;
    int lrow8 = lane >> 3;                         // 0..7 within wave's 8 rows
    int gl = ((lane & 7) ^ lrow8) << 3;            // pre-swizzled source granule (shorts)
    constexpr int MR = MT / 32;                    // acc M-fragments per wave
    f32x4 acc[MR][4] = {};
    for (int kt = 0; kt < K; kt += 64) {
#pragma unroll
        for (int i = 0; i < MT / 32; ++i) {
            int rb = i * 32 + wid * 8;
            int row = rb + lrow8;
            gload16(&Ah[(long)(m0 + row) * K + kt + gl], &sAh[rb * 64]);
        }
#pragma unroll
        for (int i = 0; i < 4; ++i) {
            int rb = i * 32 + wid * 8;
            int row = rb + lrow8;
            gload16(&Bp[(long)(n0 + row) * K + kt + gl], &sB[rb * 64]);
        }
        __syncthreads();
#pragma unroll
        for (int ks = 0; ks < 2; ++ks) {
            int gk = ks * 4 + khalf;
            h8_t ah[MR], bh[4];
#pragma unroll
            for (int i = 0; i < MR; ++i)
                ah[i] = *(const h8_t*)&sAh[swz64(wr + i * 16 + lrow, gk)];
#pragma unroll
            for (int i = 0; i < 4; ++i)
                bh[i] = *(const h8_t*)&sB[swz64(wc + i * 16 + lrow, gk)];
#pragma unroll
            for (int mi = 0; mi < MR; ++mi)
#pragma unroll
                for (int ni = 0; ni < 4; ++ni)
                    acc[mi][ni] = __builtin_amdgcn_mfma_f32_16x16x32_f16(
                        ah[mi], bh[ni], acc[mi][ni], 0, 0, 0);
        }
        __syncthreads();
    }
    int crow = (lane >> 4) * 4, ccol = lane & 15;
#pragma unroll
    for (int mi = 0; mi < MR; ++mi)
#pragma unroll
        for (int ni = 0; ni < 4; ++ni)
#pragma unroll
            for (int r = 0; r < 4; ++r) {
                long row = m0 + wr + mi * 16 + crow + r;
                long col = n0 + wc + ni * 16 + ccol;
                float v = acc[mi][ni][r];
                if constexpr (OUT_F16)
                    ((short*)Cv)[(long)b * bC + row * rstride + col] = f2h_bits(v);
                else
                    ((float*)Cv)[(long)b * bC + row * rstride + col] = v;
            }
}

// ---------------- fused depthwise 3x3 + (q,k) L2-norm, register column-stencil ----------------
// Input: f16 in first 8KB of each 16KB channel slot. Output in-place per slot:
// q/k channels -> [hi 4096 shorts][lo 4096 shorts]; v channels -> packed-pair ints.
__global__ __launch_bounds__(256) void k_dwl2_rs(int* __restrict__ qkv,
                                                 const float* __restrict__ w) {
    __shared__ float red[4];
    int ch = blockIdx.x, b = blockIdx.y;
    bool is_qk = ch < 1024;
    int* pi = qkv + ((long)b * C3 + ch) * HW;       // slot base (HW ints = 16KB)
    short* ps = (short*)pi;
    const short* pin = (const short*)pi;            // f16 input, first 4096 shorts
    float w9[9];
#pragma unroll
    for (int i = 0; i < 9; ++i) w9[i] = w[ch * 9 + i];
    int t = threadIdx.x, wid = t >> 6, lane = t & 63;
    int y0 = wid * 16;
    float out[16];
#pragma unroll
    for (int j = 0; j < 16; ++j) out[j] = 0.f;
#pragma unroll
    for (int i = 0; i < 18; ++i) {
        int r = y0 - 1 + i;
        float v = (r >= 0 && r < 64) ? h2f_bits(pin[r * 64 + lane]) : 0.f;
        float vl = __shfl_up(v, 1);
        float vr = __shfl_down(v, 1);
        if (lane == 0) vl = 0.f;
        if (lane == 63) vr = 0.f;
        int j = i - 1;  // r - y0
        if (j + 1 >= 0 && j + 1 < 16) out[j + 1] += w9[0] * vl + w9[1] * v + w9[2] * vr;
        if (j >= 0 && j < 16)         out[j]     += w9[3] * vl + w9[4] * v + w9[5] * vr;
        if (j - 1 >= 0 && j - 1 < 16) out[j - 1] += w9[6] * vl + w9[7] * v + w9[8] * vr;
    }
    if (is_qk) {
        float ss = 0.f;
#pragma unroll
        for (int j = 0; j < 16; ++j) ss += out[j] * out[j];
#pragma unroll
        for (int o = 32; o; o >>= 1) ss += __shfl_xor(ss, o);
        if (lane == 0) red[wid] = ss;
        __syncthreads();   // also orders all loads before in-place stores
        float tot = red[0] + red[1] + red[2] + red[3];
        float sc = 1.f / fmaxf(sqrtf(tot), 1e-12f);
#pragma unroll
        for (int j = 0; j < 16; ++j) {
            short hi, lo;
            split_bf16(out[j] * sc, hi, lo);
            int n = (y0 + j) * 64 + lane;
            ps[n] = hi;
            ps[4096 + n] = lo;
        }
    } else {
        __syncthreads();   // in-place safety: all loads before any store
#pragma unroll
        for (int j = 0; j < 16; ++j)
            pi[(y0 + j) * 64 + lane] = pack_split(out[j]);
    }
}

// ---------------- attn partials: per (h, kslice, b): q(64xK)*k(64xK)^T, bf16 3-pass ----------------
// q/k read from channel-local hi/lo half-planes via global_load_lds (pre-swizzled source).
__global__ __launch_bounds__(256) void k_attn_gl(const short* __restrict__ qkv_sh,
                                                 float* __restrict__ attn_part) {
    __shared__ short sQh[64 * 128], sQl[64 * 128], sKh[64 * 128], sKl[64 * 128];
    int h = blockIdx.x, ksl = blockIdx.y, b = blockIdx.z;
    // channel slot = HW*2 shorts (hi 4096 | lo 4096)
    const short* qb = qkv_sh + ((long)b * C3 + h * 64) * (HW * 2L);
    const short* kb = qb + (long)512 * HW * 2;
    int t = threadIdx.x, wid = t >> 6, lane = t & 63;
    int lrow = lane & 15, khalf = lane >> 4;
    f32x4 acc[4] = {};
    for (int kt = ksl * 512; kt < ksl * 512 + 512; kt += 128) {
#pragma unroll
        for (int i = 0; i < 4; ++i) {
            int rb = wid * 16 + i * 4;
            int row = rb + (lane >> 4);
            int gsrc = ((lane & 15) ^ (row & 15)) << 3;
            const short* qrow = qb + (long)row * (HW * 2L) + kt + gsrc;
            const short* krow = kb + (long)row * (HW * 2L) + kt + gsrc;
            gload16(qrow,        &sQh[rb * 128]);
            gload16(qrow + 4096, &sQl[rb * 128]);
            gload16(krow,        &sKh[rb * 128]);
            gload16(krow + 4096, &sKl[rb * 128]);
        }
        __syncthreads();
#pragma unroll
        for (int ks = 0; ks < 4; ++ks) {
            int gk = ks * 4 + khalf;
            short8 kh = *(const short8*)&sKh[swz128(wid * 16 + lrow, gk)];
            short8 kl = *(const short8*)&sKl[swz128(wid * 16 + lrow, gk)];
#pragma unroll
            for (int mi = 0; mi < 4; ++mi) {
                short8 qh = *(const short8*)&sQh[swz128(mi * 16 + lrow, gk)];
                short8 ql = *(const short8*)&sQl[swz128(mi * 16 + lrow, gk)];
                acc[mi] = __builtin_amdgcn_mfma_f32_16x16x32_bf16(qh, kh, acc[mi], 0, 0, 0);
                acc[mi] = __builtin_amdgcn_mfma_f32_16x16x32_bf16(ql, kh, acc[mi], 0, 0, 0);
                acc[mi] = __builtin_amdgcn_mfma_f32_16x16x32_bf16(qh, kl, acc[mi], 0, 0, 0);
            }
        }
        __syncthreads();
    }
    float* op = attn_part + (((long)b * 8 + ksl) * 8 + h) * 4096;
    int crow = (lane >> 4) * 4, ccol = lane & 15;
#pragma unroll
    for (int mi = 0; mi < 4; ++mi)
#pragma unroll
        for (int r = 0; r < 4; ++r)
            op[(mi * 16 + crow + r) * 64 + wid * 16 + ccol] = acc[mi][r];
}

// ---------------- fused 4x top-k masked softmax combine -> Wc (f32) ----------------
__global__ __launch_bounds__(256) void k_smcomb(const float* __restrict__ attn_part,
                                                const float* __restrict__ temp,
                                                const float* __restrict__ a1,
                                                const float* __restrict__ a2,
                                                const float* __restrict__ a3,
                                                const float* __restrict__ a4,
                                                float* __restrict__ Wc) {
    int t = threadIdx.x, wid = t >> 6, lane = t & 63;
    int b = blockIdx.z;
    int r = blockIdx.x * 4 + wid;   // (h, qrow) 0..511
    int h = r >> 6, qr = r & 63;
    float a = 0.f;
#pragma unroll
    for (int s = 0; s < 8; ++s)
        a += attn_part[(((long)b * 8 + s) * 8 + h) * 4096 + qr * 64 + lane];
    a *= temp[h];
    int cnt = 0;
#pragma unroll
    for (int j = 0; j < 64; ++j) {
        float aj = __shfl(a, j);
        cnt += (aj > a) ? 1 : 0;
    }
    float m = a;
#pragma unroll
    for (int o = 32; o; o >>= 1) m = fmaxf(m, __shfl_xor(m, o));
    float e = expf(a - m);
    const int kk[4] = {32, 42, 48, 51};
    float coef[4] = {a1[0], a2[0], a3[0], a4[0]};
    float out = 0.f;
#pragma unroll
    for (int i = 0; i < 4; ++i) {
        float ei = (cnt < kk[i]) ? e : 0.f;
        float d = ei;
#pragma unroll
        for (int o = 32; o; o >>= 1) d += __shfl_xor(d, o);
        out += coef[i] * ei / d;
    }
    Wc[((long)b * 8 + h) * 4096 + qr * 64 + lane] = out;
}

// ---------------- attT[n][c] = sum_d v[d][n]*Wc[c][d], bf16 3-pass, f16 out ----------------
// v read directly from qkv packed-pair [d][n]; transpose fused into LDS staging.
__global__ __launch_bounds__(256) void k_wv_pp(const float* __restrict__ Wc,
                                               const int* __restrict__ qkv_pp,
                                               short* __restrict__ attTs) {
    __shared__ int sVi[64 * 128];            // [d][n ^ swz(d)] packed ints (32 KB)
    __shared__ short sWh[64 * 64], sWl[64 * 64];
    int nb = blockIdx.x, h = blockIdx.y, b = blockIdx.z;
    int n0 = nb * 128;
    const float* wp = Wc + ((long)b * 8 + h) * 4096;
    const int* vp = qkv_pp + ((long)b * C3 + 1024 + h * 64) * HW;
    int t = threadIdx.x, wid = t >> 6, lane = t & 63;
    int lrow = lane & 15, khalf = lane >> 4;
    // stage V tile: rows d=0..63, cols n0..n0+127 (coalesced), XOR-swizzled cols
#pragma unroll
    for (int p = 0; p < 8; ++p) {
        int id = p * 256 + t;
        int d = id >> 5, c4 = (id & 31) * 4;
        int4v v = *(const int4v*)&vp[(long)d * HW + n0 + c4];
        int cs = c4 ^ (((d >> 3) & 3) << 3);
        *(int4v*)&sVi[d * 128 + cs] = v;
    }
    // stage Wc hi/lo planes
#pragma unroll
    for (int p = 0; p < 2; ++p) {
        int id = p * 256 + t, row = id >> 3, g = id & 7;
        f32x4 va = *(const f32x4*)&wp[row * 64 + g * 8];
        f32x4 vb = *(const f32x4*)&wp[row * 64 + g * 8 + 4];
        short8 hh, ll;
#pragma unroll
        for (int j = 0; j < 4; ++j) {
            short h0, l0, h1, l1;
            split_bf16(va[j], h0, l0);
            split_bf16(vb[j], h1, l1);
            hh[j] = h0;     ll[j] = l0;
            hh[4 + j] = h1; ll[4 + j] = l1;
        }
        int off = swz64(row, g);
        *(short8*)&sWh[off] = hh;
        *(short8*)&sWl[off] = ll;
    }
    __syncthreads();
    f32x4 acc[2][4] = {};
#pragma unroll
    for (int ks = 0; ks < 2; ++ks) {
        int gk = ks * 4 + khalf;
        short8 vh[2], vl[2], wh[4], wl[4];
#pragma unroll
        for (int i = 0; i < 2; ++i) {
            int nrow = wid * 32 + i * 16 + lrow;
            int col = nrow ^ ((gk & 3) << 3);
            int vi[8];
#pragma unroll
            for (int j = 0; j < 8; ++j)
                vi[j] = sVi[(gk * 8 + j) * 128 + col];
            int hi_[4], lo_[4];
#pragma unroll
            for (int m = 0; m < 4; ++m) {
                unsigned a = (unsigned)vi[2 * m], c = (unsigned)vi[2 * m + 1];
                hi_[m] = (int)((a & 0xffffu) | (c << 16));          // hi shorts (low16)
                lo_[m] = (int)((a >> 16) | (c & 0xffff0000u));      // lo shorts (high16)
            }
            int4v hv = {hi_[0], hi_[1], hi_[2], hi_[3]};
            int4v lv = {lo_[0], lo_[1], lo_[2], lo_[3]};
            vh[i] = __builtin_bit_cast(short8, hv);
            vl[i] = __builtin_bit_cast(short8, lv);
        }
#pragma unroll
        for (int i = 0; i < 4; ++i) {
            int rr = i * 16 + lrow;
            wh[i] = *(const short8*)&sWh[swz64(rr, gk)];
            wl[i] = *(const short8*)&sWl[swz64(rr, gk)];
        }
#pragma unroll
        for (int mi = 0; mi < 2; ++mi)
#pragma unroll
            for (int ni = 0; ni < 4; ++ni) {
                acc[mi][ni] = __builtin_amdgcn_mfma_f32_16x16x32_bf16(
                    vh[mi], wh[ni], acc[mi][ni], 0, 0, 0);
                acc[mi][ni] = __builtin_amdgcn_mfma_f32_16x16x32_bf16(
                    vl[mi], wh[ni], acc[mi][ni], 0, 0, 0);
                acc[mi][ni] = __builtin_amdgcn_mfma_f32_16x16x32_bf16(
                    vh[mi], wl[ni], acc[mi][ni], 0, 0, 0);
            }
    }
    short* op = attTs + (long)b * ((long)C3 * HW * 2);
    int crow = (lane >> 4) * 4, ccol = lane & 15;
#pragma unroll
    for (int mi = 0; mi < 2; ++mi)
#pragma unroll
        for (int ni = 0; ni < 4; ++ni)
#pragma unroll
            for (int r = 0; r < 4; ++r) {
                long n = n0 + wid * 32 + mi * 16 + crow + r;
                int c = h * 64 + ni * 16 + ccol;
                op[n * CHN + c] = f2h_bits(acc[mi][ni][r]);
            }
}

extern "C" void kernel_launch(void* const* d_in, const int* in_sizes, int n_in,
                              void* d_out, int out_size, void* d_ws, size_t ws_size,
                              hipStream_t stream) {
    const float* x      = (const float*)d_in[0];
    const float* qkv_w  = (const float*)d_in[1];
    const float* dw_w   = (const float*)d_in[2];
    const float* proj_w = (const float*)d_in[3];
    const float* temp   = (const float*)d_in[4];
    const float* a1     = (const float*)d_in[5];
    const float* a2     = (const float*)d_in[6];
    const float* a3     = (const float*)d_in[7];
    const float* a4     = (const float*)d_in[8];
    float* out = (float*)d_out;

    char* ws = (char*)d_ws;
    // layout (139,984,896 B total, proven safe):
    //   0           qkvi [GB][1536] x 16KB channel slots (100,663,296 B):
    //               GEMM writes f16 into first 8KB of each slot; dwl2 rewrites
    //               in-place: q/k -> [hi|lo] half-planes, v -> packed-pair ints.
    //               Per-batch q-region reused as attT f16 after attn.
    //   100663296   xTs f16 [GB][4096][512] (16 MB)
    //   134217728   REGION_A: wqh f16 hi plane (1.5 MB) then attn_part f32 (4 MB)
    //   138412032   Wc f32 [GB][8][64][64] (524,288 B)
    //   138936320   wph (524,288 B)
    int*   qkvi      = (int*)(ws);
    short* xTs       = (short*)(ws + 100663296);
    short* wqh       = (short*)(ws + 134217728);
    float* attn_part = (float*)(ws + 134217728);
    float* Wc        = (float*)(ws + 138412032);
    short* wph       = (short*)(ws + 138936320);

    k_w_hi<<<256, 256, 0, stream>>>(proj_w, wph, 65536);

    for (int g = 0; g < 2; ++g) {
        const float* xg = x + (long)g * GB * CHN * HW;
        float* outg = out + (long)g * GB * CHN * HW;
        // 0. qkv weights -> f16 hi plane (region shared with attn_part)
        k_w_hi<<<768, 256, 0, stream>>>(qkv_w, wqh, 196608);
        // 1. x -> xTs f16 [n][c]
        k_transpose_xf16<<<dim3(64, 8, GB), 256, 0, stream>>>(xg, xTs);
        // 2. qkv = Wqkv(f16 hi) * x, 1-pass, f16 out into slot first-half
        //    (row stride 8192 shorts = one 16KB slot)
        k_gemm_f16<128, true><<<dim3(32, 12, GB), 256, 0, stream>>>(
            wqh, xTs, qkvi, C3, HW, CHN,
            (long)HW * CHN, (long)C3 * 8192, 8192);
        // 3. depthwise 3x3 + q,k L2-norm: f16 -> hi/lo half-planes (q,k) / packed pair (v)
        k_dwl2_rs<<<dim3(C3, GB), 256, 0, stream>>>(qkvi, dw_w);
        // 4. attn partials (8 K-slices), exact bf16 3-pass, gload_lds staging
        k_attn_gl<<<dim3(8, 8, GB), 256, 0, stream>>>((const short*)qkvi, attn_part);
        // 5. fused top-k softmax combine
        k_smcomb<<<dim3(128, 1, GB), 256, 0, stream>>>(attn_part, temp, a1, a2, a3, a4, Wc);
        // 6. attT f16 = (Wc * v)^T, v read directly (fused transpose), into dead q-region
        k_wv_pp<<<dim3(32, 8, GB), 256, 0, stream>>>(Wc, qkvi, (short*)qkvi);
        // 7. out = Wproj(f16 hi) * att  (M=512, N=4096, K=512), 1-pass, f32 out
        k_gemm_f16<64, false><<<dim3(32, 8, GB), 256, 0, stream>>>(
            wph, (const short*)qkvi, outg, CHN, HW, CHN,
            (long)C3 * HW * 2, (long)CHN * HW, HW);
    }
}

// Round 12
// 266.723 us; speedup vs baseline: 4.4094x; 1.0247x over previous
//
#include <hip/hip_runtime.h>
#include <hip/hip_bf16.h>

#define CHN 512
#define HW  4096
#define C3  1536
#define GB  4   // batches per group

typedef __hip_bfloat16 bf16;
typedef __attribute__((ext_vector_type(8))) short short8;
typedef __attribute__((ext_vector_type(4))) short short4v;
typedef __attribute__((ext_vector_type(4))) float f32x4;
typedef __attribute__((ext_vector_type(4))) int   int4v;
typedef _Float16 h8_t __attribute__((ext_vector_type(8)));

__device__ inline float b2f_bits(short s) {
    union { unsigned u; float f; } uf;
    uf.u = ((unsigned)(unsigned short)s) << 16;
    return uf.f;
}
__device__ inline short f2b_bits(float x) {
    union { __hip_bfloat16 h; short s; } u;
    u.h = __float2bfloat16(x);
    return u.s;
}
// bf16 split (x ~= hi+lo, ~2^-17): precision-critical q/k path
__device__ inline void split_bf16(float x, short& hi, short& lo) {
    hi = f2b_bits(x);
    lo = f2b_bits(x - b2f_bits(hi));
}
// f16 helpers: hi ~2^-12, hi+lo ~2^-22
__device__ inline short f2h_bits(float x) {
    _Float16 h = (_Float16)x;
    return __builtin_bit_cast(short, h);
}
__device__ inline float h2f_bits(short s) {
    return (float)__builtin_bit_cast(_Float16, s);
}
__device__ inline void split_f16(float x, short& hi, short& lo) {
    _Float16 h = (_Float16)x;
    _Float16 l = (_Float16)(x - (float)h);
    hi = __builtin_bit_cast(short, h);
    lo = __builtin_bit_cast(short, l);
}
// XOR-swizzled LDS index (short units): row-major [rows][64], 16B granules
__device__ inline int swz64(int row, int g) {
    return row * 64 + ((g ^ (row & 7)) << 3);
}
__device__ inline int swz128(int row, int g) {
    return row * 128 + ((g ^ (row & 15)) << 3);
}
// async global->LDS 16B: lane's data lands at lds_base + lane*16B
__device__ inline void gload16(const void* g, void* l) {
    __builtin_amdgcn_global_load_lds(
        (const __attribute__((address_space(1))) void*)g,
        (__attribute__((address_space(3))) void*)l, 16, 0, 0);
}

// ---------------- weights f32 -> f16 (hi only) ----------------
__global__ __launch_bounds__(256) void k_w_hi(const float* __restrict__ w,
                                              short* __restrict__ wh, int n4) {
    int i = blockIdx.x * 256 + threadIdx.x;
    if (i < n4) {
        f32x4 v = *(const f32x4*)&w[i * 4];
        short4v h;
#pragma unroll
        for (int j = 0; j < 4; ++j) h[j] = f2h_bits(v[j]);
        *(short4v*)&wh[i * 4] = h;
    }
}

// ---------------- x [C][N] f32 -> xT [N][C] f16 ----------------
__global__ __launch_bounds__(256) void k_transpose_xf16(const float* __restrict__ in,
                                                        short* __restrict__ out) {
    __shared__ float tile[64][65];
    int b = blockIdx.z;
    int c0 = blockIdx.y * 64, n0 = blockIdx.x * 64;
    const float* ip = in + (long)b * ((long)CHN * HW);
    short* op = out + (long)b * ((long)HW * CHN);
    int t = threadIdx.x;
#pragma unroll
    for (int p = 0; p < 4; ++p) {
        int id = p * 256 + t;
        int r = id >> 4, c4 = (id & 15) * 4;
        f32x4 v = *(const f32x4*)&ip[(long)(c0 + r) * HW + n0 + c4];
#pragma unroll
        for (int j = 0; j < 4; ++j) tile[r][c4 + j] = v[j];
    }
    __syncthreads();
    int col = t & 63, rr = t >> 6;
#pragma unroll
    for (int p = 0; p < 16; ++p) {
        int r = p * 4 + rr;
        op[(long)(n0 + r) * CHN + c0 + col] = f2h_bits(tile[col][r]);
    }
}

// ---------------- GEMM: C[b] = A (MxK f16 hi) * B[b]^T (NxK f16), 1-pass ----------------
// OUT_F16: f16 output via per-wave LDS repack + vectorized 8B stores.
template <int MT, bool OUT_F16>
__global__ __launch_bounds__(256) void k_gemm_f16(const short* __restrict__ Ah,
                                                  const short* __restrict__ B,
                                                  void* __restrict__ Cv,
                                                  int M, int N, int K,
                                                  long bB, long bC, long rstride) {
    __shared__ short smem[(MT + 128) * 64];
    short* sAh = smem;
    short* sB  = smem + MT * 64;
    int b = blockIdx.z;
    int m0 = blockIdx.y * MT, n0 = blockIdx.x * 128;
    const short* Bp = B + (long)b * bB;
    int t = threadIdx.x, wid = t >> 6, lane = t & 63;
    int wr = (wid >> 1) * (MT / 2), wc = (wid & 1) * 64;
    int lrow = lane & 15, khalf = lane >> 4;
    int lrow8 = lane >> 3;                         // 0..7 within wave's 8 rows
    int gl = ((lane & 7) ^ lrow8) << 3;            // pre-swizzled source granule (shorts)
    constexpr int MR = MT / 32;                    // acc M-fragments per wave
    f32x4 acc[MR][4] = {};
    for (int kt = 0; kt < K; kt += 64) {
#pragma unroll
        for (int i = 0; i < MT / 32; ++i) {
            int rb = i * 32 + wid * 8;
            int row = rb + lrow8;
            gload16(&Ah[(long)(m0 + row) * K + kt + gl], &sAh[rb * 64]);
        }
#pragma unroll
        for (int i = 0; i < 4; ++i) {
            int rb = i * 32 + wid * 8;
            int row = rb + lrow8;
            gload16(&Bp[(long)(n0 + row) * K + kt + gl], &sB[rb * 64]);
        }
        __syncthreads();
#pragma unroll
        for (int ks = 0; ks < 2; ++ks) {
            int gk = ks * 4 + khalf;
            h8_t ah[MR], bh[4];
#pragma unroll
            for (int i = 0; i < MR; ++i)
                ah[i] = *(const h8_t*)&sAh[swz64(wr + i * 16 + lrow, gk)];
#pragma unroll
            for (int i = 0; i < 4; ++i)
                bh[i] = *(const h8_t*)&sB[swz64(wc + i * 16 + lrow, gk)];
#pragma unroll
            for (int mi = 0; mi < MR; ++mi)
#pragma unroll
                for (int ni = 0; ni < 4; ++ni)
                    acc[mi][ni] = __builtin_amdgcn_mfma_f32_16x16x32_f16(
                        ah[mi], bh[ni], acc[mi][ni], 0, 0, 0);
        }
        __syncthreads();
    }
    int crow = (lane >> 4) * 4, ccol = lane & 15;
    if constexpr (OUT_F16) {
        // per-wave 64x64 f16 repack in its own LDS quadrant (XOR-swizzled 8B groups)
        short* rp = smem + wid * 4096;
#pragma unroll
        for (int mi = 0; mi < MR; ++mi)
#pragma unroll
            for (int ni = 0; ni < 4; ++ni)
#pragma unroll
                for (int r = 0; r < 4; ++r) {
                    int row = mi * 16 + crow + r;
                    int col = ni * 16 + ccol;
                    int addr = row * 64 + ((((col >> 2) ^ (row & 15)) << 2) | (col & 3));
                    rp[addr] = f2h_bits(acc[mi][ni][r]);
                }
        __syncthreads();
        short* Cp = (short*)Cv + (long)b * bC + (long)(m0 + wr) * rstride + n0 + wc;
#pragma unroll
        for (int it = 0; it < 16; ++it) {
            int row = it * 4 + (lane >> 4);
            int c4 = lane & 15;
            int addr = row * 64 + ((c4 ^ (row & 15)) << 2);
            short4v v4 = *(short4v*)&rp[addr];
            *(short4v*)&Cp[(long)row * rstride + c4 * 4] = v4;
        }
    } else {
#pragma unroll
        for (int mi = 0; mi < MR; ++mi)
#pragma unroll
            for (int ni = 0; ni < 4; ++ni)
#pragma unroll
                for (int r = 0; r < 4; ++r) {
                    long row = m0 + wr + mi * 16 + crow + r;
                    long col = n0 + wc + ni * 16 + ccol;
                    ((float*)Cv)[(long)b * bC + row * rstride + col] = acc[mi][ni][r];
                }
    }
}

// ---------------- fused depthwise 3x3 + (q,k) L2-norm, register column-stencil ----------------
// Input: f16 in first 8KB of each 16KB channel slot. Output in-place per slot:
// q/k channels -> [hi 4096 shorts][lo 4096 shorts]; v channels -> f16 (first half).
__global__ __launch_bounds__(256) void k_dwl2_rs(int* __restrict__ qkv,
                                                 const float* __restrict__ w) {
    __shared__ float red[4];
    int ch = blockIdx.x, b = blockIdx.y;
    bool is_qk = ch < 1024;
    int* pi = qkv + ((long)b * C3 + ch) * HW;       // slot base (HW ints = 16KB)
    short* ps = (short*)pi;
    const short* pin = (const short*)pi;            // f16 input, first 4096 shorts
    float w9[9];
#pragma unroll
    for (int i = 0; i < 9; ++i) w9[i] = w[ch * 9 + i];
    int t = threadIdx.x, wid = t >> 6, lane = t & 63;
    int y0 = wid * 16;
    float out[16];
#pragma unroll
    for (int j = 0; j < 16; ++j) out[j] = 0.f;
#pragma unroll
    for (int i = 0; i < 18; ++i) {
        int r = y0 - 1 + i;
        float v = (r >= 0 && r < 64) ? h2f_bits(pin[r * 64 + lane]) : 0.f;
        float vl = __shfl_up(v, 1);
        float vr = __shfl_down(v, 1);
        if (lane == 0) vl = 0.f;
        if (lane == 63) vr = 0.f;
        int j = i - 1;  // r - y0
        if (j + 1 >= 0 && j + 1 < 16) out[j + 1] += w9[0] * vl + w9[1] * v + w9[2] * vr;
        if (j >= 0 && j < 16)         out[j]     += w9[3] * vl + w9[4] * v + w9[5] * vr;
        if (j - 1 >= 0 && j - 1 < 16) out[j - 1] += w9[6] * vl + w9[7] * v + w9[8] * vr;
    }
    if (is_qk) {
        float ss = 0.f;
#pragma unroll
        for (int j = 0; j < 16; ++j) ss += out[j] * out[j];
#pragma unroll
        for (int o = 32; o; o >>= 1) ss += __shfl_xor(ss, o);
        if (lane == 0) red[wid] = ss;
        __syncthreads();   // also orders all loads before in-place stores
        float tot = red[0] + red[1] + red[2] + red[3];
        float sc = 1.f / fmaxf(sqrtf(tot), 1e-12f);
#pragma unroll
        for (int j = 0; j < 16; ++j) {
            short hi, lo;
            split_bf16(out[j] * sc, hi, lo);
            int n = (y0 + j) * 64 + lane;
            ps[n] = hi;
            ps[4096 + n] = lo;
        }
    } else {
        __syncthreads();   // in-place safety: all loads before any store
#pragma unroll
        for (int j = 0; j < 16; ++j)
            ps[(y0 + j) * 64 + lane] = f2h_bits(out[j]);
    }
}

// ---------------- attn partials: per (h, kslice, b): q(64xK)*k(64xK)^T, bf16 3-pass ----------------
// q/k read from channel-local hi/lo half-planes via global_load_lds (pre-swizzled source).
__global__ __launch_bounds__(256) void k_attn_gl(const short* __restrict__ qkv_sh,
                                                 float* __restrict__ attn_part) {
    __shared__ short sQh[64 * 128], sQl[64 * 128], sKh[64 * 128], sKl[64 * 128];
    int h = blockIdx.x, ksl = blockIdx.y, b = blockIdx.z;
    // channel slot = HW*2 shorts (hi 4096 | lo 4096)
    const short* qb = qkv_sh + ((long)b * C3 + h * 64) * (HW * 2L);
    const short* kb = qb + (long)512 * HW * 2;
    int t = threadIdx.x, wid = t >> 6, lane = t & 63;
    int lrow = lane & 15, khalf = lane >> 4;
    f32x4 acc[4] = {};
    for (int kt = ksl * 512; kt < ksl * 512 + 512; kt += 128) {
#pragma unroll
        for (int i = 0; i < 4; ++i) {
            int rb = wid * 16 + i * 4;
            int row = rb + (lane >> 4);
            int gsrc = ((lane & 15) ^ (row & 15)) << 3;
            const short* qrow = qb + (long)row * (HW * 2L) + kt + gsrc;
            const short* krow = kb + (long)row * (HW * 2L) + kt + gsrc;
            gload16(qrow,        &sQh[rb * 128]);
            gload16(qrow + 4096, &sQl[rb * 128]);
            gload16(krow,        &sKh[rb * 128]);
            gload16(krow + 4096, &sKl[rb * 128]);
        }
        __syncthreads();
#pragma unroll
        for (int ks = 0; ks < 4; ++ks) {
            int gk = ks * 4 + khalf;
            short8 kh = *(const short8*)&sKh[swz128(wid * 16 + lrow, gk)];
            short8 kl = *(const short8*)&sKl[swz128(wid * 16 + lrow, gk)];
#pragma unroll
            for (int mi = 0; mi < 4; ++mi) {
                short8 qh = *(const short8*)&sQh[swz128(mi * 16 + lrow, gk)];
                short8 ql = *(const short8*)&sQl[swz128(mi * 16 + lrow, gk)];
                acc[mi] = __builtin_amdgcn_mfma_f32_16x16x32_bf16(qh, kh, acc[mi], 0, 0, 0);
                acc[mi] = __builtin_amdgcn_mfma_f32_16x16x32_bf16(ql, kh, acc[mi], 0, 0, 0);
                acc[mi] = __builtin_amdgcn_mfma_f32_16x16x32_bf16(qh, kl, acc[mi], 0, 0, 0);
            }
        }
        __syncthreads();
    }
    float* op = attn_part + (((long)b * 8 + ksl) * 8 + h) * 4096;
    int crow = (lane >> 4) * 4, ccol = lane & 15;
#pragma unroll
    for (int mi = 0; mi < 4; ++mi)
#pragma unroll
        for (int r = 0; r < 4; ++r)
            op[(mi * 16 + crow + r) * 64 + wid * 16 + ccol] = acc[mi][r];
}

// ---------------- fused 4x top-k masked softmax combine -> Wc (f32) ----------------
__global__ __launch_bounds__(256) void k_smcomb(const float* __restrict__ attn_part,
                                                const float* __restrict__ temp,
                                                const float* __restrict__ a1,
                                                const float* __restrict__ a2,
                                                const float* __restrict__ a3,
                                                const float* __restrict__ a4,
                                                float* __restrict__ Wc) {
    int t = threadIdx.x, wid = t >> 6, lane = t & 63;
    int b = blockIdx.z;
    int r = blockIdx.x * 4 + wid;   // (h, qrow) 0..511
    int h = r >> 6, qr = r & 63;
    float a = 0.f;
#pragma unroll
    for (int s = 0; s < 8; ++s)
        a += attn_part[(((long)b * 8 + s) * 8 + h) * 4096 + qr * 64 + lane];
    a *= temp[h];
    int cnt = 0;
#pragma unroll
    for (int j = 0; j < 64; ++j) {
        float aj = __shfl(a, j);
        cnt += (aj > a) ? 1 : 0;
    }
    float m = a;
#pragma unroll
    for (int o = 32; o; o >>= 1) m = fmaxf(m, __shfl_xor(m, o));
    float e = expf(a - m);
    const int kk[4] = {32, 42, 48, 51};
    float coef[4] = {a1[0], a2[0], a3[0], a4[0]};
    float out = 0.f;
#pragma unroll
    for (int i = 0; i < 4; ++i) {
        float ei = (cnt < kk[i]) ? e : 0.f;
        float d = ei;
#pragma unroll
        for (int o = 32; o; o >>= 1) d += __shfl_xor(d, o);
        out += coef[i] * ei / d;
    }
    Wc[((long)b * 8 + h) * 4096 + qr * 64 + lane] = out;
}

// ---------------- attT[n][c] = sum_d v[d][n]*Wc[c][d], f16 2-pass ----------------
// v (f16, slot first-half) transposed into LDS during staging (8-short-group XOR swizzle).
__global__ __launch_bounds__(256) void k_wv_f16(const float* __restrict__ Wc,
                                                const short* __restrict__ qkv_sh,
                                                short* __restrict__ attTs) {
    __shared__ short sVt[128 * 64];          // [n][d swizzled] f16 (16 KB)
    __shared__ short sWh[64 * 64], sWl[64 * 64];
    int nb = blockIdx.x, h = blockIdx.y, b = blockIdx.z;
    int n0 = nb * 128;
    const float* wp = Wc + ((long)b * 8 + h) * 4096;
    const short* vp = qkv_sh + ((long)b * C3 + 1024 + h * 64) * 8192L;  // slot stride 8192 sh
    int t = threadIdx.x, wid = t >> 6, lane = t & 63;
    int lrow = lane & 15, khalf = lane >> 4;
    // stage V: load v[d][n0+n8..+8] (d = lane, n8 = wave/p uniform), write transposed
#pragma unroll
    for (int p = 0; p < 4; ++p) {
        int d = lane;
        int n8 = (p * 4 + wid) * 8;
        short8 v8 = *(const short8*)&vp[(long)d * 8192 + n0 + n8];
#pragma unroll
        for (int j = 0; j < 8; ++j) {
            int n = n8 + j;
            sVt[n * 64 + (((d >> 3) ^ (n & 7)) << 3) + (d & 7)] = v8[j];
        }
    }
    // stage Wc hi/lo f16 planes
#pragma unroll
    for (int p = 0; p < 2; ++p) {
        int id = p * 256 + t, row = id >> 3, g = id & 7;
        f32x4 va = *(const f32x4*)&wp[row * 64 + g * 8];
        f32x4 vb = *(const f32x4*)&wp[row * 64 + g * 8 + 4];
        short8 hh, ll;
#pragma unroll
        for (int j = 0; j < 4; ++j) {
            short h0, l0, h1, l1;
            split_f16(va[j], h0, l0);
            split_f16(vb[j], h1, l1);
            hh[j] = h0;     ll[j] = l0;
            hh[4 + j] = h1; ll[4 + j] = l1;
        }
        int off = swz64(row, g);
        *(short8*)&sWh[off] = hh;
        *(short8*)&sWl[off] = ll;
    }
    __syncthreads();
    f32x4 acc[2][4] = {};
#pragma unroll
    for (int ks = 0; ks < 2; ++ks) {
        int gk = ks * 4 + khalf;
        h8_t vf[2], wh[4], wl[4];
#pragma unroll
        for (int i = 0; i < 2; ++i) {
            int n = wid * 32 + i * 16 + lrow;
            vf[i] = *(const h8_t*)&sVt[n * 64 + ((gk ^ (n & 7)) << 3)];
        }
#pragma unroll
        for (int i = 0; i < 4; ++i) {
            int rr = i * 16 + lrow;
            wh[i] = *(const h8_t*)&sWh[swz64(rr, gk)];
            wl[i] = *(const h8_t*)&sWl[swz64(rr, gk)];
        }
#pragma unroll
        for (int mi = 0; mi < 2; ++mi)
#pragma unroll
            for (int ni = 0; ni < 4; ++ni) {
                acc[mi][ni] = __builtin_amdgcn_mfma_f32_16x16x32_f16(
                    vf[mi], wh[ni], acc[mi][ni], 0, 0, 0);
                acc[mi][ni] = __builtin_amdgcn_mfma_f32_16x16x32_f16(
                    vf[mi], wl[ni], acc[mi][ni], 0, 0, 0);
            }
    }
    short* op = attTs + (long)b * ((long)C3 * HW * 2);
    int crow = (lane >> 4) * 4, ccol = lane & 15;
#pragma unroll
    for (int mi = 0; mi < 2; ++mi)
#pragma unroll
        for (int ni = 0; ni < 4; ++ni)
#pragma unroll
            for (int r = 0; r < 4; ++r) {
                long n = n0 + wid * 32 + mi * 16 + crow + r;
                int c = h * 64 + ni * 16 + ccol;
                op[n * CHN + c] = f2h_bits(acc[mi][ni][r]);
            }
}

extern "C" void kernel_launch(void* const* d_in, const int* in_sizes, int n_in,
                              void* d_out, int out_size, void* d_ws, size_t ws_size,
                              hipStream_t stream) {
    const float* x      = (const float*)d_in[0];
    const float* qkv_w  = (const float*)d_in[1];
    const float* dw_w   = (const float*)d_in[2];
    const float* proj_w = (const float*)d_in[3];
    const float* temp   = (const float*)d_in[4];
    const float* a1     = (const float*)d_in[5];
    const float* a2     = (const float*)d_in[6];
    const float* a3     = (const float*)d_in[7];
    const float* a4     = (const float*)d_in[8];
    float* out = (float*)d_out;

    char* ws = (char*)d_ws;
    // layout (141,033,472 B total == R1-proven cap):
    //   0           qkvi [GB][1536] x 16KB channel slots (100,663,296 B):
    //               GEMM writes f16 into first 8KB of each slot; dwl2 rewrites
    //               in-place: q/k -> [hi|lo] half-planes, v -> f16 first-half.
    //               Per-batch q-region reused as attT f16 after attn.
    //   100663296   xTs f16 [GB][4096][512] (16 MB)
    //   134217728   attn_part f32 (4 MB)
    //   138412032   Wc f32 [GB][8][64][64] (524,288 B)
    //   138936320   wph (524,288 B)
    //   139460608   wqh (1,572,864 B; ends exactly at 141,033,472)
    int*   qkvi      = (int*)(ws);
    short* xTs       = (short*)(ws + 100663296);
    float* attn_part = (float*)(ws + 134217728);
    float* Wc        = (float*)(ws + 138412032);
    short* wph       = (short*)(ws + 138936320);
    short* wqh       = (short*)(ws + 139460608);

    k_w_hi<<<256, 256, 0, stream>>>(proj_w, wph, 65536);
    k_w_hi<<<768, 256, 0, stream>>>(qkv_w, wqh, 196608);

    for (int g = 0; g < 2; ++g) {
        const float* xg = x + (long)g * GB * CHN * HW;
        float* outg = out + (long)g * GB * CHN * HW;
        // 1. x -> xTs f16 [n][c]
        k_transpose_xf16<<<dim3(64, 8, GB), 256, 0, stream>>>(xg, xTs);
        // 2. qkv = Wqkv(f16 hi) * x, 1-pass, f16 out into slot first-half
        k_gemm_f16<128, true><<<dim3(32, 12, GB), 256, 0, stream>>>(
            wqh, xTs, qkvi, C3, HW, CHN,
            (long)HW * CHN, (long)C3 * 8192, 8192);
        // 3. depthwise 3x3 + q,k L2-norm: f16 -> hi/lo half-planes (q,k) / f16 (v)
        k_dwl2_rs<<<dim3(C3, GB), 256, 0, stream>>>(qkvi, dw_w);
        // 4. attn partials (8 K-slices), exact bf16 3-pass, gload_lds staging
        k_attn_gl<<<dim3(8, 8, GB), 256, 0, stream>>>((const short*)qkvi, attn_part);
        // 5. fused top-k softmax combine
        k_smcomb<<<dim3(128, 1, GB), 256, 0, stream>>>(attn_part, temp, a1, a2, a3, a4, Wc);
        // 6. attT f16 = (Wc * v)^T, f16 2-pass, into dead q-region
        k_wv_f16<<<dim3(32, 8, GB), 256, 0, stream>>>(Wc, (const short*)qkvi, (short*)qkvi);
        // 7. out = Wproj(f16 hi) * att  (M=512, N=4096, K=512), 1-pass, f32 out
        k_gemm_f16<64, false><<<dim3(32, 8, GB), 256, 0, stream>>>(
            wph, (const short*)qkvi, outg, CHN, HW, CHN,
            (long)C3 * HW * 2, (long)CHN * HW, HW);
    }
}

// Round 13
// 260.482 us; speedup vs baseline: 4.5150x; 1.0240x over previous
//
#include <hip/hip_runtime.h>
#include <hip/hip_bf16.h>

#define CHN 512
#define HW  4096
#define C3  1536
#define GB  4   // batches per group

typedef __hip_bfloat16 bf16;
typedef __attribute__((ext_vector_type(8))) short short8;
typedef __attribute__((ext_vector_type(4))) short short4v;
typedef __attribute__((ext_vector_type(4))) float f32x4;
typedef __attribute__((ext_vector_type(4))) int   int4v;
typedef _Float16 h8_t __attribute__((ext_vector_type(8)));

__device__ inline float b2f_bits(short s) {
    union { unsigned u; float f; } uf;
    uf.u = ((unsigned)(unsigned short)s) << 16;
    return uf.f;
}
__device__ inline short f2b_bits(float x) {
    union { __hip_bfloat16 h; short s; } u;
    u.h = __float2bfloat16(x);
    return u.s;
}
// bf16 split (x ~= hi+lo, ~2^-17): precision-critical q/k path
__device__ inline void split_bf16(float x, short& hi, short& lo) {
    hi = f2b_bits(x);
    lo = f2b_bits(x - b2f_bits(hi));
}
// f16 helpers: hi ~2^-12, hi+lo ~2^-22
__device__ inline short f2h_bits(float x) {
    _Float16 h = (_Float16)x;
    return __builtin_bit_cast(short, h);
}
__device__ inline float h2f_bits(short s) {
    return (float)__builtin_bit_cast(_Float16, s);
}
__device__ inline void split_f16(float x, short& hi, short& lo) {
    _Float16 h = (_Float16)x;
    _Float16 l = (_Float16)(x - (float)h);
    hi = __builtin_bit_cast(short, h);
    lo = __builtin_bit_cast(short, l);
}
// XOR-swizzled LDS index (short units): row-major [rows][64], 16B granules
__device__ inline int swz64(int row, int g) {
    return row * 64 + ((g ^ (row & 7)) << 3);
}
__device__ inline int swz128(int row, int g) {
    return row * 128 + ((g ^ (row & 15)) << 3);
}
// async global->LDS 16B: lane's data lands at lds_base + lane*16B
__device__ inline void gload16(const void* g, void* l) {
    __builtin_amdgcn_global_load_lds(
        (const __attribute__((address_space(1))) void*)g,
        (__attribute__((address_space(3))) void*)l, 16, 0, 0);
}

// ---------------- weights f32 -> f16 (hi only) ----------------
__global__ __launch_bounds__(256) void k_w_hi(const float* __restrict__ w,
                                              short* __restrict__ wh, int n4) {
    int i = blockIdx.x * 256 + threadIdx.x;
    if (i < n4) {
        f32x4 v = *(const f32x4*)&w[i * 4];
        short4v h;
#pragma unroll
        for (int j = 0; j < 4; ++j) h[j] = f2h_bits(v[j]);
        *(short4v*)&wh[i * 4] = h;
    }
}

// ---------------- x [C][N] f32 -> xT [N][C] f16 ----------------
__global__ __launch_bounds__(256) void k_transpose_xf16(const float* __restrict__ in,
                                                        short* __restrict__ out) {
    __shared__ float tile[64][65];
    int b = blockIdx.z;
    int c0 = blockIdx.y * 64, n0 = blockIdx.x * 64;
    const float* ip = in + (long)b * ((long)CHN * HW);
    short* op = out + (long)b * ((long)HW * CHN);
    int t = threadIdx.x;
#pragma unroll
    for (int p = 0; p < 4; ++p) {
        int id = p * 256 + t;
        int r = id >> 4, c4 = (id & 15) * 4;
        f32x4 v = *(const f32x4*)&ip[(long)(c0 + r) * HW + n0 + c4];
#pragma unroll
        for (int j = 0; j < 4; ++j) tile[r][c4 + j] = v[j];
    }
    __syncthreads();
    int col = t & 63, rr = t >> 6;
#pragma unroll
    for (int p = 0; p < 16; ++p) {
        int r = p * 4 + rr;
        op[(long)(n0 + r) * CHN + c0 + col] = f2h_bits(tile[col][r]);
    }
}

// ---------------- GEMM: C[b] = A (MxK f16 hi) * B[b]^T (NxK f16), 1-pass ----------------
// OUT_F16: write f16 at row stride rstride (shorts); else f32 at rstride (floats).
template <int MT, bool OUT_F16>
__global__ __launch_bounds__(256) void k_gemm_f16(const short* __restrict__ Ah,
                                                  const short* __restrict__ B,
                                                  void* __restrict__ Cv,
                                                  int M, int N, int K,
                                                  long bB, long bC, long rstride) {
    __shared__ short sAh[MT * 64], sB[128 * 64];
    int b = blockIdx.z;
    int m0 = blockIdx.y * MT, n0 = blockIdx.x * 128;
    const short* Bp = B + (long)b * bB;
    int t = threadIdx.x, wid = t >> 6, lane = t & 63;
    int wr = (wid >> 1) * (MT / 2), wc = (wid & 1) * 64;
    int lrow = lane & 15, khalf = lane >> 4;
    int lrow8 = lane >> 3;                         // 0..7 within wave's 8 rows
    int gl = ((lane & 7) ^ lrow8) << 3;            // pre-swizzled source granule (shorts)
    constexpr int MR = MT / 32;                    // acc M-fragments per wave
    f32x4 acc[MR][4] = {};
    for (int kt = 0; kt < K; kt += 64) {
#pragma unroll
        for (int i = 0; i < MT / 32; ++i) {
            int rb = i * 32 + wid * 8;
            int row = rb + lrow8;
            gload16(&Ah[(long)(m0 + row) * K + kt + gl], &sAh[rb * 64]);
        }
#pragma unroll
        for (int i = 0; i < 4; ++i) {
            int rb = i * 32 + wid * 8;
            int row = rb + lrow8;
            gload16(&Bp[(long)(n0 + row) * K + kt + gl], &sB[rb * 64]);
        }
        __syncthreads();
#pragma unroll
        for (int ks = 0; ks < 2; ++ks) {
            int gk = ks * 4 + khalf;
            h8_t ah[MR], bh[4];
#pragma unroll
            for (int i = 0; i < MR; ++i)
                ah[i] = *(const h8_t*)&sAh[swz64(wr + i * 16 + lrow, gk)];
#pragma unroll
            for (int i = 0; i < 4; ++i)
                bh[i] = *(const h8_t*)&sB[swz64(wc + i * 16 + lrow, gk)];
#pragma unroll
            for (int mi = 0; mi < MR; ++mi)
#pragma unroll
                for (int ni = 0; ni < 4; ++ni)
                    acc[mi][ni] = __builtin_amdgcn_mfma_f32_16x16x32_f16(
                        ah[mi], bh[ni], acc[mi][ni], 0, 0, 0);
        }
        __syncthreads();
    }
    int crow = (lane >> 4) * 4, ccol = lane & 15;
#pragma unroll
    for (int mi = 0; mi < MR; ++mi)
#pragma unroll
        for (int ni = 0; ni < 4; ++ni)
#pragma unroll
            for (int r = 0; r < 4; ++r) {
                long row = m0 + wr + mi * 16 + crow + r;
                long col = n0 + wc + ni * 16 + ccol;
                float v = acc[mi][ni][r];
                if constexpr (OUT_F16)
                    ((short*)Cv)[(long)b * bC + row * rstride + col] = f2h_bits(v);
                else
                    ((float*)Cv)[(long)b * bC + row * rstride + col] = v;
            }
}

// ---------------- fused depthwise 3x3 + (q,k) L2-norm, register column-stencil ----------------
// Input: f16 in first 8KB of each 16KB channel slot. Output in-place per slot:
// q/k channels -> [hi 4096 shorts][lo 4096 shorts]; v channels -> f16 (first half).
__global__ __launch_bounds__(256) void k_dwl2_rs(int* __restrict__ qkv,
                                                 const float* __restrict__ w) {
    __shared__ float red[4];
    int ch = blockIdx.x, b = blockIdx.y;
    bool is_qk = ch < 1024;
    int* pi = qkv + ((long)b * C3 + ch) * HW;       // slot base (HW ints = 16KB)
    short* ps = (short*)pi;
    const short* pin = (const short*)pi;            // f16 input, first 4096 shorts
    float w9[9];
#pragma unroll
    for (int i = 0; i < 9; ++i) w9[i] = w[ch * 9 + i];
    int t = threadIdx.x, wid = t >> 6, lane = t & 63;
    int y0 = wid * 16;
    float out[16];
#pragma unroll
    for (int j = 0; j < 16; ++j) out[j] = 0.f;
#pragma unroll
    for (int i = 0; i < 18; ++i) {
        int r = y0 - 1 + i;
        float v = (r >= 0 && r < 64) ? h2f_bits(pin[r * 64 + lane]) : 0.f;
        float vl = __shfl_up(v, 1);
        float vr = __shfl_down(v, 1);
        if (lane == 0) vl = 0.f;
        if (lane == 63) vr = 0.f;
        int j = i - 1;  // r - y0
        if (j + 1 >= 0 && j + 1 < 16) out[j + 1] += w9[0] * vl + w9[1] * v + w9[2] * vr;
        if (j >= 0 && j < 16)         out[j]     += w9[3] * vl + w9[4] * v + w9[5] * vr;
        if (j - 1 >= 0 && j - 1 < 16) out[j - 1] += w9[6] * vl + w9[7] * v + w9[8] * vr;
    }
    if (is_qk) {
        float ss = 0.f;
#pragma unroll
        for (int j = 0; j < 16; ++j) ss += out[j] * out[j];
#pragma unroll
        for (int o = 32; o; o >>= 1) ss += __shfl_xor(ss, o);
        if (lane == 0) red[wid] = ss;
        __syncthreads();   // also orders all loads before in-place stores
        float tot = red[0] + red[1] + red[2] + red[3];
        float sc = 1.f / fmaxf(sqrtf(tot), 1e-12f);
#pragma unroll
        for (int j = 0; j < 16; ++j) {
            short hi, lo;
            split_bf16(out[j] * sc, hi, lo);
            int n = (y0 + j) * 64 + lane;
            ps[n] = hi;
            ps[4096 + n] = lo;
        }
    } else {
        __syncthreads();   // in-place safety: all loads before any store
#pragma unroll
        for (int j = 0; j < 16; ++j)
            ps[(y0 + j) * 64 + lane] = f2h_bits(out[j]);
    }
}

// ---------------- attn partials: per (h, kslice, b): q(64xK)*k(64xK)^T, bf16 3-pass ----------------
// 16 K-slices of 256 for 2 blocks/CU; q/k staged via global_load_lds (pre-swizzled source).
__global__ __launch_bounds__(256) void k_attn_gl(const short* __restrict__ qkv_sh,
                                                 float* __restrict__ attn_part) {
    __shared__ short sQh[64 * 128], sQl[64 * 128], sKh[64 * 128], sKl[64 * 128];
    int h = blockIdx.x, ksl = blockIdx.y, b = blockIdx.z;
    // channel slot = HW*2 shorts (hi 4096 | lo 4096)
    const short* qb = qkv_sh + ((long)b * C3 + h * 64) * (HW * 2L);
    const short* kb = qb + (long)512 * HW * 2;
    int t = threadIdx.x, wid = t >> 6, lane = t & 63;
    int lrow = lane & 15, khalf = lane >> 4;
    f32x4 acc[4] = {};
    for (int kt = ksl * 256; kt < ksl * 256 + 256; kt += 128) {
#pragma unroll
        for (int i = 0; i < 4; ++i) {
            int rb = wid * 16 + i * 4;
            int row = rb + (lane >> 4);
            int gsrc = ((lane & 15) ^ (row & 15)) << 3;
            const short* qrow = qb + (long)row * (HW * 2L) + kt + gsrc;
            const short* krow = kb + (long)row * (HW * 2L) + kt + gsrc;
            gload16(qrow,        &sQh[rb * 128]);
            gload16(qrow + 4096, &sQl[rb * 128]);
            gload16(krow,        &sKh[rb * 128]);
            gload16(krow + 4096, &sKl[rb * 128]);
        }
        __syncthreads();
#pragma unroll
        for (int ks = 0; ks < 4; ++ks) {
            int gk = ks * 4 + khalf;
            short8 kh = *(const short8*)&sKh[swz128(wid * 16 + lrow, gk)];
            short8 kl = *(const short8*)&sKl[swz128(wid * 16 + lrow, gk)];
#pragma unroll
            for (int mi = 0; mi < 4; ++mi) {
                short8 qh = *(const short8*)&sQh[swz128(mi * 16 + lrow, gk)];
                short8 ql = *(const short8*)&sQl[swz128(mi * 16 + lrow, gk)];
                acc[mi] = __builtin_amdgcn_mfma_f32_16x16x32_bf16(qh, kh, acc[mi], 0, 0, 0);
                acc[mi] = __builtin_amdgcn_mfma_f32_16x16x32_bf16(ql, kh, acc[mi], 0, 0, 0);
                acc[mi] = __builtin_amdgcn_mfma_f32_16x16x32_bf16(qh, kl, acc[mi], 0, 0, 0);
            }
        }
        __syncthreads();
    }
    float* op = attn_part + (((long)b * 16 + ksl) * 8 + h) * 4096;
    int crow = (lane >> 4) * 4, ccol = lane & 15;
#pragma unroll
    for (int mi = 0; mi < 4; ++mi)
#pragma unroll
        for (int r = 0; r < 4; ++r)
            op[(mi * 16 + crow + r) * 64 + wid * 16 + ccol] = acc[mi][r];
}

// ---------------- fused 4x top-k masked softmax combine -> Wc (f32) ----------------
__global__ __launch_bounds__(256) void k_smcomb(const float* __restrict__ attn_part,
                                                const float* __restrict__ temp,
                                                const float* __restrict__ a1,
                                                const float* __restrict__ a2,
                                                const float* __restrict__ a3,
                                                const float* __restrict__ a4,
                                                float* __restrict__ Wc) {
    int t = threadIdx.x, wid = t >> 6, lane = t & 63;
    int b = blockIdx.z;
    int r = blockIdx.x * 4 + wid;   // (h, qrow) 0..511
    int h = r >> 6, qr = r & 63;
    float a = 0.f;
#pragma unroll
    for (int s = 0; s < 16; ++s)
        a += attn_part[(((long)b * 16 + s) * 8 + h) * 4096 + qr * 64 + lane];
    a *= temp[h];
    int cnt = 0;
#pragma unroll
    for (int j = 0; j < 64; ++j) {
        float aj = __shfl(a, j);
        cnt += (aj > a) ? 1 : 0;
    }
    float m = a;
#pragma unroll
    for (int o = 32; o; o >>= 1) m = fmaxf(m, __shfl_xor(m, o));
    float e = expf(a - m);
    const int kk[4] = {32, 42, 48, 51};
    float coef[4] = {a1[0], a2[0], a3[0], a4[0]};
    float out = 0.f;
#pragma unroll
    for (int i = 0; i < 4; ++i) {
        float ei = (cnt < kk[i]) ? e : 0.f;
        float d = ei;
#pragma unroll
        for (int o = 32; o; o >>= 1) d += __shfl_xor(d, o);
        out += coef[i] * ei / d;
    }
    Wc[((long)b * 8 + h) * 4096 + qr * 64 + lane] = out;
}

// ---------------- attT[n][c] = sum_d v[d][n]*Wc[c][d], f16 2-pass ----------------
// v (f16, slot first-half) transposed into LDS during staging (8-short-group XOR swizzle).
__global__ __launch_bounds__(256) void k_wv_f16(const float* __restrict__ Wc,
                                                const short* __restrict__ qkv_sh,
                                                short* __restrict__ attTs) {
    __shared__ short sVt[128 * 64];          // [n][d swizzled] f16 (16 KB)
    __shared__ short sWh[64 * 64], sWl[64 * 64];
    int nb = blockIdx.x, h = blockIdx.y, b = blockIdx.z;
    int n0 = nb * 128;
    const float* wp = Wc + ((long)b * 8 + h) * 4096;
    const short* vp = qkv_sh + ((long)b * C3 + 1024 + h * 64) * 8192L;  // slot stride 8192 sh
    int t = threadIdx.x, wid = t >> 6, lane = t & 63;
    int lrow = lane & 15, khalf = lane >> 4;
    // stage V: load v[d][n0+n8..+8] (d = lane, n8 = wave/p uniform), write transposed
#pragma unroll
    for (int p = 0; p < 4; ++p) {
        int d = lane;
        int n8 = (p * 4 + wid) * 8;
        short8 v8 = *(const short8*)&vp[(long)d * 8192 + n0 + n8];
#pragma unroll
        for (int j = 0; j < 8; ++j) {
            int n = n8 + j;
            sVt[n * 64 + (((d >> 3) ^ (n & 7)) << 3) + (d & 7)] = v8[j];
        }
    }
    // stage Wc hi/lo f16 planes
#pragma unroll
    for (int p = 0; p < 2; ++p) {
        int id = p * 256 + t, row = id >> 3, g = id & 7;
        f32x4 va = *(const f32x4*)&wp[row * 64 + g * 8];
        f32x4 vb = *(const f32x4*)&wp[row * 64 + g * 8 + 4];
        short8 hh, ll;
#pragma unroll
        for (int j = 0; j < 4; ++j) {
            short h0, l0, h1, l1;
            split_f16(va[j], h0, l0);
            split_f16(vb[j], h1, l1);
            hh[j] = h0;     ll[j] = l0;
            hh[4 + j] = h1; ll[4 + j] = l1;
        }
        int off = swz64(row, g);
        *(short8*)&sWh[off] = hh;
        *(short8*)&sWl[off] = ll;
    }
    __syncthreads();
    f32x4 acc[2][4] = {};
#pragma unroll
    for (int ks = 0; ks < 2; ++ks) {
        int gk = ks * 4 + khalf;
        h8_t vf[2], wh[4], wl[4];
#pragma unroll
        for (int i = 0; i < 2; ++i) {
            int n = wid * 32 + i * 16 + lrow;
            vf[i] = *(const h8_t*)&sVt[n * 64 + ((gk ^ (n & 7)) << 3)];
        }
#pragma unroll
        for (int i = 0; i < 4; ++i) {
            int rr = i * 16 + lrow;
            wh[i] = *(const h8_t*)&sWh[swz64(rr, gk)];
            wl[i] = *(const h8_t*)&sWl[swz64(rr, gk)];
        }
#pragma unroll
        for (int mi = 0; mi < 2; ++mi)
#pragma unroll
            for (int ni = 0; ni < 4; ++ni) {
                acc[mi][ni] = __builtin_amdgcn_mfma_f32_16x16x32_f16(
                    vf[mi], wh[ni], acc[mi][ni], 0, 0, 0);
                acc[mi][ni] = __builtin_amdgcn_mfma_f32_16x16x32_f16(
                    vf[mi], wl[ni], acc[mi][ni], 0, 0, 0);
            }
    }
    short* op = attTs + (long)b * ((long)C3 * HW * 2);
    int crow = (lane >> 4) * 4, ccol = lane & 15;
#pragma unroll
    for (int mi = 0; mi < 2; ++mi)
#pragma unroll
        for (int ni = 0; ni < 4; ++ni)
#pragma unroll
            for (int r = 0; r < 4; ++r) {
                long n = n0 + wid * 32 + mi * 16 + crow + r;
                int c = h * 64 + ni * 16 + ccol;
                op[n * CHN + c] = f2h_bits(acc[mi][ni][r]);
            }
}

extern "C" void kernel_launch(void* const* d_in, const int* in_sizes, int n_in,
                              void* d_out, int out_size, void* d_ws, size_t ws_size,
                              hipStream_t stream) {
    const float* x      = (const float*)d_in[0];
    const float* qkv_w  = (const float*)d_in[1];
    const float* dw_w   = (const float*)d_in[2];
    const float* proj_w = (const float*)d_in[3];
    const float* temp   = (const float*)d_in[4];
    const float* a1     = (const float*)d_in[5];
    const float* a2     = (const float*)d_in[6];
    const float* a3     = (const float*)d_in[7];
    const float* a4     = (const float*)d_in[8];
    float* out = (float*)d_out;

    char* ws = (char*)d_ws;
    // layout (141,033,472 B total == R1-proven cap):
    //   0           qkvi [GB][1536] x 16KB channel slots (100,663,296 B):
    //               GEMM writes f16 into first 8KB of each slot; dwl2 rewrites
    //               in-place: q/k -> [hi|lo] half-planes, v -> f16 first-half.
    //               Per-batch q-region reused as attT f16 after attn.
    //   100663296   SHARED region (33,554,432 B):
    //               xTs f16 [GB][4096][512] (16 MB, steps 1-2) then
    //               attn_part f32 [GB][16][8][4096] (8 MB, steps 4-5)
    //   138412032   Wc f32 [GB][8][64][64] (524,288 B)
    //   138936320   wph (524,288 B)
    //   139460608   wqh (1,572,864 B; ends exactly at 141,033,472)
    int*   qkvi      = (int*)(ws);
    short* xTs       = (short*)(ws + 100663296);
    float* attn_part = (float*)(ws + 100663296);
    float* Wc        = (float*)(ws + 138412032);
    short* wph       = (short*)(ws + 138936320);
    short* wqh       = (short*)(ws + 139460608);

    k_w_hi<<<256, 256, 0, stream>>>(proj_w, wph, 65536);
    k_w_hi<<<768, 256, 0, stream>>>(qkv_w, wqh, 196608);

    for (int g = 0; g < 2; ++g) {
        const float* xg = x + (long)g * GB * CHN * HW;
        float* outg = out + (long)g * GB * CHN * HW;
        // 1. x -> xTs f16 [n][c]
        k_transpose_xf16<<<dim3(64, 8, GB), 256, 0, stream>>>(xg, xTs);
        // 2. qkv = Wqkv(f16 hi) * x, 1-pass, f16 out into slot first-half
        k_gemm_f16<128, true><<<dim3(32, 12, GB), 256, 0, stream>>>(
            wqh, xTs, qkvi, C3, HW, CHN,
            (long)HW * CHN, (long)C3 * 8192, 8192);
        // 3. depthwise 3x3 + q,k L2-norm: f16 -> hi/lo half-planes (q,k) / f16 (v)
        k_dwl2_rs<<<dim3(C3, GB), 256, 0, stream>>>(qkvi, dw_w);
        // 4. attn partials (16 K-slices, 2 blocks/CU), exact bf16 3-pass
        k_attn_gl<<<dim3(8, 16, GB), 256, 0, stream>>>((const short*)qkvi, attn_part);
        // 5. fused top-k softmax combine (16-way partial sum)
        k_smcomb<<<dim3(128, 1, GB), 256, 0, stream>>>(attn_part, temp, a1, a2, a3, a4, Wc);
        // 6. attT f16 = (Wc * v)^T, f16 2-pass, into dead q-region
        k_wv_f16<<<dim3(32, 8, GB), 256, 0, stream>>>(Wc, (const short*)qkvi, (short*)qkvi);
        // 7. out = Wproj(f16 hi) * att  (M=512, N=4096, K=512), 1-pass, f32 out
        k_gemm_f16<64, false><<<dim3(32, 8, GB), 256, 0, stream>>>(
            wph, (const short*)qkvi, outg, CHN, HW, CHN,
            (long)C3 * HW * 2, (long)CHN * HW, HW);
    }
}